// Round 9
// baseline (5336.838 us; speedup 1.0000x reference)
//
#include <hip/hip_runtime.h>
#include <math.h>

// ---------------------------------------------------------------------------
// Refine (RE-GCN style): bf16-MFMA recurrence + decoder; f32 state with bf16
// mirrors. Round-6 base + CSR segment-mean (plain float4 gather-sum kernels;
// no f32 atomics, no 41MB memsets). All new kernels use only codegen patterns
// that compiled in rounds 0-6 (float4 loads, int atomics, global-only scans).
// N_ENT=20000 N_REL=256 H=512 C=64 K=3 L=2 T=8 E=30000 B=4096
// ---------------------------------------------------------------------------

#define N_ENT 20000
#define N_REL 256
#define HD    512
#define NE    30000
#define NB    4096
#define NT    8

typedef __attribute__((ext_vector_type(8))) short          bf16x8;
typedef __attribute__((ext_vector_type(4))) float          f32x4;
typedef __attribute__((ext_vector_type(8))) unsigned short u16x8;
typedef __attribute__((ext_vector_type(4))) unsigned short u16x4;

static __device__ __forceinline__ float sigmoidf_(float x) {
  return 1.0f / (1.0f + expf(-x));
}
static __device__ __forceinline__ unsigned short f2bf(float f) {  // RNE
  unsigned u = __float_as_uint(f);
  return (unsigned short)((u + 0x7FFFu + ((u >> 16) & 1u)) >> 16);
}

// ---------------- row L2 normalize + bf16 mirror ---------------------------
__global__ void rownorm_kernel(const float* __restrict__ in, float* __restrict__ out,
                               unsigned short* __restrict__ outb, int rows) {
  int wid = (blockIdx.x * blockDim.x + threadIdx.x) >> 6;
  int lane = threadIdx.x & 63;
  if (wid >= rows) return;
  const float4* ip = (const float4*)(in + (size_t)wid * HD);
  float4 v0 = ip[lane];
  float4 v1 = ip[lane + 64];
  float s = v0.x * v0.x + v0.y * v0.y + v0.z * v0.z + v0.w * v0.w
          + v1.x * v1.x + v1.y * v1.y + v1.z * v1.z + v1.w * v1.w;
  #pragma unroll
  for (int m = 1; m < 64; m <<= 1) s += __shfl_xor(s, m);
  float inv = 1.0f / (sqrtf(s) + 1e-8f);
  float4* op = (float4*)(out + (size_t)wid * HD);
  v0.x *= inv; v0.y *= inv; v0.z *= inv; v0.w *= inv;
  v1.x *= inv; v1.y *= inv; v1.z *= inv; v1.w *= inv;
  op[lane] = v0; op[lane + 64] = v1;
  unsigned short* ob = outb + (size_t)wid * HD;
  u16x4 p0 = {f2bf(v0.x), f2bf(v0.y), f2bf(v0.z), f2bf(v0.w)};
  u16x4 p1 = {f2bf(v1.x), f2bf(v1.y), f2bf(v1.z), f2bf(v1.w)};
  *(u16x4*)&ob[lane * 4] = p0;
  *(u16x4*)&ob[(lane + 64) * 4] = p1;
}

// ---------------- CSR build: zero -> hist -> 3-step scan -> scatter --------
__global__ void zero_hist_kernel(int* __restrict__ h) {
  int i = blockIdx.x * 256 + threadIdx.x;
  if (i < N_ENT + N_REL) h[i] = 0;
}

__global__ void hist_kernel(const int* __restrict__ d, const int* __restrict__ r,
                            int* __restrict__ histD, int* __restrict__ histR) {
  int e = blockIdx.x * 256 + threadIdx.x;
  if (e >= NE) return;
  atomicAdd(&histD[d[e]], 1);
  atomicAdd(&histR[r[e]], 1);
}

// step 1: per-thread chunk sums of histD -> partD[256]
__global__ void scan_part_kernel(const int* __restrict__ histD, int* __restrict__ partD) {
  int t = threadIdx.x;
  int base = t * 80;                         // 256*80 >= 20000
  int s = 0;
  for (int i = 0; i < 80; ++i) {
    int idx = base + i;
    if (idx < N_ENT) s += histD[idx];
  }
  partD[t] = s;
}

// step 2: single thread: exclusive-scan partD (in place, partD[256]=total)
// and exclusive-scan histR -> startR/posR.
__global__ void scan_serial_kernel(int* __restrict__ partD, const int* __restrict__ histR,
                                   int* __restrict__ startR, int* __restrict__ posR) {
  int run = 0;
  for (int i = 0; i < 256; ++i) { int v = partD[i]; partD[i] = run; run += v; }
  partD[256] = run;
  run = 0;
  for (int i = 0; i < 256; ++i) { int v = histR[i]; startR[i] = run; posR[i] = run; run += v; }
  startR[256] = run;
}

// step 3: per-thread local exclusive scan of its chunk -> startD/posD
__global__ void scan_local_kernel(const int* __restrict__ histD, const int* __restrict__ partD,
                                  int* __restrict__ startD, int* __restrict__ posD) {
  int t = threadIdx.x;
  int run = partD[t];
  int base = t * 80;
  for (int i = 0; i < 80; ++i) {
    int idx = base + i;
    if (idx < N_ENT) {
      startD[idx] = run;
      posD[idx] = run;
      run += histD[idx];
    }
  }
  if (t == 0) startD[N_ENT] = partD[256];
}

__global__ void scatter_kernel(const int* __restrict__ d, const int* __restrict__ r,
                               int* __restrict__ posD, int* __restrict__ posR,
                               int* __restrict__ edgeD, int* __restrict__ edgeR) {
  int e = blockIdx.x * 256 + threadIdx.x;
  if (e >= NE) return;
  int p = atomicAdd(&posD[d[e]], 1);
  edgeD[p] = e;
  int p2 = atomicAdd(&posR[r[e]], 1);
  edgeR[p2] = e;
}

// ---------------- seg-sum via CSR: one wave per output row (f32) -----------
// aggR[r] = sum over edges with rel==r of ent[src[e]]; cntR[r] = degree.
__global__ __launch_bounds__(256)
void agg_rel_csr(const float* __restrict__ ent, const int* __restrict__ src,
                 const int* __restrict__ edgeR, const int* __restrict__ startR,
                 float* __restrict__ aggR, float* __restrict__ cntR) {
  int r = blockIdx.x * 4 + (threadIdx.x >> 6);
  if (r >= N_REL) return;
  int lane = threadIdx.x & 63;
  int s0 = startR[r], s1 = startR[r + 1];
  float4 a = make_float4(0.f, 0.f, 0.f, 0.f);
  float4 b = make_float4(0.f, 0.f, 0.f, 0.f);
  for (int i = s0; i < s1; ++i) {
    int e = edgeR[i];
    int s = src[e];
    const float4* p = (const float4*)(ent + (size_t)s * HD);
    float4 x = p[lane];
    float4 y = p[lane + 64];
    a.x += x.x; a.y += x.y; a.z += x.z; a.w += x.w;
    b.x += y.x; b.y += y.y; b.z += y.z; b.w += y.w;
  }
  float4* op = (float4*)(aggR + (size_t)r * HD);
  op[lane] = a;
  op[lane + 64] = b;
  if (lane == 0) cntR[r] = (float)(s1 - s0);
}

// aggE[d] = sum over edges with dst==d of (h[src[e]] + relh[erel[e]]); cntE[d].
__global__ __launch_bounds__(256)
void agg_ent_csr(const float* __restrict__ h, const float* __restrict__ relh,
                 const int* __restrict__ src, const int* __restrict__ erel,
                 const int* __restrict__ edgeD, const int* __restrict__ startD,
                 float* __restrict__ aggE, float* __restrict__ cntE) {
  int d = blockIdx.x * 4 + (threadIdx.x >> 6);
  if (d >= N_ENT) return;
  int lane = threadIdx.x & 63;
  int s0 = startD[d], s1 = startD[d + 1];
  float4 a = make_float4(0.f, 0.f, 0.f, 0.f);
  float4 b = make_float4(0.f, 0.f, 0.f, 0.f);
  for (int i = s0; i < s1; ++i) {
    int e = edgeD[i];
    int s = src[e], r = erel[e];
    const float4* hp = (const float4*)(h + (size_t)s * HD);
    const float4* rp = (const float4*)(relh + (size_t)r * HD);
    float4 x = hp[lane];
    float4 y = hp[lane + 64];
    float4 u = rp[lane];
    float4 v = rp[lane + 64];
    a.x += x.x + u.x; a.y += x.y + u.y; a.z += x.z + u.z; a.w += x.w + u.w;
    b.x += y.x + v.x; b.y += y.y + v.y; b.z += y.z + v.z; b.w += y.w + v.w;
  }
  float4* op = (float4*)(aggE + (size_t)d * HD);
  op[lane] = a;
  op[lane + 64] = b;
  if (lane == 0) cntE[d] = (float)(s1 - s0);
}

// ---------------- GRU elementwise (+bias fold, +bf16 mirror) ---------------
__global__ void gru_kernel(const float* __restrict__ gi, const float* __restrict__ gh,
                           const float* __restrict__ bih, const float* __restrict__ bhh,
                           float* __restrict__ relh, unsigned short* __restrict__ relhb) {
  int i = blockIdx.x * blockDim.x + threadIdx.x;
  if (i >= N_REL * HD) return;
  int row = i >> 9, col = i & 511;
  const float* gir = gi + (size_t)row * 1536;
  const float* ghr = gh + (size_t)row * 1536;
  float ir = gir[col] + bih[col];
  float iz = gir[col + 512] + bih[col + 512];
  float inn = gir[col + 1024] + bih[col + 1024];
  float hr = ghr[col] + bhh[col];
  float hz = ghr[col + 512] + bhh[col + 512];
  float hn = ghr[col + 1024] + bhh[col + 1024];
  float r = sigmoidf_(ir + hr);
  float z = sigmoidf_(iz + hz);
  float n = tanhf(inn + r * hn);
  float v = (1.0f - z) * n + z * relh[i];
  relh[i] = v;
  relhb[i] = f2bf(v);
}

// ---------------- gather rows (f32) ----------------------------------------
__global__ void gather_kernel(const float* __restrict__ table, const int* __restrict__ idx,
                              float* __restrict__ out, int rows) {
  int i = blockIdx.x * blockDim.x + threadIdx.x;
  if (i >= rows * (HD / 4)) return;
  int row = i >> 7, q = i & 127;
  ((float4*)out)[i] = ((const float4*)(table + (size_t)idx[row] * HD))[q];
}

// ---------------- flat f32 -> bf16 convert (n multiple of 8) ---------------
__global__ void f2b_kernel(const float* __restrict__ in, unsigned short* __restrict__ out, int n) {
  int i = blockIdx.x * blockDim.x + threadIdx.x;
  if (i * 8 >= n) return;
  float4 a = *(const float4*)&in[i * 8];
  float4 b = *(const float4*)&in[i * 8 + 4];
  u16x8 pk = {f2bf(a.x), f2bf(a.y), f2bf(a.z), f2bf(a.w),
              f2bf(b.x), f2bf(b.y), f2bf(b.z), f2bf(b.w)};
  *(u16x8*)&out[i * 8] = pk;
}

// ---------------------------------------------------------------------------
// pack_nn: B (KxN f32 row-major) -> bf16 LDS-image layout:
// step s (32 k): idx = (s*N + n)*32 + ((g ^ ((n>>2)&3))<<3) + j  holds
// B[s*32 + g*8 + j][n].
// ---------------------------------------------------------------------------
__global__ void pack_nn_kernel(const float* __restrict__ B, unsigned short* __restrict__ out,
                               int K, int N) {
  int id = blockIdx.x * 256 + threadIdx.x;
  if (id >= (K >> 3) * N) return;
  int s = id / (N * 4);
  int rem = id - s * (N * 4);
  int n = rem >> 2, g = rem & 3;
  const float* src = B + (size_t)(s * 32 + g * 8) * N + n;
  u16x8 pk;
  #pragma unroll
  for (int j = 0; j < 8; ++j) pk[j] = f2bf(src[(size_t)j * N]);
  *(u16x8*)&out[((size_t)s * N + n) * 32 + ((g ^ ((n >> 2) & 3)) << 3)] = pk;
}

// ---------------------------------------------------------------------------
// GEMM core (round-6 form): single-barrier double-buffered bf16 MFMA GEMM.
// A = [A0 (M x K0, f32, row-scaled by 1/max(cnt,1)) | A1 (M x K1, bf16)].
// ACT: 0 plain, 1 relu(+mirror), 3 gate: u=sigmoid(v+bias[n]); C=u*D+(1-u)*C.
// ---------------------------------------------------------------------------
template <int ACT, int MIRROR>
static __device__ __forceinline__
void gemm_core(const float* __restrict__ A0, int K0, const float* __restrict__ cntA,
               const unsigned short* __restrict__ A1, int K1,
               const unsigned short* __restrict__ Bp,
               const float* __restrict__ bias, const float* __restrict__ D,
               float* __restrict__ C, unsigned short* __restrict__ Cb,
               int M, int N, int m0, int n0,
               unsigned short (*As)[8192], unsigned short (*Bs)[8192]) {
  const int tid = threadIdx.x;
  const int lane = tid & 63;
  const int wv = tid >> 6;
  const int wm = wv >> 1, wn = wv & 1;
  const int lr = lane & 15, lg = lane >> 4;
  const int arow = tid >> 1;
  const int akh = (tid & 1) * 32;
  const int achunk = (tid & 1) * 4;
  const int NIT = (K0 + K1) >> 6;

  float s0 = 1.0f;
  if (K0 > 0 && (m0 + arow) < M) s0 = 1.0f / fmaxf(cntA[m0 + arow], 1.0f);

  f32x4 acc[4][4];
  #pragma unroll
  for (int i = 0; i < 4; ++i)
    #pragma unroll
    for (int j = 0; j < 4; ++j) acc[i][j] = (f32x4){0.f, 0.f, 0.f, 0.f};

  auto gload = [&](int it, u16x8* ar, u16x8* br) {
    int mrow = m0 + arow;
    int kk = it * 64 + akh;
    if (mrow < M) {
      if (kk < K0) {
        const float* p = A0 + (size_t)mrow * K0 + kk;
        #pragma unroll
        for (int q = 0; q < 4; ++q) {
          float4 x = *(const float4*)(p + q * 8);
          float4 y = *(const float4*)(p + q * 8 + 4);
          ar[q] = (u16x8){f2bf(x.x * s0), f2bf(x.y * s0), f2bf(x.z * s0), f2bf(x.w * s0),
                          f2bf(y.x * s0), f2bf(y.y * s0), f2bf(y.z * s0), f2bf(y.w * s0)};
        }
      } else {
        const unsigned short* p = A1 + (size_t)mrow * K1 + (kk - K0);
        #pragma unroll
        for (int q = 0; q < 4; ++q) ar[q] = *(const u16x8*)&p[q * 8];
      }
    } else {
      #pragma unroll
      for (int q = 0; q < 4; ++q) ar[q] = (u16x8){0, 0, 0, 0, 0, 0, 0, 0};
    }
    const unsigned short* b0 = Bp + ((size_t)(2 * it) * N + n0) * 32;
    const unsigned short* b1 = Bp + ((size_t)(2 * it + 1) * N + n0) * 32;
    br[0] = *(const u16x8*)&b0[tid * 8];
    br[1] = *(const u16x8*)&b0[2048 + tid * 8];
    br[2] = *(const u16x8*)&b1[tid * 8];
    br[3] = *(const u16x8*)&b1[2048 + tid * 8];
  };
  auto swrite = [&](int nb, const u16x8* ar, const u16x8* br) {
    #pragma unroll
    for (int q = 0; q < 4; ++q) {
      int chunk = achunk + q;
      *(u16x8*)&As[nb][arow * 64 + ((chunk ^ (arow & 7)) << 3)] = ar[q];
    }
    *(u16x8*)&Bs[nb][tid * 8] = br[0];
    *(u16x8*)&Bs[nb][2048 + tid * 8] = br[1];
    *(u16x8*)&Bs[nb][4096 + tid * 8] = br[2];
    *(u16x8*)&Bs[nb][4096 + 2048 + tid * 8] = br[3];
  };

  {
    u16x8 ar[4], br[4];
    gload(0, ar, br);
    swrite(0, ar, br);
  }
  __syncthreads();

  int cur = 0;
  for (int it = 0; it < NIT; ++it) {
    u16x8 ar[4], br[4];
    if (it + 1 < NIT) gload(it + 1, ar, br);
    bf16x8 af[2][4], bfr[2][4];
    #pragma unroll
    for (int u = 0; u < 2; ++u)
      #pragma unroll
      for (int i = 0; i < 4; ++i) {
        int r = wm * 64 + i * 16 + lr;
        af[u][i] = *(const bf16x8*)&As[cur][r * 64 + (((u * 4 + lg) ^ (r & 7)) << 3)];
        int nl = wn * 64 + i * 16 + lr;
        bfr[u][i] = *(const bf16x8*)&Bs[cur][u * 4096 + nl * 32 + ((lg ^ ((nl >> 2) & 3)) << 3)];
      }
    #pragma unroll
    for (int u = 0; u < 2; ++u)
      #pragma unroll
      for (int i = 0; i < 4; ++i)
        #pragma unroll
        for (int j = 0; j < 4; ++j)
          acc[i][j] = __builtin_amdgcn_mfma_f32_16x16x32_bf16(af[u][i], bfr[u][j], acc[i][j], 0, 0, 0);
    if (it + 1 < NIT) swrite(cur ^ 1, ar, br);
    __syncthreads();
    cur ^= 1;
  }

  #pragma unroll
  for (int i = 0; i < 4; ++i) {
    int m = m0 + wm * 64 + i * 16 + lg * 4;
    #pragma unroll
    for (int j = 0; j < 4; ++j) {
      int n = n0 + wn * 64 + j * 16 + lr;
      #pragma unroll
      for (int q = 0; q < 4; ++q) {
        int mr = m + q;
        if (mr >= M) continue;
        size_t o = (size_t)mr * N + n;
        float v = acc[i][j][q];
        if (ACT == 0) {
          C[o] = v;
        } else if (ACT == 1) {
          float rr = fmaxf(v, 0.0f);
          C[o] = rr;
          if (MIRROR) Cb[o] = f2bf(rr);
        } else {
          float u_ = sigmoidf_(v + bias[n]);
          float rr = u_ * D[o] + (1.0f - u_) * C[o];
          C[o] = rr;
          if (MIRROR) Cb[o] = f2bf(rr);
        }
      }
    }
  }
}

template <int ACT, int MIRROR>
__global__ __launch_bounds__(256, 2)
void gemm_nn2(const float* __restrict__ A0, int K0, const float* __restrict__ cntA,
              const unsigned short* __restrict__ A1, int K1,
              const unsigned short* __restrict__ Bp,
              const float* __restrict__ bias, const float* __restrict__ D,
              float* __restrict__ C, unsigned short* __restrict__ Cb, int M, int N) {
  __shared__ unsigned short As[2][8192];
  __shared__ unsigned short Bs[2][8192];
  gemm_core<ACT, MIRROR>(A0, K0, cntA, A1, K1, Bp, bias, D, C, Cb, M, N,
                         blockIdx.x * 128, blockIdx.y * 128, As, Bs);
}

// Fused GRU GEMMs: z=0 -> gi = [aggR/cnt | rel_bf] @ wp_ih; z=1 -> gh = relh_bf @ wp_hh
__global__ __launch_bounds__(256, 2)
void gru_gemms(const float* __restrict__ aggR, const float* __restrict__ cntR,
               const unsigned short* __restrict__ rel_bf,
               const unsigned short* __restrict__ relh_bf,
               const unsigned short* __restrict__ wp_ih,
               const unsigned short* __restrict__ wp_hh,
               float* __restrict__ gi, float* __restrict__ gh) {
  __shared__ unsigned short As[2][8192];
  __shared__ unsigned short Bs[2][8192];
  if (blockIdx.z == 0)
    gemm_core<0, 0>(aggR, 512, cntR, rel_bf, 512, wp_ih, nullptr, nullptr,
                    gi, nullptr, N_REL, 1536, blockIdx.x * 128, blockIdx.y * 128, As, Bs);
  else
    gemm_core<0, 0>(nullptr, 0, nullptr, relh_bf, 512, wp_hh, nullptr, nullptr,
                    gh, nullptr, N_REL, 1536, blockIdx.x * 128, blockIdx.y * 128, As, Bs);
}

// ---------------------------------------------------------------------------
// pack_fw: fw (32768x512 f32) -> bf16 image (same layout as pack_nn, N=512)
// ---------------------------------------------------------------------------
__global__ __launch_bounds__(256)
void pack_fw_kernel(const float* __restrict__ f0, const float* __restrict__ f1,
                    const float* __restrict__ f2, const float* __restrict__ f3,
                    unsigned short* __restrict__ o0, unsigned short* __restrict__ o1,
                    unsigned short* __restrict__ o2, unsigned short* __restrict__ o3) {
  __shared__ float L[32][512];
  const float* fw; unsigned short* op;
  switch (blockIdx.y) {
    case 0: fw = f0; op = o0; break;
    case 1: fw = f1; op = o1; break;
    case 2: fw = f2; op = o2; break;
    default: fw = f3; op = o3; break;
  }
  int s = blockIdx.x, tid = threadIdx.x;
  #pragma unroll
  for (int i = 0; i < 16; ++i) {
    int idx = tid + 256 * i;
    int r = idx >> 7, cq = (idx & 127) << 2;
    *(float4*)&L[r][cq] = *(const float4*)&fw[(size_t)(s * 32 + r) * 512 + cq];
  }
  __syncthreads();
  #pragma unroll
  for (int ii = 0; ii < 8; ++ii) {
    int slot = tid + 256 * ii;
    int n = slot >> 2, g = slot & 3;
    u16x8 pk;
    #pragma unroll
    for (int j = 0; j < 8; ++j) pk[j] = f2bf(L[g * 8 + j][n]);
    size_t off = (size_t)s * 16384 + n * 32 + ((g ^ ((n >> 2) & 3)) << 3);
    *(u16x8*)&op[off] = pk;
  }
}

// ---------------------------------------------------------------------------
// convgen: conv1d('SAME',K=3)+relu -> A_conv bf16 [NB][c*512+h], both paths.
// ---------------------------------------------------------------------------
template <int CIN>
__global__ __launch_bounds__(256)
void convgen_kernel(const float* __restrict__ X0e, const float* __restrict__ X1e,
                    const float* __restrict__ X2e,
                    const float* __restrict__ cwE, const float* __restrict__ cbE,
                    const float* __restrict__ X0r, const float* __restrict__ X1r,
                    const float* __restrict__ X2r,
                    const float* __restrict__ cwR, const float* __restrict__ cbR,
                    unsigned short* __restrict__ Ae, unsigned short* __restrict__ Ar) {
  __shared__ float wsm[64 * CIN * 3];
  __shared__ float bsm[64];
  const int path = blockIdx.y;
  const float* X[CIN]; const float* cw; const float* cb; unsigned short* A;
  if (path == 0) {
    X[0] = X0e; X[1] = X1e; if constexpr (CIN == 3) X[2] = X2e;
    cw = cwE; cb = cbE; A = Ae;
  } else {
    X[0] = X0r; X[1] = X1r; if constexpr (CIN == 3) X[2] = X2r;
    cw = cwR; cb = cbR; A = Ar;
  }
  const int tid = threadIdx.x;
  for (int i = tid; i < 64 * CIN * 3; i += 256) wsm[i] = cw[i];
  if (tid < 64) bsm[tid] = cb[tid];
  __syncthreads();

  const int o = tid & 63;
  const int b = blockIdx.x * 4 + (tid >> 6);
  const int h = o * 8;

  float xm[CIN][8], xl[CIN], xr[CIN];
  #pragma unroll
  for (int ci = 0; ci < CIN; ++ci) {
    const float* row = X[ci] + (size_t)b * HD + h;
    float4 a4 = *(const float4*)row;
    float4 b4 = *(const float4*)(row + 4);
    xm[ci][0] = a4.x; xm[ci][1] = a4.y; xm[ci][2] = a4.z; xm[ci][3] = a4.w;
    xm[ci][4] = b4.x; xm[ci][5] = b4.y; xm[ci][6] = b4.z; xm[ci][7] = b4.w;
    xl[ci] = (h > 0) ? row[-1] : 0.f;
    xr[ci] = (h + 8 < HD) ? row[8] : 0.f;
  }
  unsigned short* dst = A + (size_t)b * 32768 + h;
  for (int c = 0; c < 64; ++c) {
    float v[8];
    float cbv = bsm[c];
    #pragma unroll
    for (int e = 0; e < 8; ++e) v[e] = cbv;
    #pragma unroll
    for (int ci = 0; ci < CIN; ++ci) {
      float w0 = wsm[(c * CIN + ci) * 3 + 0];
      float w1 = wsm[(c * CIN + ci) * 3 + 1];
      float w2 = wsm[(c * CIN + ci) * 3 + 2];
      #pragma unroll
      for (int e = 0; e < 8; ++e) {
        float lft = e ? xm[ci][e - 1] : xl[ci];
        float rgt = (e < 7) ? xm[ci][e + 1] : xr[ci];
        v[e] = fmaf(lft, w0, fmaf(xm[ci][e], w1, fmaf(rgt, w2, v[e])));
      }
    }
    u16x8 pk;
    #pragma unroll
    for (int e = 0; e < 8; ++e) pk[e] = f2bf(fmaxf(v[e], 0.f));
    *(u16x8*)&dst[c * 512] = pk;
  }
}

// ---------------------------------------------------------------------------
// gemm_fc: part[path][ks] = A_conv(4096 x 32768 bf16) @ fw-image, KSPLIT=4.
// ---------------------------------------------------------------------------
__global__ __launch_bounds__(256, 2)
void gemm_fc(const unsigned short* __restrict__ Abuf,
             const unsigned short* __restrict__ fwpE,
             const unsigned short* __restrict__ fwpR,
             float* __restrict__ partBase) {
  __shared__ unsigned short As[2][128 * 64];
  __shared__ unsigned short Bs[2][2 * 128 * 32];
  const int tid = threadIdx.x;
  const int lane = tid & 63;
  const int wv = tid >> 6;
  const int wm = wv >> 1, wn = wv & 1;
  const int lr = lane & 15, lg = lane >> 4;
  const int m0 = blockIdx.x * 128;
  const int n0 = blockIdx.y * 128;
  const int path = blockIdx.z >> 2;
  const int ks = blockIdx.z & 3;

  const unsigned short* A = Abuf + (size_t)path * ((size_t)NB * 32768);
  const unsigned short* fwp = (path == 0) ? fwpE : fwpR;
  float* part = partBase + (size_t)(path * 4 + ks) * ((size_t)NB * HD);

  const int arow = tid >> 1;
  const int achunk = (tid & 1) * 4;
  const unsigned short* aRow = A + (size_t)(m0 + arow) * 32768 + ks * 8192 + achunk * 8;
  const unsigned short* bBase = fwp + (size_t)(ks * 256) * 16384 + (size_t)n0 * 32;

  f32x4 acc[4][4];
  #pragma unroll
  for (int i = 0; i < 4; ++i)
    #pragma unroll
    for (int j = 0; j < 4; ++j) acc[i][j] = (f32x4){0.f, 0.f, 0.f, 0.f};

  auto gload = [&](int it, u16x8* ar, u16x8* br) {
    const unsigned short* ap = aRow + it * 64;
    #pragma unroll
    for (int q = 0; q < 4; ++q) ar[q] = *(const u16x8*)&ap[q * 8];
    const unsigned short* bp = bBase + (size_t)it * 2 * 16384;
    br[0] = *(const u16x8*)&bp[tid * 8];
    br[1] = *(const u16x8*)&bp[2048 + tid * 8];
    br[2] = *(const u16x8*)&bp[16384 + tid * 8];
    br[3] = *(const u16x8*)&bp[16384 + 2048 + tid * 8];
  };
  auto swrite = [&](int nb, const u16x8* ar, const u16x8* br) {
    #pragma unroll
    for (int q = 0; q < 4; ++q) {
      int chunk = achunk + q;
      *(u16x8*)&As[nb][arow * 64 + ((chunk ^ (arow & 7)) << 3)] = ar[q];
    }
    *(u16x8*)&Bs[nb][tid * 8] = br[0];
    *(u16x8*)&Bs[nb][2048 + tid * 8] = br[1];
    *(u16x8*)&Bs[nb][4096 + tid * 8] = br[2];
    *(u16x8*)&Bs[nb][4096 + 2048 + tid * 8] = br[3];
  };

  {
    u16x8 ar[4], br[4];
    gload(0, ar, br);
    swrite(0, ar, br);
  }
  __syncthreads();

  int cur = 0;
  for (int it = 0; it < 128; ++it) {
    u16x8 ar[4], br[4];
    if (it < 127) gload(it + 1, ar, br);
    bf16x8 af[2][4], bfr[2][4];
    #pragma unroll
    for (int u = 0; u < 2; ++u)
      #pragma unroll
      for (int i = 0; i < 4; ++i) {
        int r = wm * 64 + i * 16 + lr;
        af[u][i] = *(const bf16x8*)&As[cur][r * 64 + (((u * 4 + lg) ^ (r & 7)) << 3)];
        int nl = wn * 64 + i * 16 + lr;
        bfr[u][i] = *(const bf16x8*)&Bs[cur][u * 4096 + nl * 32 + ((lg ^ ((nl >> 2) & 3)) << 3)];
      }
    #pragma unroll
    for (int u = 0; u < 2; ++u)
      #pragma unroll
      for (int i = 0; i < 4; ++i)
        #pragma unroll
        for (int j = 0; j < 4; ++j)
          acc[i][j] = __builtin_amdgcn_mfma_f32_16x16x32_bf16(af[u][i], bfr[u][j], acc[i][j], 0, 0, 0);
    if (it < 127) swrite(cur ^ 1, ar, br);
    __syncthreads();
    cur ^= 1;
  }

  #pragma unroll
  for (int i = 0; i < 4; ++i) {
    int m = m0 + wm * 64 + i * 16 + lg * 4;
    #pragma unroll
    for (int j = 0; j < 4; ++j) {
      int n = n0 + wn * 64 + j * 16 + lr;
      #pragma unroll
      for (int q = 0; q < 4; ++q)
        part[(size_t)(m + q) * HD + n] = acc[i][j][q];
    }
  }
}

// ---------------------------------------------------------------------------
// reduce 4 split-K partials + bias + relu -> f32 out AND bf16 out
// ---------------------------------------------------------------------------
__global__ void reduce4_kernel(const float* __restrict__ pE, const float* __restrict__ pR,
                               const float* __restrict__ bE, const float* __restrict__ bR,
                               float* __restrict__ oE, float* __restrict__ oR,
                               unsigned short* __restrict__ obE, unsigned short* __restrict__ obR) {
  int p = blockIdx.y;
  const float* part = p ? pR : pE;
  const float* bias = p ? bR : bE;
  float* o = p ? oR : oE;
  unsigned short* ob = p ? obR : obE;
  int i = blockIdx.x * 256 + threadIdx.x;
  int col = (i << 2) & 511;
  float4 s = *(const float4*)&part[(size_t)i * 4];
  #pragma unroll
  for (int ks = 1; ks < 4; ++ks) {
    float4 t = *(const float4*)&part[(size_t)ks * (NB * HD) + i * 4];
    s.x += t.x; s.y += t.y; s.z += t.z; s.w += t.w;
  }
  float4 b4 = *(const float4*)&bias[col];
  s.x = fmaxf(s.x + b4.x, 0.f); s.y = fmaxf(s.y + b4.y, 0.f);
  s.z = fmaxf(s.z + b4.z, 0.f); s.w = fmaxf(s.w + b4.w, 0.f);
  *(float4*)&o[(size_t)i * 4] = s;
  u16x4 pk = {f2bf(s.x), f2bf(s.y), f2bf(s.z), f2bf(s.w)};
  *(u16x4*)&ob[(size_t)i * 4] = pk;
}

// ---------------------------------------------------------------------------
// bf16 NT GEMM: C(MxN, f32) = A(MxK) @ B(NxK)^T, both bf16 row-major.
// ---------------------------------------------------------------------------
__global__ __launch_bounds__(256, 3)
void gemm_nt_bf16(const unsigned short* __restrict__ A, const unsigned short* __restrict__ B,
                  float* __restrict__ C, int M, int N, int K) {
  __shared__ unsigned short As[128 * 64];
  __shared__ unsigned short Bs[128 * 64];
  const int tid = threadIdx.x;
  const int lane = tid & 63;
  const int w = tid >> 6;
  const int wm = w >> 1, wn = w & 1;
  const int m0 = blockIdx.x * 128, n0 = blockIdx.y * 128;
  const int lr = lane & 15, lg = lane >> 4;

  f32x4 acc[4][4];
  #pragma unroll
  for (int i = 0; i < 4; ++i)
    #pragma unroll
    for (int j = 0; j < 4; ++j) acc[i][j] = (f32x4){0.f, 0.f, 0.f, 0.f};

  for (int k0 = 0; k0 < K; k0 += 64) {
    __syncthreads();
    {
      int row = tid >> 1, half = tid & 1;
      const unsigned short* asrc = A + (size_t)(m0 + row) * K + k0 + half * 32;
      #pragma unroll
      for (int q = 0; q < 4; ++q) {
        int chunk = half * 4 + q;
        *(u16x8*)&As[row * 64 + (chunk ^ (row & 7)) * 8] = *(const u16x8*)&asrc[q * 8];
      }
      int nrow = n0 + row;
      const unsigned short* bsrc = B + (size_t)nrow * K + k0 + half * 32;
      u16x8 z = {0, 0, 0, 0, 0, 0, 0, 0};
      #pragma unroll
      for (int q = 0; q < 4; ++q) {
        int chunk = half * 4 + q;
        u16x8 v = (nrow < N) ? *(const u16x8*)&bsrc[q * 8] : z;
        *(u16x8*)&Bs[row * 64 + (chunk ^ (row & 7)) * 8] = v;
      }
    }
    __syncthreads();
    #pragma unroll
    for (int u = 0; u < 2; ++u) {
      bf16x8 a[4], b[4];
      #pragma unroll
      for (int i = 0; i < 4; ++i) {
        int r = wm * 64 + i * 16 + lr;
        a[i] = *(const bf16x8*)&As[r * 64 + (((u * 4 + lg) ^ (r & 7))) * 8];
        int n = wn * 64 + i * 16 + lr;
        b[i] = *(const bf16x8*)&Bs[n * 64 + (((u * 4 + lg) ^ (n & 7))) * 8];
      }
      #pragma unroll
      for (int i = 0; i < 4; ++i)
        #pragma unroll
        for (int j = 0; j < 4; ++j)
          acc[i][j] = __builtin_amdgcn_mfma_f32_16x16x32_bf16(a[i], b[j], acc[i][j], 0, 0, 0);
    }
  }

  #pragma unroll
  for (int i = 0; i < 4; ++i) {
    int m = m0 + wm * 64 + i * 16 + lg * 4;
    #pragma unroll
    for (int j = 0; j < 4; ++j) {
      int n = n0 + wn * 64 + j * 16 + lr;
      if (n < N) {
        #pragma unroll
        for (int q = 0; q < 4; ++q)
          C[(size_t)(m + q) * N + n] = acc[i][j][q];
      }
    }
  }
}

// ---------------------------------------------------------------------------
extern "C" void kernel_launch(void* const* d_in, const int* in_sizes, int n_in,
                              void* d_out, int out_size, void* d_ws, size_t ws_size,
                              hipStream_t stream) {
  const float* ent_embeds = (const float*)d_in[0];
  const float* rel_embeds = (const float*)d_in[1];
  const float* W_msg  = (const float*)d_in[2];
  const float* W_self = (const float*)d_in[3];
  const float* gru_Wih = (const float*)d_in[4];
  const float* gru_Whh = (const float*)d_in[5];
  const float* gru_bih = (const float*)d_in[6];
  const float* gru_bhh = (const float*)d_in[7];
  const float* gate_W = (const float*)d_in[8];
  const float* gate_b = (const float*)d_in[9];
  const float* e_conv1 = (const float*)d_in[10]; const float* e_cb1 = (const float*)d_in[11];
  const float* e_fc1   = (const float*)d_in[12]; const float* e_fb1 = (const float*)d_in[13];
  const float* e_conv2 = (const float*)d_in[14]; const float* e_cb2 = (const float*)d_in[15];
  const float* e_fc2   = (const float*)d_in[16]; const float* e_fb2 = (const float*)d_in[17];
  const float* r_conv1 = (const float*)d_in[18]; const float* r_cb1 = (const float*)d_in[19];
  const float* r_fc1   = (const float*)d_in[20]; const float* r_fb1 = (const float*)d_in[21];
  const float* r_conv2 = (const float*)d_in[22]; const float* r_cb2 = (const float*)d_in[23];
  const float* r_fc2   = (const float*)d_in[24]; const float* r_fb2 = (const float*)d_in[25];
  const int* src  = (const int*)d_in[26];
  const int* dst  = (const int*)d_in[27];
  const int* erel = (const int*)d_in[28];
  const int* subj = (const int*)d_in[29];
  const int* rel  = (const int*)d_in[30];
  const int* obj  = (const int*)d_in[31];
  float* out = (float*)d_out;

  // -------- workspace layout (round-6 base + CSR ints) --------
  float* w = (float*)d_ws;
  float* ent   = w; w += (size_t)N_ENT * HD;
  float* relh  = w; w += (size_t)N_REL * HD;
  float* aggR  = w; w += (size_t)N_REL * HD;
  float* cntR  = w; w += N_REL;
  float* gi    = w; w += (size_t)N_REL * 1536;
  float* gh    = w; w += (size_t)N_REL * 1536;
  float* aggE  = w; w += (size_t)N_ENT * HD;     // } aggE..h1b reused post-loop as
  float* cntE  = w; w += N_ENT;                  // } packed-fw storage
  float* tmp   = w; w += (size_t)N_ENT * HD;
  float* h0b   = w; w += (size_t)N_ENT * HD;
  float* h1b   = w; w += (size_t)N_ENT * HD;
  float* se    = w; w += (size_t)NB * HD;
  float* re_   = w; w += (size_t)NB * HD;
  float* oe    = w; w += (size_t)NB * HD;
  float* o1    = w; w += (size_t)NB * HD;
  float* q1    = w; w += (size_t)NB * HD;
  float* o2    = w; w += (size_t)NB * HD;
  float* q2    = w; w += (size_t)NB * HD;
  unsigned short* ent_bf  = (unsigned short*)w; w += (size_t)N_ENT * HD / 2;
  unsigned short* relh_bf = (unsigned short*)w; w += (size_t)N_REL * HD / 2;
  unsigned short* rel_bf  = (unsigned short*)w; w += (size_t)N_REL * HD / 2;
  unsigned short* h0b_bf  = (unsigned short*)w; w += (size_t)N_ENT * HD / 2;
  unsigned short* h1b_bf  = (unsigned short*)w; w += (size_t)N_ENT * HD / 2;
  unsigned short* o1b = (unsigned short*)w; w += (size_t)NB * HD / 2;
  unsigned short* q1b = (unsigned short*)w; w += (size_t)NB * HD / 2;
  unsigned short* o2b = (unsigned short*)w; w += (size_t)NB * HD / 2;
  unsigned short* q2b = (unsigned short*)w; w += (size_t)NB * HD / 2;
  // recurrence weight packs (bf16)
  unsigned short* wp_ih = (unsigned short*)w;            // 1024x1536
  unsigned short* wp_hh = wp_ih + (size_t)1024 * 1536;   // 512x1536
  unsigned short* wp_l0 = wp_hh + (size_t)512 * 1536;    // 1024x512
  unsigned short* wp_l1 = wp_l0 + (size_t)1024 * 512;    // 1024x512
  unsigned short* wp_g  = wp_l1 + (size_t)1024 * 512;    // 512x512
  w += ((size_t)1024 * 1536 + 512 * 1536 + 2 * 1024 * 512 + 512 * 512) / 2;
  // CSR buffers (int)
  int* histD  = (int*)w;                 // 20000
  int* histR  = histD + N_ENT;           // 256 (contiguous: one zero kernel)
  int* partD  = histR + N_REL;           // 257
  int* startD = partD + 257;             // 20001
  int* posD   = startD + (N_ENT + 1);    // 20000
  int* startR = posD + N_ENT;            // 257
  int* posR   = startR + 257;            // 256
  int* edgeD  = posR + N_REL;            // 30000
  int* edgeR  = edgeD + NE;              // 30000
  // fw packs alias the recurrence temporaries (used only post-loop)
  unsigned short* fwp0 = (unsigned short*)aggE;
  unsigned short* fwp1 = fwp0 + (size_t)16777216;
  unsigned short* fwp2 = fwp1 + (size_t)16777216;
  unsigned short* fwp3 = fwp2 + (size_t)16777216;
  (void)tmp;
  // decoder scratch in d_out (written+consumed before logits):
  unsigned short* Abuf = (unsigned short*)out;          // 2 x NB x 32768 u16
  float* pE = out + (size_t)2 * NB * 32768 / 2;         // f32 offset after Abuf
  float* pR = pE + (size_t)4 * NB * HD;

  const dim3 g_gru(2, 12, 2);  // 256 x 1536, z = {gi, gh}
  const dim3 g_ent(157, 4);    // 20000 x 512

  // -------- weight packing (once) --------
  {
    int t;
    t = (1024 * 1536) / 8; pack_nn_kernel<<<(t + 255) / 256, 256, 0, stream>>>(gru_Wih, wp_ih, 1024, 1536);
    t = (512 * 1536) / 8;  pack_nn_kernel<<<(t + 255) / 256, 256, 0, stream>>>(gru_Whh, wp_hh, 512, 1536);
    t = (512 * 512) / 8;
    pack_nn_kernel<<<(t + 255) / 256, 256, 0, stream>>>(W_msg, wp_l0, 512, 512);
    pack_nn_kernel<<<(t + 255) / 256, 256, 0, stream>>>(W_self, wp_l0 + (size_t)512 * 512, 512, 512);
    pack_nn_kernel<<<(t + 255) / 256, 256, 0, stream>>>(W_msg + (size_t)512 * 512, wp_l1, 512, 512);
    pack_nn_kernel<<<(t + 255) / 256, 256, 0, stream>>>(W_self + (size_t)512 * 512, wp_l1 + (size_t)512 * 512, 512, 512);
    pack_nn_kernel<<<(t + 255) / 256, 256, 0, stream>>>(gate_W, wp_g, 512, 512);
  }

  // -------- init --------
  rownorm_kernel<<<N_ENT / 4, 256, 0, stream>>>(ent_embeds, ent, ent_bf, N_ENT);
  hipMemcpyAsync(relh, rel_embeds, (size_t)N_REL * HD * 4, hipMemcpyDeviceToDevice, stream);
  f2b_kernel<<<(N_REL * HD / 8) / 256, 256, 0, stream>>>(rel_embeds, rel_bf, N_REL * HD);
  f2b_kernel<<<(N_REL * HD / 8) / 256, 256, 0, stream>>>(rel_embeds, relh_bf, N_REL * HD);

  // -------- timestep loop --------
  for (int t = 0; t < NT; ++t) {
    const int* st = src + t * NE;
    const int* dt = dst + t * NE;
    const int* rt = erel + t * NE;

    // CSR build (shared by agg_rel + both layers)
    zero_hist_kernel<<<(N_ENT + N_REL + 255) / 256, 256, 0, stream>>>(histD);
    hist_kernel<<<(NE + 255) / 256, 256, 0, stream>>>(dt, rt, histD, histR);
    scan_part_kernel<<<1, 256, 0, stream>>>(histD, partD);
    scan_serial_kernel<<<1, 1, 0, stream>>>(partD, histR, startR, posR);
    scan_local_kernel<<<1, 256, 0, stream>>>(histD, partD, startD, posD);
    scatter_kernel<<<(NE + 255) / 256, 256, 0, stream>>>(dt, rt, posD, posR, edgeD, edgeR);

    // relation evolution
    agg_rel_csr<<<N_REL / 4, 256, 0, stream>>>(ent, st, edgeR, startR, aggR, cntR);
    gru_gemms<<<g_gru, 256, 0, stream>>>(aggR, cntR, rel_bf, relh_bf, wp_ih, wp_hh, gi, gh);
    gru_kernel<<<(N_REL * HD) / 256, 256, 0, stream>>>(gi, gh, gru_bih, gru_bhh, relh, relh_bf);

    // entity evolution: h = relu([mean-agg | h] @ [Wmsg;Wself]) per layer
    agg_ent_csr<<<N_ENT / 4, 256, 0, stream>>>(ent, relh, st, rt, edgeD, startD, aggE, cntE);
    gemm_nn2<1, 1><<<g_ent, 256, 0, stream>>>(aggE, 512, cntE, ent_bf, 512, wp_l0,
                                              nullptr, nullptr, h0b, h0b_bf, N_ENT, 512);
    agg_ent_csr<<<N_ENT / 4, 256, 0, stream>>>(h0b, relh, st, rt, edgeD, startD, aggE, cntE);
    gemm_nn2<1, 0><<<g_ent, 256, 0, stream>>>(aggE, 512, cntE, h0b_bf, 512, wp_l1,
                                              nullptr, nullptr, h1b, nullptr, N_ENT, 512);
    rownorm_kernel<<<N_ENT / 4, 256, 0, stream>>>(h1b, h1b, h1b_bf, N_ENT);
    gemm_nn2<3, 1><<<g_ent, 256, 0, stream>>>(nullptr, 0, nullptr, h1b_bf, 512, wp_g,
                                              gate_b, h1b, ent, ent_bf, N_ENT, 512);
  }

  // -------- decoder prep --------
  pack_fw_kernel<<<dim3(1024, 4), 256, 0, stream>>>(e_fc1, r_fc1, e_fc2, r_fc2,
                                                    fwp0, fwp1, fwp2, fwp3);
  gather_kernel<<<(NB * HD / 4) / 256, 256, 0, stream>>>(ent, subj, se, NB);
  gather_kernel<<<(NB * HD / 4) / 256, 256, 0, stream>>>(relh, rel, re_, NB);
  gather_kernel<<<(NB * HD / 4) / 256, 256, 0, stream>>>(ent, obj, oe, NB);

  unsigned short* A_E = Abuf;
  unsigned short* A_R = Abuf + (size_t)NB * 32768;

  // -------- decoder stage 1 --------
  convgen_kernel<2><<<dim3(NB / 4, 2), 256, 0, stream>>>(
      se, re_, nullptr, e_conv1, e_cb1,
      se, oe, nullptr, r_conv1, r_cb1, A_E, A_R);
  gemm_fc<<<dim3(32, 4, 8), 256, 0, stream>>>(Abuf, fwp0, fwp1, pE);
  reduce4_kernel<<<dim3(NB * HD / 4 / 256, 2), 256, 0, stream>>>(
      pE, pR, e_fb1, r_fb1, o1, q1, o1b, q1b);

  // -------- decoder stage 2 --------
  convgen_kernel<3><<<dim3(NB / 4, 2), 256, 0, stream>>>(
      o1, se, re_, e_conv2, e_cb2,
      q1, se, oe, r_conv2, r_cb2, A_E, A_R);
  gemm_fc<<<dim3(32, 4, 8), 256, 0, stream>>>(Abuf, fwp2, fwp3, pE);
  reduce4_kernel<<<dim3(NB * HD / 4 / 256, 2), 256, 0, stream>>>(
      pE, pR, e_fb2, r_fb2, o2, q2, o2b, q2b);

  // -------- logits (bf16 MFMA) --------
  size_t off0 = 0;
  size_t off1 = (size_t)NB * N_ENT;
  size_t off2 = off1 + (size_t)NB * N_REL;
  size_t off3 = off2 + (size_t)NB * N_ENT;
  gemm_nt_bf16<<<dim3(32, 157), 256, 0, stream>>>(o1b, ent_bf, out + off0, NB, N_ENT, HD);
  gemm_nt_bf16<<<dim3(32, 2), 256, 0, stream>>>(q1b, relh_bf, out + off1, NB, N_REL, HD);
  gemm_nt_bf16<<<dim3(32, 157), 256, 0, stream>>>(o2b, ent_bf, out + off2, NB, N_ENT, HD);
  gemm_nt_bf16<<<dim3(32, 2), 256, 0, stream>>>(q2b, relh_bf, out + off3, NB, N_REL, HD);
}

// Round 10
// 4641.774 us; speedup vs baseline: 1.1497x; 1.1497x over previous
//
#include <hip/hip_runtime.h>
#include <math.h>

// ---------------------------------------------------------------------------
// Refine (RE-GCN style): bf16-MFMA recurrence + decoder; f32 state with bf16
// mirrors. CSR segment-mean with ALL 8 timestep CSRs prebuilt before the loop
// (batched kernels). gemm_fc uses depth-2 register prefetch (static set
// selection via unroll-by-2).
// N_ENT=20000 N_REL=256 H=512 C=64 K=3 L=2 T=8 E=30000 B=4096
// ---------------------------------------------------------------------------

#define N_ENT 20000
#define N_REL 256
#define HD    512
#define NE    30000
#define NB    4096
#define NT    8

typedef __attribute__((ext_vector_type(8))) short          bf16x8;
typedef __attribute__((ext_vector_type(4))) float          f32x4;
typedef __attribute__((ext_vector_type(8))) unsigned short u16x8;
typedef __attribute__((ext_vector_type(4))) unsigned short u16x4;

static __device__ __forceinline__ float sigmoidf_(float x) {
  return 1.0f / (1.0f + expf(-x));
}
static __device__ __forceinline__ unsigned short f2bf(float f) {  // RNE
  unsigned u = __float_as_uint(f);
  return (unsigned short)((u + 0x7FFFu + ((u >> 16) & 1u)) >> 16);
}

// ---------------- row L2 normalize + bf16 mirror ---------------------------
__global__ void rownorm_kernel(const float* __restrict__ in, float* __restrict__ out,
                               unsigned short* __restrict__ outb, int rows) {
  int wid = (blockIdx.x * blockDim.x + threadIdx.x) >> 6;
  int lane = threadIdx.x & 63;
  if (wid >= rows) return;
  const float4* ip = (const float4*)(in + (size_t)wid * HD);
  float4 v0 = ip[lane];
  float4 v1 = ip[lane + 64];
  float s = v0.x * v0.x + v0.y * v0.y + v0.z * v0.z + v0.w * v0.w
          + v1.x * v1.x + v1.y * v1.y + v1.z * v1.z + v1.w * v1.w;
  #pragma unroll
  for (int m = 1; m < 64; m <<= 1) s += __shfl_xor(s, m);
  float inv = 1.0f / (sqrtf(s) + 1e-8f);
  float4* op = (float4*)(out + (size_t)wid * HD);
  v0.x *= inv; v0.y *= inv; v0.z *= inv; v0.w *= inv;
  v1.x *= inv; v1.y *= inv; v1.z *= inv; v1.w *= inv;
  op[lane] = v0; op[lane + 64] = v1;
  unsigned short* ob = outb + (size_t)wid * HD;
  u16x4 p0 = {f2bf(v0.x), f2bf(v0.y), f2bf(v0.z), f2bf(v0.w)};
  u16x4 p1 = {f2bf(v1.x), f2bf(v1.y), f2bf(v1.z), f2bf(v1.w)};
  *(u16x4*)&ob[lane * 4] = p0;
  *(u16x4*)&ob[(lane + 64) * 4] = p1;
}

// ---------------- batched CSR build (all 8 timesteps upfront) --------------
__global__ void zero_hist_all(int* __restrict__ h) {
  int i = blockIdx.x * 256 + threadIdx.x;
  if (i < NT * (N_ENT + N_REL)) h[i] = 0;
}

__global__ void hist_all(const int* __restrict__ dst, const int* __restrict__ rel,
                         int* __restrict__ histD8, int* __restrict__ histR8) {
  int e = blockIdx.x * 256 + threadIdx.x;
  int t = blockIdx.y;
  if (e >= NE) return;
  atomicAdd(&histD8[t * N_ENT + dst[t * NE + e]], 1);
  atomicAdd(&histR8[t * N_REL + rel[t * NE + e]], 1);
}

// per-thread chunk sums of histD[t] -> partD8[t][256]
__global__ void scan_part_all(const int* __restrict__ histD8, int* __restrict__ partD8) {
  int t = blockIdx.x, tid = threadIdx.x;
  const int* hd = histD8 + t * N_ENT;
  int base = tid * 80;                       // 256*80 >= 20000
  int s = 0;
  for (int i = 0; i < 80; ++i) {
    int idx = base + i;
    if (idx < N_ENT) s += hd[idx];
  }
  partD8[t * 257 + tid] = s;
}

// 1 thread per t: exclusive-scan partD (in place, [256]=total) and histR.
__global__ void scan_serial_all(int* __restrict__ partD8, const int* __restrict__ histR8,
                                int* __restrict__ startR8, int* __restrict__ posR8) {
  int t = blockIdx.x;
  int* pd = partD8 + t * 257;
  int run = 0;
  for (int i = 0; i < 256; ++i) { int v = pd[i]; pd[i] = run; run += v; }
  pd[256] = run;
  const int* hr = histR8 + t * N_REL;
  int* sr = startR8 + t * 257;
  int* pr = posR8 + t * N_REL;
  run = 0;
  for (int i = 0; i < 256; ++i) { int v = hr[i]; sr[i] = run; pr[i] = run; run += v; }
  sr[256] = run;
}

// per-thread local exclusive scan of its chunk -> startD/posD
__global__ void scan_local_all(const int* __restrict__ histD8, const int* __restrict__ partD8,
                               int* __restrict__ startD8, int* __restrict__ posD8) {
  int t = blockIdx.x, tid = threadIdx.x;
  const int* hd = histD8 + t * N_ENT;
  int* sd = startD8 + t * (N_ENT + 1);
  int* pd = posD8 + t * N_ENT;
  int run = partD8[t * 257 + tid];
  int base = tid * 80;
  for (int i = 0; i < 80; ++i) {
    int idx = base + i;
    if (idx < N_ENT) {
      sd[idx] = run;
      pd[idx] = run;
      run += hd[idx];
    }
  }
  if (tid == 0) sd[N_ENT] = partD8[t * 257 + 256];
}

__global__ void scatter_all(const int* __restrict__ dst, const int* __restrict__ rel,
                            int* __restrict__ posD8, int* __restrict__ posR8,
                            int* __restrict__ edgeD8, int* __restrict__ edgeR8) {
  int e = blockIdx.x * 256 + threadIdx.x;
  int t = blockIdx.y;
  if (e >= NE) return;
  int p = atomicAdd(&posD8[t * N_ENT + dst[t * NE + e]], 1);
  edgeD8[t * NE + p] = e;
  int p2 = atomicAdd(&posR8[t * N_REL + rel[t * NE + e]], 1);
  edgeR8[t * NE + p2] = e;
}

// ---------------- seg-sum via CSR: one wave per output row (f32) -----------
__global__ __launch_bounds__(256)
void agg_rel_csr(const float* __restrict__ ent, const int* __restrict__ src,
                 const int* __restrict__ edgeR, const int* __restrict__ startR,
                 float* __restrict__ aggR, float* __restrict__ cntR) {
  int r = blockIdx.x * 4 + (threadIdx.x >> 6);
  if (r >= N_REL) return;
  int lane = threadIdx.x & 63;
  int s0 = startR[r], s1 = startR[r + 1];
  float4 a = make_float4(0.f, 0.f, 0.f, 0.f);
  float4 b = make_float4(0.f, 0.f, 0.f, 0.f);
  for (int i = s0; i < s1; ++i) {
    int e = edgeR[i];
    int s = src[e];
    const float4* p = (const float4*)(ent + (size_t)s * HD);
    float4 x = p[lane];
    float4 y = p[lane + 64];
    a.x += x.x; a.y += x.y; a.z += x.z; a.w += x.w;
    b.x += y.x; b.y += y.y; b.z += y.z; b.w += y.w;
  }
  float4* op = (float4*)(aggR + (size_t)r * HD);
  op[lane] = a;
  op[lane + 64] = b;
  if (lane == 0) cntR[r] = (float)(s1 - s0);
}

__global__ __launch_bounds__(256)
void agg_ent_csr(const float* __restrict__ h, const float* __restrict__ relh,
                 const int* __restrict__ src, const int* __restrict__ erel,
                 const int* __restrict__ edgeD, const int* __restrict__ startD,
                 float* __restrict__ aggE, float* __restrict__ cntE) {
  int d = blockIdx.x * 4 + (threadIdx.x >> 6);
  if (d >= N_ENT) return;
  int lane = threadIdx.x & 63;
  int s0 = startD[d], s1 = startD[d + 1];
  float4 a = make_float4(0.f, 0.f, 0.f, 0.f);
  float4 b = make_float4(0.f, 0.f, 0.f, 0.f);
  for (int i = s0; i < s1; ++i) {
    int e = edgeD[i];
    int s = src[e], r = erel[e];
    const float4* hp = (const float4*)(h + (size_t)s * HD);
    const float4* rp = (const float4*)(relh + (size_t)r * HD);
    float4 x = hp[lane];
    float4 y = hp[lane + 64];
    float4 u = rp[lane];
    float4 v = rp[lane + 64];
    a.x += x.x + u.x; a.y += x.y + u.y; a.z += x.z + u.z; a.w += x.w + u.w;
    b.x += y.x + v.x; b.y += y.y + v.y; b.z += y.z + v.z; b.w += y.w + v.w;
  }
  float4* op = (float4*)(aggE + (size_t)d * HD);
  op[lane] = a;
  op[lane + 64] = b;
  if (lane == 0) cntE[d] = (float)(s1 - s0);
}

// ---------------- GRU elementwise (+bias fold, +bf16 mirror) ---------------
__global__ void gru_kernel(const float* __restrict__ gi, const float* __restrict__ gh,
                           const float* __restrict__ bih, const float* __restrict__ bhh,
                           float* __restrict__ relh, unsigned short* __restrict__ relhb) {
  int i = blockIdx.x * blockDim.x + threadIdx.x;
  if (i >= N_REL * HD) return;
  int row = i >> 9, col = i & 511;
  const float* gir = gi + (size_t)row * 1536;
  const float* ghr = gh + (size_t)row * 1536;
  float ir = gir[col] + bih[col];
  float iz = gir[col + 512] + bih[col + 512];
  float inn = gir[col + 1024] + bih[col + 1024];
  float hr = ghr[col] + bhh[col];
  float hz = ghr[col + 512] + bhh[col + 512];
  float hn = ghr[col + 1024] + bhh[col + 1024];
  float r = sigmoidf_(ir + hr);
  float z = sigmoidf_(iz + hz);
  float n = tanhf(inn + r * hn);
  float v = (1.0f - z) * n + z * relh[i];
  relh[i] = v;
  relhb[i] = f2bf(v);
}

// ---------------- gather rows (f32) ----------------------------------------
__global__ void gather_kernel(const float* __restrict__ table, const int* __restrict__ idx,
                              float* __restrict__ out, int rows) {
  int i = blockIdx.x * blockDim.x + threadIdx.x;
  if (i >= rows * (HD / 4)) return;
  int row = i >> 7, q = i & 127;
  ((float4*)out)[i] = ((const float4*)(table + (size_t)idx[row] * HD))[q];
}

// ---------------- flat f32 -> bf16 convert (n multiple of 8) ---------------
__global__ void f2b_kernel(const float* __restrict__ in, unsigned short* __restrict__ out, int n) {
  int i = blockIdx.x * blockDim.x + threadIdx.x;
  if (i * 8 >= n) return;
  float4 a = *(const float4*)&in[i * 8];
  float4 b = *(const float4*)&in[i * 8 + 4];
  u16x8 pk = {f2bf(a.x), f2bf(a.y), f2bf(a.z), f2bf(a.w),
              f2bf(b.x), f2bf(b.y), f2bf(b.z), f2bf(b.w)};
  *(u16x8*)&out[i * 8] = pk;
}

// ---------------------------------------------------------------------------
// pack_nn: B (KxN f32 row-major) -> bf16 LDS-image layout:
// step s (32 k): idx = (s*N + n)*32 + ((g ^ ((n>>2)&3))<<3) + j  holds
// B[s*32 + g*8 + j][n].
// ---------------------------------------------------------------------------
__global__ void pack_nn_kernel(const float* __restrict__ B, unsigned short* __restrict__ out,
                               int K, int N) {
  int id = blockIdx.x * 256 + threadIdx.x;
  if (id >= (K >> 3) * N) return;
  int s = id / (N * 4);
  int rem = id - s * (N * 4);
  int n = rem >> 2, g = rem & 3;
  const float* src = B + (size_t)(s * 32 + g * 8) * N + n;
  u16x8 pk;
  #pragma unroll
  for (int j = 0; j < 8; ++j) pk[j] = f2bf(src[(size_t)j * N]);
  *(u16x8*)&out[((size_t)s * N + n) * 32 + ((g ^ ((n >> 2) & 3)) << 3)] = pk;
}

// ---------------------------------------------------------------------------
// GEMM core (round-6 form): single-barrier double-buffered bf16 MFMA GEMM.
// A = [A0 (M x K0, f32, row-scaled by 1/max(cnt,1)) | A1 (M x K1, bf16)].
// ACT: 0 plain, 1 relu(+mirror), 3 gate: u=sigmoid(v+bias[n]); C=u*D+(1-u)*C.
// ---------------------------------------------------------------------------
template <int ACT, int MIRROR>
static __device__ __forceinline__
void gemm_core(const float* __restrict__ A0, int K0, const float* __restrict__ cntA,
               const unsigned short* __restrict__ A1, int K1,
               const unsigned short* __restrict__ Bp,
               const float* __restrict__ bias, const float* __restrict__ D,
               float* __restrict__ C, unsigned short* __restrict__ Cb,
               int M, int N, int m0, int n0,
               unsigned short (*As)[8192], unsigned short (*Bs)[8192]) {
  const int tid = threadIdx.x;
  const int lane = tid & 63;
  const int wv = tid >> 6;
  const int wm = wv >> 1, wn = wv & 1;
  const int lr = lane & 15, lg = lane >> 4;
  const int arow = tid >> 1;
  const int akh = (tid & 1) * 32;
  const int achunk = (tid & 1) * 4;
  const int NIT = (K0 + K1) >> 6;

  float s0 = 1.0f;
  if (K0 > 0 && (m0 + arow) < M) s0 = 1.0f / fmaxf(cntA[m0 + arow], 1.0f);

  f32x4 acc[4][4];
  #pragma unroll
  for (int i = 0; i < 4; ++i)
    #pragma unroll
    for (int j = 0; j < 4; ++j) acc[i][j] = (f32x4){0.f, 0.f, 0.f, 0.f};

  auto gload = [&](int it, u16x8* ar, u16x8* br) {
    int mrow = m0 + arow;
    int kk = it * 64 + akh;
    if (mrow < M) {
      if (kk < K0) {
        const float* p = A0 + (size_t)mrow * K0 + kk;
        #pragma unroll
        for (int q = 0; q < 4; ++q) {
          float4 x = *(const float4*)(p + q * 8);
          float4 y = *(const float4*)(p + q * 8 + 4);
          ar[q] = (u16x8){f2bf(x.x * s0), f2bf(x.y * s0), f2bf(x.z * s0), f2bf(x.w * s0),
                          f2bf(y.x * s0), f2bf(y.y * s0), f2bf(y.z * s0), f2bf(y.w * s0)};
        }
      } else {
        const unsigned short* p = A1 + (size_t)mrow * K1 + (kk - K0);
        #pragma unroll
        for (int q = 0; q < 4; ++q) ar[q] = *(const u16x8*)&p[q * 8];
      }
    } else {
      #pragma unroll
      for (int q = 0; q < 4; ++q) ar[q] = (u16x8){0, 0, 0, 0, 0, 0, 0, 0};
    }
    const unsigned short* b0 = Bp + ((size_t)(2 * it) * N + n0) * 32;
    const unsigned short* b1 = Bp + ((size_t)(2 * it + 1) * N + n0) * 32;
    br[0] = *(const u16x8*)&b0[tid * 8];
    br[1] = *(const u16x8*)&b0[2048 + tid * 8];
    br[2] = *(const u16x8*)&b1[tid * 8];
    br[3] = *(const u16x8*)&b1[2048 + tid * 8];
  };
  auto swrite = [&](int nb, const u16x8* ar, const u16x8* br) {
    #pragma unroll
    for (int q = 0; q < 4; ++q) {
      int chunk = achunk + q;
      *(u16x8*)&As[nb][arow * 64 + ((chunk ^ (arow & 7)) << 3)] = ar[q];
    }
    *(u16x8*)&Bs[nb][tid * 8] = br[0];
    *(u16x8*)&Bs[nb][2048 + tid * 8] = br[1];
    *(u16x8*)&Bs[nb][4096 + tid * 8] = br[2];
    *(u16x8*)&Bs[nb][4096 + 2048 + tid * 8] = br[3];
  };

  {
    u16x8 ar[4], br[4];
    gload(0, ar, br);
    swrite(0, ar, br);
  }
  __syncthreads();

  int cur = 0;
  for (int it = 0; it < NIT; ++it) {
    u16x8 ar[4], br[4];
    if (it + 1 < NIT) gload(it + 1, ar, br);
    bf16x8 af[2][4], bfr[2][4];
    #pragma unroll
    for (int u = 0; u < 2; ++u)
      #pragma unroll
      for (int i = 0; i < 4; ++i) {
        int r = wm * 64 + i * 16 + lr;
        af[u][i] = *(const bf16x8*)&As[cur][r * 64 + (((u * 4 + lg) ^ (r & 7)) << 3)];
        int nl = wn * 64 + i * 16 + lr;
        bfr[u][i] = *(const bf16x8*)&Bs[cur][u * 4096 + nl * 32 + ((lg ^ ((nl >> 2) & 3)) << 3)];
      }
    #pragma unroll
    for (int u = 0; u < 2; ++u)
      #pragma unroll
      for (int i = 0; i < 4; ++i)
        #pragma unroll
        for (int j = 0; j < 4; ++j)
          acc[i][j] = __builtin_amdgcn_mfma_f32_16x16x32_bf16(af[u][i], bfr[u][j], acc[i][j], 0, 0, 0);
    if (it + 1 < NIT) swrite(cur ^ 1, ar, br);
    __syncthreads();
    cur ^= 1;
  }

  #pragma unroll
  for (int i = 0; i < 4; ++i) {
    int m = m0 + wm * 64 + i * 16 + lg * 4;
    #pragma unroll
    for (int j = 0; j < 4; ++j) {
      int n = n0 + wn * 64 + j * 16 + lr;
      #pragma unroll
      for (int q = 0; q < 4; ++q) {
        int mr = m + q;
        if (mr >= M) continue;
        size_t o = (size_t)mr * N + n;
        float v = acc[i][j][q];
        if (ACT == 0) {
          C[o] = v;
        } else if (ACT == 1) {
          float rr = fmaxf(v, 0.0f);
          C[o] = rr;
          if (MIRROR) Cb[o] = f2bf(rr);
        } else {
          float u_ = sigmoidf_(v + bias[n]);
          float rr = u_ * D[o] + (1.0f - u_) * C[o];
          C[o] = rr;
          if (MIRROR) Cb[o] = f2bf(rr);
        }
      }
    }
  }
}

template <int ACT, int MIRROR>
__global__ __launch_bounds__(256, 2)
void gemm_nn2(const float* __restrict__ A0, int K0, const float* __restrict__ cntA,
              const unsigned short* __restrict__ A1, int K1,
              const unsigned short* __restrict__ Bp,
              const float* __restrict__ bias, const float* __restrict__ D,
              float* __restrict__ C, unsigned short* __restrict__ Cb, int M, int N) {
  __shared__ unsigned short As[2][8192];
  __shared__ unsigned short Bs[2][8192];
  gemm_core<ACT, MIRROR>(A0, K0, cntA, A1, K1, Bp, bias, D, C, Cb, M, N,
                         blockIdx.x * 128, blockIdx.y * 128, As, Bs);
}

// Fused GRU GEMMs: z=0 -> gi = [aggR/cnt | rel_bf] @ wp_ih; z=1 -> gh = relh_bf @ wp_hh
__global__ __launch_bounds__(256, 2)
void gru_gemms(const float* __restrict__ aggR, const float* __restrict__ cntR,
               const unsigned short* __restrict__ rel_bf,
               const unsigned short* __restrict__ relh_bf,
               const unsigned short* __restrict__ wp_ih,
               const unsigned short* __restrict__ wp_hh,
               float* __restrict__ gi, float* __restrict__ gh) {
  __shared__ unsigned short As[2][8192];
  __shared__ unsigned short Bs[2][8192];
  if (blockIdx.z == 0)
    gemm_core<0, 0>(aggR, 512, cntR, rel_bf, 512, wp_ih, nullptr, nullptr,
                    gi, nullptr, N_REL, 1536, blockIdx.x * 128, blockIdx.y * 128, As, Bs);
  else
    gemm_core<0, 0>(nullptr, 0, nullptr, relh_bf, 512, wp_hh, nullptr, nullptr,
                    gh, nullptr, N_REL, 1536, blockIdx.x * 128, blockIdx.y * 128, As, Bs);
}

// ---------------------------------------------------------------------------
// pack_fw: fw (32768x512 f32) -> bf16 image (same layout as pack_nn, N=512)
// ---------------------------------------------------------------------------
__global__ __launch_bounds__(256)
void pack_fw_kernel(const float* __restrict__ f0, const float* __restrict__ f1,
                    const float* __restrict__ f2, const float* __restrict__ f3,
                    unsigned short* __restrict__ o0, unsigned short* __restrict__ o1,
                    unsigned short* __restrict__ o2, unsigned short* __restrict__ o3) {
  __shared__ float L[32][512];
  const float* fw; unsigned short* op;
  switch (blockIdx.y) {
    case 0: fw = f0; op = o0; break;
    case 1: fw = f1; op = o1; break;
    case 2: fw = f2; op = o2; break;
    default: fw = f3; op = o3; break;
  }
  int s = blockIdx.x, tid = threadIdx.x;
  #pragma unroll
  for (int i = 0; i < 16; ++i) {
    int idx = tid + 256 * i;
    int r = idx >> 7, cq = (idx & 127) << 2;
    *(float4*)&L[r][cq] = *(const float4*)&fw[(size_t)(s * 32 + r) * 512 + cq];
  }
  __syncthreads();
  #pragma unroll
  for (int ii = 0; ii < 8; ++ii) {
    int slot = tid + 256 * ii;
    int n = slot >> 2, g = slot & 3;
    u16x8 pk;
    #pragma unroll
    for (int j = 0; j < 8; ++j) pk[j] = f2bf(L[g * 8 + j][n]);
    size_t off = (size_t)s * 16384 + n * 32 + ((g ^ ((n >> 2) & 3)) << 3);
    *(u16x8*)&op[off] = pk;
  }
}

// ---------------------------------------------------------------------------
// convgen: conv1d('SAME',K=3)+relu -> A_conv bf16 [NB][c*512+h], both paths.
// ---------------------------------------------------------------------------
template <int CIN>
__global__ __launch_bounds__(256)
void convgen_kernel(const float* __restrict__ X0e, const float* __restrict__ X1e,
                    const float* __restrict__ X2e,
                    const float* __restrict__ cwE, const float* __restrict__ cbE,
                    const float* __restrict__ X0r, const float* __restrict__ X1r,
                    const float* __restrict__ X2r,
                    const float* __restrict__ cwR, const float* __restrict__ cbR,
                    unsigned short* __restrict__ Ae, unsigned short* __restrict__ Ar) {
  __shared__ float wsm[64 * CIN * 3];
  __shared__ float bsm[64];
  const int path = blockIdx.y;
  const float* X[CIN]; const float* cw; const float* cb; unsigned short* A;
  if (path == 0) {
    X[0] = X0e; X[1] = X1e; if constexpr (CIN == 3) X[2] = X2e;
    cw = cwE; cb = cbE; A = Ae;
  } else {
    X[0] = X0r; X[1] = X1r; if constexpr (CIN == 3) X[2] = X2r;
    cw = cwR; cb = cbR; A = Ar;
  }
  const int tid = threadIdx.x;
  for (int i = tid; i < 64 * CIN * 3; i += 256) wsm[i] = cw[i];
  if (tid < 64) bsm[tid] = cb[tid];
  __syncthreads();

  const int o = tid & 63;
  const int b = blockIdx.x * 4 + (tid >> 6);
  const int h = o * 8;

  float xm[CIN][8], xl[CIN], xr[CIN];
  #pragma unroll
  for (int ci = 0; ci < CIN; ++ci) {
    const float* row = X[ci] + (size_t)b * HD + h;
    float4 a4 = *(const float4*)row;
    float4 b4 = *(const float4*)(row + 4);
    xm[ci][0] = a4.x; xm[ci][1] = a4.y; xm[ci][2] = a4.z; xm[ci][3] = a4.w;
    xm[ci][4] = b4.x; xm[ci][5] = b4.y; xm[ci][6] = b4.z; xm[ci][7] = b4.w;
    xl[ci] = (h > 0) ? row[-1] : 0.f;
    xr[ci] = (h + 8 < HD) ? row[8] : 0.f;
  }
  unsigned short* dst = A + (size_t)b * 32768 + h;
  for (int c = 0; c < 64; ++c) {
    float v[8];
    float cbv = bsm[c];
    #pragma unroll
    for (int e = 0; e < 8; ++e) v[e] = cbv;
    #pragma unroll
    for (int ci = 0; ci < CIN; ++ci) {
      float w0 = wsm[(c * CIN + ci) * 3 + 0];
      float w1 = wsm[(c * CIN + ci) * 3 + 1];
      float w2 = wsm[(c * CIN + ci) * 3 + 2];
      #pragma unroll
      for (int e = 0; e < 8; ++e) {
        float lft = e ? xm[ci][e - 1] : xl[ci];
        float rgt = (e < 7) ? xm[ci][e + 1] : xr[ci];
        v[e] = fmaf(lft, w0, fmaf(xm[ci][e], w1, fmaf(rgt, w2, v[e])));
      }
    }
    u16x8 pk;
    #pragma unroll
    for (int e = 0; e < 8; ++e) pk[e] = f2bf(fmaxf(v[e], 0.f));
    *(u16x8*)&dst[c * 512] = pk;
  }
}

// ---------------------------------------------------------------------------
// gemm_fc: part[path][ks] = A_conv(4096 x 32768 bf16) @ fw-image, KSPLIT=4.
// Depth-2 register prefetch: two alternating reg sets, loop unrolled by 2 so
// set selection is static. Load-to-consume distance ~1.7 phases.
// ---------------------------------------------------------------------------
__global__ __launch_bounds__(256, 2)
void gemm_fc(const unsigned short* __restrict__ Abuf,
             const unsigned short* __restrict__ fwpE,
             const unsigned short* __restrict__ fwpR,
             float* __restrict__ partBase) {
  __shared__ unsigned short As[2][128 * 64];
  __shared__ unsigned short Bs[2][2 * 128 * 32];
  const int tid = threadIdx.x;
  const int lane = tid & 63;
  const int wv = tid >> 6;
  const int wm = wv >> 1, wn = wv & 1;
  const int lr = lane & 15, lg = lane >> 4;
  const int m0 = blockIdx.x * 128;
  const int n0 = blockIdx.y * 128;
  const int path = blockIdx.z >> 2;
  const int ks = blockIdx.z & 3;

  const unsigned short* A = Abuf + (size_t)path * ((size_t)NB * 32768);
  const unsigned short* fwp = (path == 0) ? fwpE : fwpR;
  float* part = partBase + (size_t)(path * 4 + ks) * ((size_t)NB * HD);

  const int arow = tid >> 1;
  const int achunk = (tid & 1) * 4;
  const unsigned short* aRow = A + (size_t)(m0 + arow) * 32768 + ks * 8192 + achunk * 8;
  const unsigned short* bBase = fwp + (size_t)(ks * 256) * 16384 + (size_t)n0 * 32;

  f32x4 acc[4][4];
  #pragma unroll
  for (int i = 0; i < 4; ++i)
    #pragma unroll
    for (int j = 0; j < 4; ++j) acc[i][j] = (f32x4){0.f, 0.f, 0.f, 0.f};

  auto gload = [&](int it, u16x8* ar, u16x8* br) {
    const unsigned short* ap = aRow + it * 64;
    #pragma unroll
    for (int q = 0; q < 4; ++q) ar[q] = *(const u16x8*)&ap[q * 8];
    const unsigned short* bp = bBase + (size_t)it * 2 * 16384;
    br[0] = *(const u16x8*)&bp[tid * 8];
    br[1] = *(const u16x8*)&bp[2048 + tid * 8];
    br[2] = *(const u16x8*)&bp[16384 + tid * 8];
    br[3] = *(const u16x8*)&bp[16384 + 2048 + tid * 8];
  };
  auto swrite = [&](int nb, const u16x8* ar, const u16x8* br) {
    #pragma unroll
    for (int q = 0; q < 4; ++q) {
      int chunk = achunk + q;
      *(u16x8*)&As[nb][arow * 64 + ((chunk ^ (arow & 7)) << 3)] = ar[q];
    }
    *(u16x8*)&Bs[nb][tid * 8] = br[0];
    *(u16x8*)&Bs[nb][2048 + tid * 8] = br[1];
    *(u16x8*)&Bs[nb][4096 + tid * 8] = br[2];
    *(u16x8*)&Bs[nb][4096 + 2048 + tid * 8] = br[3];
  };
  auto mfma_phase = [&](int nb) {
    bf16x8 af[2][4], bfr[2][4];
    #pragma unroll
    for (int u = 0; u < 2; ++u)
      #pragma unroll
      for (int i = 0; i < 4; ++i) {
        int r = wm * 64 + i * 16 + lr;
        af[u][i] = *(const bf16x8*)&As[nb][r * 64 + (((u * 4 + lg) ^ (r & 7)) << 3)];
        int nl = wn * 64 + i * 16 + lr;
        bfr[u][i] = *(const bf16x8*)&Bs[nb][u * 4096 + nl * 32 + ((lg ^ ((nl >> 2) & 3)) << 3)];
      }
    #pragma unroll
    for (int u = 0; u < 2; ++u)
      #pragma unroll
      for (int i = 0; i < 4; ++i)
        #pragma unroll
        for (int j = 0; j < 4; ++j)
          acc[i][j] = __builtin_amdgcn_mfma_f32_16x16x32_bf16(af[u][i], bfr[u][j], acc[i][j], 0, 0, 0);
  };

  // Reg set S0 holds data for even iterations, S1 for odd (statically indexed).
  u16x8 ar0[4], br0[4], ar1[4], br1[4];
  gload(0, ar0, br0);
  swrite(0, ar0, br0);
  gload(1, ar1, br1);      // data for it=1
  __syncthreads();

  int cur = 0;
  for (int itp = 0; itp < 128; itp += 2) {
    // even iteration it = itp
    if (itp + 2 < 128) gload(itp + 2, ar0, br0);     // data for itp+2 (even)
    mfma_phase(cur);
    swrite(cur ^ 1, ar1, br1);                       // data for itp+1 (odd, always exists)
    __syncthreads();
    cur ^= 1;
    // odd iteration it = itp+1
    if (itp + 3 < 128) gload(itp + 3, ar1, br1);     // data for itp+3 (odd)
    mfma_phase(cur);
    if (itp + 2 < 128) swrite(cur ^ 1, ar0, br0);    // data for itp+2 (even)
    __syncthreads();
    cur ^= 1;
  }

  #pragma unroll
  for (int i = 0; i < 4; ++i) {
    int m = m0 + wm * 64 + i * 16 + lg * 4;
    #pragma unroll
    for (int j = 0; j < 4; ++j) {
      int n = n0 + wn * 64 + j * 16 + lr;
      #pragma unroll
      for (int q = 0; q < 4; ++q)
        part[(size_t)(m + q) * HD + n] = acc[i][j][q];
    }
  }
}

// ---------------------------------------------------------------------------
// reduce 4 split-K partials + bias + relu -> f32 out AND bf16 out
// ---------------------------------------------------------------------------
__global__ void reduce4_kernel(const float* __restrict__ pE, const float* __restrict__ pR,
                               const float* __restrict__ bE, const float* __restrict__ bR,
                               float* __restrict__ oE, float* __restrict__ oR,
                               unsigned short* __restrict__ obE, unsigned short* __restrict__ obR) {
  int p = blockIdx.y;
  const float* part = p ? pR : pE;
  const float* bias = p ? bR : bE;
  float* o = p ? oR : oE;
  unsigned short* ob = p ? obR : obE;
  int i = blockIdx.x * 256 + threadIdx.x;
  int col = (i << 2) & 511;
  float4 s = *(const float4*)&part[(size_t)i * 4];
  #pragma unroll
  for (int ks = 1; ks < 4; ++ks) {
    float4 t = *(const float4*)&part[(size_t)ks * (NB * HD) + i * 4];
    s.x += t.x; s.y += t.y; s.z += t.z; s.w += t.w;
  }
  float4 b4 = *(const float4*)&bias[col];
  s.x = fmaxf(s.x + b4.x, 0.f); s.y = fmaxf(s.y + b4.y, 0.f);
  s.z = fmaxf(s.z + b4.z, 0.f); s.w = fmaxf(s.w + b4.w, 0.f);
  *(float4*)&o[(size_t)i * 4] = s;
  u16x4 pk = {f2bf(s.x), f2bf(s.y), f2bf(s.z), f2bf(s.w)};
  *(u16x4*)&ob[(size_t)i * 4] = pk;
}

// ---------------------------------------------------------------------------
// bf16 NT GEMM: C(MxN, f32) = A(MxK) @ B(NxK)^T, both bf16 row-major.
// ---------------------------------------------------------------------------
__global__ __launch_bounds__(256, 3)
void gemm_nt_bf16(const unsigned short* __restrict__ A, const unsigned short* __restrict__ B,
                  float* __restrict__ C, int M, int N, int K) {
  __shared__ unsigned short As[128 * 64];
  __shared__ unsigned short Bs[128 * 64];
  const int tid = threadIdx.x;
  const int lane = tid & 63;
  const int w = tid >> 6;
  const int wm = w >> 1, wn = w & 1;
  const int m0 = blockIdx.x * 128, n0 = blockIdx.y * 128;
  const int lr = lane & 15, lg = lane >> 4;

  f32x4 acc[4][4];
  #pragma unroll
  for (int i = 0; i < 4; ++i)
    #pragma unroll
    for (int j = 0; j < 4; ++j) acc[i][j] = (f32x4){0.f, 0.f, 0.f, 0.f};

  for (int k0 = 0; k0 < K; k0 += 64) {
    __syncthreads();
    {
      int row = tid >> 1, half = tid & 1;
      const unsigned short* asrc = A + (size_t)(m0 + row) * K + k0 + half * 32;
      #pragma unroll
      for (int q = 0; q < 4; ++q) {
        int chunk = half * 4 + q;
        *(u16x8*)&As[row * 64 + (chunk ^ (row & 7)) * 8] = *(const u16x8*)&asrc[q * 8];
      }
      int nrow = n0 + row;
      const unsigned short* bsrc = B + (size_t)nrow * K + k0 + half * 32;
      u16x8 z = {0, 0, 0, 0, 0, 0, 0, 0};
      #pragma unroll
      for (int q = 0; q < 4; ++q) {
        int chunk = half * 4 + q;
        u16x8 v = (nrow < N) ? *(const u16x8*)&bsrc[q * 8] : z;
        *(u16x8*)&Bs[row * 64 + (chunk ^ (row & 7)) * 8] = v;
      }
    }
    __syncthreads();
    #pragma unroll
    for (int u = 0; u < 2; ++u) {
      bf16x8 a[4], b[4];
      #pragma unroll
      for (int i = 0; i < 4; ++i) {
        int r = wm * 64 + i * 16 + lr;
        a[i] = *(const bf16x8*)&As[r * 64 + (((u * 4 + lg) ^ (r & 7))) * 8];
        int n = wn * 64 + i * 16 + lr;
        b[i] = *(const bf16x8*)&Bs[n * 64 + (((u * 4 + lg) ^ (n & 7))) * 8];
      }
      #pragma unroll
      for (int i = 0; i < 4; ++i)
        #pragma unroll
        for (int j = 0; j < 4; ++j)
          acc[i][j] = __builtin_amdgcn_mfma_f32_16x16x32_bf16(a[i], b[j], acc[i][j], 0, 0, 0);
    }
  }

  #pragma unroll
  for (int i = 0; i < 4; ++i) {
    int m = m0 + wm * 64 + i * 16 + lg * 4;
    #pragma unroll
    for (int j = 0; j < 4; ++j) {
      int n = n0 + wn * 64 + j * 16 + lr;
      if (n < N) {
        #pragma unroll
        for (int q = 0; q < 4; ++q)
          C[(size_t)(m + q) * N + n] = acc[i][j][q];
      }
    }
  }
}

// ---------------------------------------------------------------------------
extern "C" void kernel_launch(void* const* d_in, const int* in_sizes, int n_in,
                              void* d_out, int out_size, void* d_ws, size_t ws_size,
                              hipStream_t stream) {
  const float* ent_embeds = (const float*)d_in[0];
  const float* rel_embeds = (const float*)d_in[1];
  const float* W_msg  = (const float*)d_in[2];
  const float* W_self = (const float*)d_in[3];
  const float* gru_Wih = (const float*)d_in[4];
  const float* gru_Whh = (const float*)d_in[5];
  const float* gru_bih = (const float*)d_in[6];
  const float* gru_bhh = (const float*)d_in[7];
  const float* gate_W = (const float*)d_in[8];
  const float* gate_b = (const float*)d_in[9];
  const float* e_conv1 = (const float*)d_in[10]; const float* e_cb1 = (const float*)d_in[11];
  const float* e_fc1   = (const float*)d_in[12]; const float* e_fb1 = (const float*)d_in[13];
  const float* e_conv2 = (const float*)d_in[14]; const float* e_cb2 = (const float*)d_in[15];
  const float* e_fc2   = (const float*)d_in[16]; const float* e_fb2 = (const float*)d_in[17];
  const float* r_conv1 = (const float*)d_in[18]; const float* r_cb1 = (const float*)d_in[19];
  const float* r_fc1   = (const float*)d_in[20]; const float* r_fb1 = (const float*)d_in[21];
  const float* r_conv2 = (const float*)d_in[22]; const float* r_cb2 = (const float*)d_in[23];
  const float* r_fc2   = (const float*)d_in[24]; const float* r_fb2 = (const float*)d_in[25];
  const int* src  = (const int*)d_in[26];
  const int* dst  = (const int*)d_in[27];
  const int* erel = (const int*)d_in[28];
  const int* subj = (const int*)d_in[29];
  const int* rel  = (const int*)d_in[30];
  const int* obj  = (const int*)d_in[31];
  float* out = (float*)d_out;

  // -------- workspace layout --------
  float* w = (float*)d_ws;
  float* ent   = w; w += (size_t)N_ENT * HD;
  float* relh  = w; w += (size_t)N_REL * HD;
  float* aggR  = w; w += (size_t)N_REL * HD;
  float* cntR  = w; w += N_REL;
  float* gi    = w; w += (size_t)N_REL * 1536;
  float* gh    = w; w += (size_t)N_REL * 1536;
  float* aggE  = w; w += (size_t)N_ENT * HD;     // } aggE..h1b reused post-loop as
  float* cntE  = w; w += N_ENT;                  // } packed-fw storage
  float* tmp   = w; w += (size_t)N_ENT * HD;
  float* h0b   = w; w += (size_t)N_ENT * HD;
  float* h1b   = w; w += (size_t)N_ENT * HD;
  float* se    = w; w += (size_t)NB * HD;
  float* re_   = w; w += (size_t)NB * HD;
  float* oe    = w; w += (size_t)NB * HD;
  float* o1    = w; w += (size_t)NB * HD;
  float* q1    = w; w += (size_t)NB * HD;
  float* o2    = w; w += (size_t)NB * HD;
  float* q2    = w; w += (size_t)NB * HD;
  unsigned short* ent_bf  = (unsigned short*)w; w += (size_t)N_ENT * HD / 2;
  unsigned short* relh_bf = (unsigned short*)w; w += (size_t)N_REL * HD / 2;
  unsigned short* rel_bf  = (unsigned short*)w; w += (size_t)N_REL * HD / 2;
  unsigned short* h0b_bf  = (unsigned short*)w; w += (size_t)N_ENT * HD / 2;
  unsigned short* h1b_bf  = (unsigned short*)w; w += (size_t)N_ENT * HD / 2;
  unsigned short* o1b = (unsigned short*)w; w += (size_t)NB * HD / 2;
  unsigned short* q1b = (unsigned short*)w; w += (size_t)NB * HD / 2;
  unsigned short* o2b = (unsigned short*)w; w += (size_t)NB * HD / 2;
  unsigned short* q2b = (unsigned short*)w; w += (size_t)NB * HD / 2;
  // recurrence weight packs (bf16)
  unsigned short* wp_ih = (unsigned short*)w;            // 1024x1536
  unsigned short* wp_hh = wp_ih + (size_t)1024 * 1536;   // 512x1536
  unsigned short* wp_l0 = wp_hh + (size_t)512 * 1536;    // 1024x512
  unsigned short* wp_l1 = wp_l0 + (size_t)1024 * 512;    // 1024x512
  unsigned short* wp_g  = wp_l1 + (size_t)1024 * 512;    // 512x512
  w += ((size_t)1024 * 1536 + 512 * 1536 + 2 * 1024 * 512 + 512 * 512) / 2;
  // batched CSR buffers (int), all 8 timesteps
  int* histD8  = (int*)w;                       // 8 x 20000
  int* histR8  = histD8 + (size_t)NT * N_ENT;   // 8 x 256 (contiguous for zeroing)
  int* partD8  = histR8 + (size_t)NT * N_REL;   // 8 x 257
  int* startD8 = partD8 + (size_t)NT * 257;     // 8 x 20001
  int* posD8   = startD8 + (size_t)NT * (N_ENT + 1);  // 8 x 20000
  int* startR8 = posD8 + (size_t)NT * N_ENT;    // 8 x 257
  int* posR8   = startR8 + (size_t)NT * 257;    // 8 x 256
  int* edgeD8  = posR8 + (size_t)NT * N_REL;    // 8 x 30000
  int* edgeR8  = edgeD8 + (size_t)NT * NE;      // 8 x 30000
  // fw packs alias the recurrence temporaries (used only post-loop)
  unsigned short* fwp0 = (unsigned short*)aggE;
  unsigned short* fwp1 = fwp0 + (size_t)16777216;
  unsigned short* fwp2 = fwp1 + (size_t)16777216;
  unsigned short* fwp3 = fwp2 + (size_t)16777216;
  (void)tmp;
  // decoder scratch in d_out (written+consumed before logits):
  unsigned short* Abuf = (unsigned short*)out;          // 2 x NB x 32768 u16
  float* pE = out + (size_t)2 * NB * 32768 / 2;         // f32 offset after Abuf
  float* pR = pE + (size_t)4 * NB * HD;

  const dim3 g_gru(2, 12, 2);  // 256 x 1536, z = {gi, gh}
  const dim3 g_ent(157, 4);    // 20000 x 512

  // -------- weight packing (once) --------
  {
    int t;
    t = (1024 * 1536) / 8; pack_nn_kernel<<<(t + 255) / 256, 256, 0, stream>>>(gru_Wih, wp_ih, 1024, 1536);
    t = (512 * 1536) / 8;  pack_nn_kernel<<<(t + 255) / 256, 256, 0, stream>>>(gru_Whh, wp_hh, 512, 1536);
    t = (512 * 512) / 8;
    pack_nn_kernel<<<(t + 255) / 256, 256, 0, stream>>>(W_msg, wp_l0, 512, 512);
    pack_nn_kernel<<<(t + 255) / 256, 256, 0, stream>>>(W_self, wp_l0 + (size_t)512 * 512, 512, 512);
    pack_nn_kernel<<<(t + 255) / 256, 256, 0, stream>>>(W_msg + (size_t)512 * 512, wp_l1, 512, 512);
    pack_nn_kernel<<<(t + 255) / 256, 256, 0, stream>>>(W_self + (size_t)512 * 512, wp_l1 + (size_t)512 * 512, 512, 512);
    pack_nn_kernel<<<(t + 255) / 256, 256, 0, stream>>>(gate_W, wp_g, 512, 512);
  }

  // -------- batched CSR build for all 8 timesteps (independent of state) ----
  zero_hist_all<<<(NT * (N_ENT + N_REL) + 255) / 256, 256, 0, stream>>>(histD8);
  hist_all<<<dim3((NE + 255) / 256, NT), 256, 0, stream>>>(dst, erel, histD8, histR8);
  scan_part_all<<<NT, 256, 0, stream>>>(histD8, partD8);
  scan_serial_all<<<NT, 1, 0, stream>>>(partD8, histR8, startR8, posR8);
  scan_local_all<<<NT, 256, 0, stream>>>(histD8, partD8, startD8, posD8);
  scatter_all<<<dim3((NE + 255) / 256, NT), 256, 0, stream>>>(dst, erel, posD8, posR8,
                                                              edgeD8, edgeR8);

  // -------- init --------
  rownorm_kernel<<<N_ENT / 4, 256, 0, stream>>>(ent_embeds, ent, ent_bf, N_ENT);
  hipMemcpyAsync(relh, rel_embeds, (size_t)N_REL * HD * 4, hipMemcpyDeviceToDevice, stream);
  f2b_kernel<<<(N_REL * HD / 8) / 256, 256, 0, stream>>>(rel_embeds, rel_bf, N_REL * HD);
  f2b_kernel<<<(N_REL * HD / 8) / 256, 256, 0, stream>>>(rel_embeds, relh_bf, N_REL * HD);

  // -------- timestep loop --------
  for (int t = 0; t < NT; ++t) {
    const int* st = src + t * NE;
    const int* rt = erel + t * NE;
    const int* edgeD = edgeD8 + (size_t)t * NE;
    const int* edgeR = edgeR8 + (size_t)t * NE;
    const int* startD = startD8 + (size_t)t * (N_ENT + 1);
    const int* startR = startR8 + (size_t)t * 257;

    // relation evolution
    agg_rel_csr<<<N_REL / 4, 256, 0, stream>>>(ent, st, edgeR, startR, aggR, cntR);
    gru_gemms<<<g_gru, 256, 0, stream>>>(aggR, cntR, rel_bf, relh_bf, wp_ih, wp_hh, gi, gh);
    gru_kernel<<<(N_REL * HD) / 256, 256, 0, stream>>>(gi, gh, gru_bih, gru_bhh, relh, relh_bf);

    // entity evolution: h = relu([mean-agg | h] @ [Wmsg;Wself]) per layer
    agg_ent_csr<<<N_ENT / 4, 256, 0, stream>>>(ent, relh, st, rt, edgeD, startD, aggE, cntE);
    gemm_nn2<1, 1><<<g_ent, 256, 0, stream>>>(aggE, 512, cntE, ent_bf, 512, wp_l0,
                                              nullptr, nullptr, h0b, h0b_bf, N_ENT, 512);
    agg_ent_csr<<<N_ENT / 4, 256, 0, stream>>>(h0b, relh, st, rt, edgeD, startD, aggE, cntE);
    gemm_nn2<1, 0><<<g_ent, 256, 0, stream>>>(aggE, 512, cntE, h0b_bf, 512, wp_l1,
                                              nullptr, nullptr, h1b, nullptr, N_ENT, 512);
    rownorm_kernel<<<N_ENT / 4, 256, 0, stream>>>(h1b, h1b, h1b_bf, N_ENT);
    gemm_nn2<3, 1><<<g_ent, 256, 0, stream>>>(nullptr, 0, nullptr, h1b_bf, 512, wp_g,
                                              gate_b, h1b, ent, ent_bf, N_ENT, 512);
  }

  // -------- decoder prep --------
  pack_fw_kernel<<<dim3(1024, 4), 256, 0, stream>>>(e_fc1, r_fc1, e_fc2, r_fc2,
                                                    fwp0, fwp1, fwp2, fwp3);
  gather_kernel<<<(NB * HD / 4) / 256, 256, 0, stream>>>(ent, subj, se, NB);
  gather_kernel<<<(NB * HD / 4) / 256, 256, 0, stream>>>(relh, rel, re_, NB);
  gather_kernel<<<(NB * HD / 4) / 256, 256, 0, stream>>>(ent, obj, oe, NB);

  unsigned short* A_E = Abuf;
  unsigned short* A_R = Abuf + (size_t)NB * 32768;

  // -------- decoder stage 1 --------
  convgen_kernel<2><<<dim3(NB / 4, 2), 256, 0, stream>>>(
      se, re_, nullptr, e_conv1, e_cb1,
      se, oe, nullptr, r_conv1, r_cb1, A_E, A_R);
  gemm_fc<<<dim3(32, 4, 8), 256, 0, stream>>>(Abuf, fwp0, fwp1, pE);
  reduce4_kernel<<<dim3(NB * HD / 4 / 256, 2), 256, 0, stream>>>(
      pE, pR, e_fb1, r_fb1, o1, q1, o1b, q1b);

  // -------- decoder stage 2 --------
  convgen_kernel<3><<<dim3(NB / 4, 2), 256, 0, stream>>>(
      o1, se, re_, e_conv2, e_cb2,
      q1, se, oe, r_conv2, r_cb2, A_E, A_R);
  gemm_fc<<<dim3(32, 4, 8), 256, 0, stream>>>(Abuf, fwp2, fwp3, pE);
  reduce4_kernel<<<dim3(NB * HD / 4 / 256, 2), 256, 0, stream>>>(
      pE, pR, e_fb2, r_fb2, o2, q2, o2b, q2b);

  // -------- logits (bf16 MFMA) --------
  size_t off0 = 0;
  size_t off1 = (size_t)NB * N_ENT;
  size_t off2 = off1 + (size_t)NB * N_REL;
  size_t off3 = off2 + (size_t)NB * N_ENT;
  gemm_nt_bf16<<<dim3(32, 157), 256, 0, stream>>>(o1b, ent_bf, out + off0, NB, N_ENT, HD);
  gemm_nt_bf16<<<dim3(32, 2), 256, 0, stream>>>(q1b, relh_bf, out + off1, NB, N_REL, HD);
  gemm_nt_bf16<<<dim3(32, 157), 256, 0, stream>>>(o2b, ent_bf, out + off2, NB, N_ENT, HD);
  gemm_nt_bf16<<<dim3(32, 2), 256, 0, stream>>>(q2b, relh_bf, out + off3, NB, N_REL, HD);
}

// Round 11
// 4530.984 us; speedup vs baseline: 1.1779x; 1.0245x over previous
//
#include <hip/hip_runtime.h>
#include <math.h>

// ---------------------------------------------------------------------------
// Refine (RE-GCN style): bf16-MFMA recurrence + decoder; f32 state with bf16
// mirrors. Batched per-timestep CSR segment-means (prebuilt before loop).
// ALL MFMA GEMMs (gemm_core, gemm_fc, gemm_nt) use the single-barrier
// depth-2 register-prefetch pipeline (static reg-set selection, unroll-by-2).
// N_ENT=20000 N_REL=256 H=512 C=64 K=3 L=2 T=8 E=30000 B=4096
// ---------------------------------------------------------------------------

#define N_ENT 20000
#define N_REL 256
#define HD    512
#define NE    30000
#define NB    4096
#define NT    8

typedef __attribute__((ext_vector_type(8))) short          bf16x8;
typedef __attribute__((ext_vector_type(4))) float          f32x4;
typedef __attribute__((ext_vector_type(8))) unsigned short u16x8;
typedef __attribute__((ext_vector_type(4))) unsigned short u16x4;

static __device__ __forceinline__ float sigmoidf_(float x) {
  return 1.0f / (1.0f + expf(-x));
}
static __device__ __forceinline__ unsigned short f2bf(float f) {  // RNE
  unsigned u = __float_as_uint(f);
  return (unsigned short)((u + 0x7FFFu + ((u >> 16) & 1u)) >> 16);
}

// ---------------- row L2 normalize + bf16 mirror ---------------------------
__global__ void rownorm_kernel(const float* __restrict__ in, float* __restrict__ out,
                               unsigned short* __restrict__ outb, int rows) {
  int wid = (blockIdx.x * blockDim.x + threadIdx.x) >> 6;
  int lane = threadIdx.x & 63;
  if (wid >= rows) return;
  const float4* ip = (const float4*)(in + (size_t)wid * HD);
  float4 v0 = ip[lane];
  float4 v1 = ip[lane + 64];
  float s = v0.x * v0.x + v0.y * v0.y + v0.z * v0.z + v0.w * v0.w
          + v1.x * v1.x + v1.y * v1.y + v1.z * v1.z + v1.w * v1.w;
  #pragma unroll
  for (int m = 1; m < 64; m <<= 1) s += __shfl_xor(s, m);
  float inv = 1.0f / (sqrtf(s) + 1e-8f);
  float4* op = (float4*)(out + (size_t)wid * HD);
  v0.x *= inv; v0.y *= inv; v0.z *= inv; v0.w *= inv;
  v1.x *= inv; v1.y *= inv; v1.z *= inv; v1.w *= inv;
  op[lane] = v0; op[lane + 64] = v1;
  unsigned short* ob = outb + (size_t)wid * HD;
  u16x4 p0 = {f2bf(v0.x), f2bf(v0.y), f2bf(v0.z), f2bf(v0.w)};
  u16x4 p1 = {f2bf(v1.x), f2bf(v1.y), f2bf(v1.z), f2bf(v1.w)};
  *(u16x4*)&ob[lane * 4] = p0;
  *(u16x4*)&ob[(lane + 64) * 4] = p1;
}

// ---------------- batched CSR build (all 8 timesteps upfront) --------------
__global__ void zero_hist_all(int* __restrict__ h) {
  int i = blockIdx.x * 256 + threadIdx.x;
  if (i < NT * (N_ENT + N_REL)) h[i] = 0;
}

__global__ void hist_all(const int* __restrict__ dst, const int* __restrict__ rel,
                         int* __restrict__ histD8, int* __restrict__ histR8) {
  int e = blockIdx.x * 256 + threadIdx.x;
  int t = blockIdx.y;
  if (e >= NE) return;
  atomicAdd(&histD8[t * N_ENT + dst[t * NE + e]], 1);
  atomicAdd(&histR8[t * N_REL + rel[t * NE + e]], 1);
}

__global__ void scan_part_all(const int* __restrict__ histD8, int* __restrict__ partD8) {
  int t = blockIdx.x, tid = threadIdx.x;
  const int* hd = histD8 + t * N_ENT;
  int base = tid * 80;                       // 256*80 >= 20000
  int s = 0;
  for (int i = 0; i < 80; ++i) {
    int idx = base + i;
    if (idx < N_ENT) s += hd[idx];
  }
  partD8[t * 257 + tid] = s;
}

__global__ void scan_serial_all(int* __restrict__ partD8, const int* __restrict__ histR8,
                                int* __restrict__ startR8, int* __restrict__ posR8) {
  int t = blockIdx.x;
  int* pd = partD8 + t * 257;
  int run = 0;
  for (int i = 0; i < 256; ++i) { int v = pd[i]; pd[i] = run; run += v; }
  pd[256] = run;
  const int* hr = histR8 + t * N_REL;
  int* sr = startR8 + t * 257;
  int* pr = posR8 + t * N_REL;
  run = 0;
  for (int i = 0; i < 256; ++i) { int v = hr[i]; sr[i] = run; pr[i] = run; run += v; }
  sr[256] = run;
}

__global__ void scan_local_all(const int* __restrict__ histD8, const int* __restrict__ partD8,
                               int* __restrict__ startD8, int* __restrict__ posD8) {
  int t = blockIdx.x, tid = threadIdx.x;
  const int* hd = histD8 + t * N_ENT;
  int* sd = startD8 + t * (N_ENT + 1);
  int* pd = posD8 + t * N_ENT;
  int run = partD8[t * 257 + tid];
  int base = tid * 80;
  for (int i = 0; i < 80; ++i) {
    int idx = base + i;
    if (idx < N_ENT) {
      sd[idx] = run;
      pd[idx] = run;
      run += hd[idx];
    }
  }
  if (tid == 0) sd[N_ENT] = partD8[t * 257 + 256];
}

__global__ void scatter_all(const int* __restrict__ dst, const int* __restrict__ rel,
                            int* __restrict__ posD8, int* __restrict__ posR8,
                            int* __restrict__ edgeD8, int* __restrict__ edgeR8) {
  int e = blockIdx.x * 256 + threadIdx.x;
  int t = blockIdx.y;
  if (e >= NE) return;
  int p = atomicAdd(&posD8[t * N_ENT + dst[t * NE + e]], 1);
  edgeD8[t * NE + p] = e;
  int p2 = atomicAdd(&posR8[t * N_REL + rel[t * NE + e]], 1);
  edgeR8[t * NE + p2] = e;
}

// ---------------- seg-sum via CSR: one wave per output row (f32) -----------
__global__ __launch_bounds__(256)
void agg_rel_csr(const float* __restrict__ ent, const int* __restrict__ src,
                 const int* __restrict__ edgeR, const int* __restrict__ startR,
                 float* __restrict__ aggR, float* __restrict__ cntR) {
  int r = blockIdx.x * 4 + (threadIdx.x >> 6);
  if (r >= N_REL) return;
  int lane = threadIdx.x & 63;
  int s0 = startR[r], s1 = startR[r + 1];
  float4 a = make_float4(0.f, 0.f, 0.f, 0.f);
  float4 b = make_float4(0.f, 0.f, 0.f, 0.f);
  for (int i = s0; i < s1; ++i) {
    int e = edgeR[i];
    int s = src[e];
    const float4* p = (const float4*)(ent + (size_t)s * HD);
    float4 x = p[lane];
    float4 y = p[lane + 64];
    a.x += x.x; a.y += x.y; a.z += x.z; a.w += x.w;
    b.x += y.x; b.y += y.y; b.z += y.z; b.w += y.w;
  }
  float4* op = (float4*)(aggR + (size_t)r * HD);
  op[lane] = a;
  op[lane + 64] = b;
  if (lane == 0) cntR[r] = (float)(s1 - s0);
}

__global__ __launch_bounds__(256)
void agg_ent_csr(const float* __restrict__ h, const float* __restrict__ relh,
                 const int* __restrict__ src, const int* __restrict__ erel,
                 const int* __restrict__ edgeD, const int* __restrict__ startD,
                 float* __restrict__ aggE, float* __restrict__ cntE) {
  int d = blockIdx.x * 4 + (threadIdx.x >> 6);
  if (d >= N_ENT) return;
  int lane = threadIdx.x & 63;
  int s0 = startD[d], s1 = startD[d + 1];
  float4 a = make_float4(0.f, 0.f, 0.f, 0.f);
  float4 b = make_float4(0.f, 0.f, 0.f, 0.f);
  for (int i = s0; i < s1; ++i) {
    int e = edgeD[i];
    int s = src[e], r = erel[e];
    const float4* hp = (const float4*)(h + (size_t)s * HD);
    const float4* rp = (const float4*)(relh + (size_t)r * HD);
    float4 x = hp[lane];
    float4 y = hp[lane + 64];
    float4 u = rp[lane];
    float4 v = rp[lane + 64];
    a.x += x.x + u.x; a.y += x.y + u.y; a.z += x.z + u.z; a.w += x.w + u.w;
    b.x += y.x + v.x; b.y += y.y + v.y; b.z += y.z + v.z; b.w += y.w + v.w;
  }
  float4* op = (float4*)(aggE + (size_t)d * HD);
  op[lane] = a;
  op[lane + 64] = b;
  if (lane == 0) cntE[d] = (float)(s1 - s0);
}

// ---------------- GRU elementwise (+bias fold, +bf16 mirror) ---------------
__global__ void gru_kernel(const float* __restrict__ gi, const float* __restrict__ gh,
                           const float* __restrict__ bih, const float* __restrict__ bhh,
                           float* __restrict__ relh, unsigned short* __restrict__ relhb) {
  int i = blockIdx.x * blockDim.x + threadIdx.x;
  if (i >= N_REL * HD) return;
  int row = i >> 9, col = i & 511;
  const float* gir = gi + (size_t)row * 1536;
  const float* ghr = gh + (size_t)row * 1536;
  float ir = gir[col] + bih[col];
  float iz = gir[col + 512] + bih[col + 512];
  float inn = gir[col + 1024] + bih[col + 1024];
  float hr = ghr[col] + bhh[col];
  float hz = ghr[col + 512] + bhh[col + 512];
  float hn = ghr[col + 1024] + bhh[col + 1024];
  float r = sigmoidf_(ir + hr);
  float z = sigmoidf_(iz + hz);
  float n = tanhf(inn + r * hn);
  float v = (1.0f - z) * n + z * relh[i];
  relh[i] = v;
  relhb[i] = f2bf(v);
}

// ---------------- gather rows (f32) ----------------------------------------
__global__ void gather_kernel(const float* __restrict__ table, const int* __restrict__ idx,
                              float* __restrict__ out, int rows) {
  int i = blockIdx.x * blockDim.x + threadIdx.x;
  if (i >= rows * (HD / 4)) return;
  int row = i >> 7, q = i & 127;
  ((float4*)out)[i] = ((const float4*)(table + (size_t)idx[row] * HD))[q];
}

// ---------------- flat f32 -> bf16 convert (n multiple of 8) ---------------
__global__ void f2b_kernel(const float* __restrict__ in, unsigned short* __restrict__ out, int n) {
  int i = blockIdx.x * blockDim.x + threadIdx.x;
  if (i * 8 >= n) return;
  float4 a = *(const float4*)&in[i * 8];
  float4 b = *(const float4*)&in[i * 8 + 4];
  u16x8 pk = {f2bf(a.x), f2bf(a.y), f2bf(a.z), f2bf(a.w),
              f2bf(b.x), f2bf(b.y), f2bf(b.z), f2bf(b.w)};
  *(u16x8*)&out[i * 8] = pk;
}

// ---------------------------------------------------------------------------
// pack_nn: B (KxN f32 row-major) -> bf16 LDS-image layout:
// step s (32 k): idx = (s*N + n)*32 + ((g ^ ((n>>2)&3))<<3) + j  holds
// B[s*32 + g*8 + j][n].
// ---------------------------------------------------------------------------
__global__ void pack_nn_kernel(const float* __restrict__ B, unsigned short* __restrict__ out,
                               int K, int N) {
  int id = blockIdx.x * 256 + threadIdx.x;
  if (id >= (K >> 3) * N) return;
  int s = id / (N * 4);
  int rem = id - s * (N * 4);
  int n = rem >> 2, g = rem & 3;
  const float* src = B + (size_t)(s * 32 + g * 8) * N + n;
  u16x8 pk;
  #pragma unroll
  for (int j = 0; j < 8; ++j) pk[j] = f2bf(src[(size_t)j * N]);
  *(u16x8*)&out[((size_t)s * N + n) * 32 + ((g ^ ((n >> 2) & 3)) << 3)] = pk;
}

// ---------------------------------------------------------------------------
// GEMM core: depth-2 register-prefetch single-barrier bf16 MFMA GEMM.
// A = [A0 (M x K0, f32, row-scaled by 1/max(cnt,1)) | A1 (M x K1, bf16)].
// ACT: 0 plain, 1 relu(+mirror), 3 gate: u=sigmoid(v+bias[n]); C=u*D+(1-u)*C.
// NIT = (K0+K1)/64, always even (8 or 16) in this model.
// ---------------------------------------------------------------------------
template <int ACT, int MIRROR>
static __device__ __forceinline__
void gemm_core(const float* __restrict__ A0, int K0, const float* __restrict__ cntA,
               const unsigned short* __restrict__ A1, int K1,
               const unsigned short* __restrict__ Bp,
               const float* __restrict__ bias, const float* __restrict__ D,
               float* __restrict__ C, unsigned short* __restrict__ Cb,
               int M, int N, int m0, int n0,
               unsigned short (*As)[8192], unsigned short (*Bs)[8192]) {
  const int tid = threadIdx.x;
  const int lane = tid & 63;
  const int wv = tid >> 6;
  const int wm = wv >> 1, wn = wv & 1;
  const int lr = lane & 15, lg = lane >> 4;
  const int arow = tid >> 1;
  const int akh = (tid & 1) * 32;
  const int achunk = (tid & 1) * 4;
  const int NIT = (K0 + K1) >> 6;

  float s0 = 1.0f;
  if (K0 > 0 && (m0 + arow) < M) s0 = 1.0f / fmaxf(cntA[m0 + arow], 1.0f);

  f32x4 acc[4][4];
  #pragma unroll
  for (int i = 0; i < 4; ++i)
    #pragma unroll
    for (int j = 0; j < 4; ++j) acc[i][j] = (f32x4){0.f, 0.f, 0.f, 0.f};

  auto gload = [&](int it, u16x8* ar, u16x8* br) {
    int mrow = m0 + arow;
    int kk = it * 64 + akh;
    if (mrow < M) {
      if (kk < K0) {
        const float* p = A0 + (size_t)mrow * K0 + kk;
        #pragma unroll
        for (int q = 0; q < 4; ++q) {
          float4 x = *(const float4*)(p + q * 8);
          float4 y = *(const float4*)(p + q * 8 + 4);
          ar[q] = (u16x8){f2bf(x.x * s0), f2bf(x.y * s0), f2bf(x.z * s0), f2bf(x.w * s0),
                          f2bf(y.x * s0), f2bf(y.y * s0), f2bf(y.z * s0), f2bf(y.w * s0)};
        }
      } else {
        const unsigned short* p = A1 + (size_t)mrow * K1 + (kk - K0);
        #pragma unroll
        for (int q = 0; q < 4; ++q) ar[q] = *(const u16x8*)&p[q * 8];
      }
    } else {
      #pragma unroll
      for (int q = 0; q < 4; ++q) ar[q] = (u16x8){0, 0, 0, 0, 0, 0, 0, 0};
    }
    const unsigned short* b0 = Bp + ((size_t)(2 * it) * N + n0) * 32;
    const unsigned short* b1 = Bp + ((size_t)(2 * it + 1) * N + n0) * 32;
    br[0] = *(const u16x8*)&b0[tid * 8];
    br[1] = *(const u16x8*)&b0[2048 + tid * 8];
    br[2] = *(const u16x8*)&b1[tid * 8];
    br[3] = *(const u16x8*)&b1[2048 + tid * 8];
  };
  auto swrite = [&](int nb, const u16x8* ar, const u16x8* br) {
    #pragma unroll
    for (int q = 0; q < 4; ++q) {
      int chunk = achunk + q;
      *(u16x8*)&As[nb][arow * 64 + ((chunk ^ (arow & 7)) << 3)] = ar[q];
    }
    *(u16x8*)&Bs[nb][tid * 8] = br[0];
    *(u16x8*)&Bs[nb][2048 + tid * 8] = br[1];
    *(u16x8*)&Bs[nb][4096 + tid * 8] = br[2];
    *(u16x8*)&Bs[nb][4096 + 2048 + tid * 8] = br[3];
  };
  auto mfma_phase = [&](int nb) {
    bf16x8 af[2][4], bfr[2][4];
    #pragma unroll
    for (int u = 0; u < 2; ++u)
      #pragma unroll
      for (int i = 0; i < 4; ++i) {
        int r = wm * 64 + i * 16 + lr;
        af[u][i] = *(const bf16x8*)&As[nb][r * 64 + (((u * 4 + lg) ^ (r & 7)) << 3)];
        int nl = wn * 64 + i * 16 + lr;
        bfr[u][i] = *(const bf16x8*)&Bs[nb][u * 4096 + nl * 32 + ((lg ^ ((nl >> 2) & 3)) << 3)];
      }
    #pragma unroll
    for (int u = 0; u < 2; ++u)
      #pragma unroll
      for (int i = 0; i < 4; ++i)
        #pragma unroll
        for (int j = 0; j < 4; ++j)
          acc[i][j] = __builtin_amdgcn_mfma_f32_16x16x32_bf16(af[u][i], bfr[u][j], acc[i][j], 0, 0, 0);
  };

  // depth-2 prologue: it0 -> LDS[0]; it1 -> reg set S1
  u16x8 ar0[4], br0[4], ar1[4], br1[4];
  gload(0, ar0, br0);
  swrite(0, ar0, br0);
  gload(1, ar1, br1);
  __syncthreads();

  int cur = 0;
  for (int itp = 0; itp < NIT; itp += 2) {
    // even iteration (itp)
    if (itp + 2 < NIT) gload(itp + 2, ar0, br0);
    mfma_phase(cur);
    swrite(cur ^ 1, ar1, br1);          // itp+1 (< NIT since NIT even)
    __syncthreads();
    cur ^= 1;
    // odd iteration (itp+1)
    if (itp + 3 < NIT) gload(itp + 3, ar1, br1);
    mfma_phase(cur);
    if (itp + 2 < NIT) swrite(cur ^ 1, ar0, br0);
    __syncthreads();
    cur ^= 1;
  }

  #pragma unroll
  for (int i = 0; i < 4; ++i) {
    int m = m0 + wm * 64 + i * 16 + lg * 4;
    #pragma unroll
    for (int j = 0; j < 4; ++j) {
      int n = n0 + wn * 64 + j * 16 + lr;
      #pragma unroll
      for (int q = 0; q < 4; ++q) {
        int mr = m + q;
        if (mr >= M) continue;
        size_t o = (size_t)mr * N + n;
        float v = acc[i][j][q];
        if (ACT == 0) {
          C[o] = v;
        } else if (ACT == 1) {
          float rr = fmaxf(v, 0.0f);
          C[o] = rr;
          if (MIRROR) Cb[o] = f2bf(rr);
        } else {
          float u_ = sigmoidf_(v + bias[n]);
          float rr = u_ * D[o] + (1.0f - u_) * C[o];
          C[o] = rr;
          if (MIRROR) Cb[o] = f2bf(rr);
        }
      }
    }
  }
}

template <int ACT, int MIRROR>
__global__ __launch_bounds__(256, 2)
void gemm_nn2(const float* __restrict__ A0, int K0, const float* __restrict__ cntA,
              const unsigned short* __restrict__ A1, int K1,
              const unsigned short* __restrict__ Bp,
              const float* __restrict__ bias, const float* __restrict__ D,
              float* __restrict__ C, unsigned short* __restrict__ Cb, int M, int N) {
  __shared__ unsigned short As[2][8192];
  __shared__ unsigned short Bs[2][8192];
  gemm_core<ACT, MIRROR>(A0, K0, cntA, A1, K1, Bp, bias, D, C, Cb, M, N,
                         blockIdx.x * 128, blockIdx.y * 128, As, Bs);
}

// Fused GRU GEMMs: z=0 -> gi = [aggR/cnt | rel_bf] @ wp_ih; z=1 -> gh = relh_bf @ wp_hh
__global__ __launch_bounds__(256, 2)
void gru_gemms(const float* __restrict__ aggR, const float* __restrict__ cntR,
               const unsigned short* __restrict__ rel_bf,
               const unsigned short* __restrict__ relh_bf,
               const unsigned short* __restrict__ wp_ih,
               const unsigned short* __restrict__ wp_hh,
               float* __restrict__ gi, float* __restrict__ gh) {
  __shared__ unsigned short As[2][8192];
  __shared__ unsigned short Bs[2][8192];
  if (blockIdx.z == 0)
    gemm_core<0, 0>(aggR, 512, cntR, rel_bf, 512, wp_ih, nullptr, nullptr,
                    gi, nullptr, N_REL, 1536, blockIdx.x * 128, blockIdx.y * 128, As, Bs);
  else
    gemm_core<0, 0>(nullptr, 0, nullptr, relh_bf, 512, wp_hh, nullptr, nullptr,
                    gh, nullptr, N_REL, 1536, blockIdx.x * 128, blockIdx.y * 128, As, Bs);
}

// ---------------------------------------------------------------------------
// pack_fw: fw (32768x512 f32) -> bf16 image (same layout as pack_nn, N=512)
// ---------------------------------------------------------------------------
__global__ __launch_bounds__(256)
void pack_fw_kernel(const float* __restrict__ f0, const float* __restrict__ f1,
                    const float* __restrict__ f2, const float* __restrict__ f3,
                    unsigned short* __restrict__ o0, unsigned short* __restrict__ o1,
                    unsigned short* __restrict__ o2, unsigned short* __restrict__ o3) {
  __shared__ float L[32][512];
  const float* fw; unsigned short* op;
  switch (blockIdx.y) {
    case 0: fw = f0; op = o0; break;
    case 1: fw = f1; op = o1; break;
    case 2: fw = f2; op = o2; break;
    default: fw = f3; op = o3; break;
  }
  int s = blockIdx.x, tid = threadIdx.x;
  #pragma unroll
  for (int i = 0; i < 16; ++i) {
    int idx = tid + 256 * i;
    int r = idx >> 7, cq = (idx & 127) << 2;
    *(float4*)&L[r][cq] = *(const float4*)&fw[(size_t)(s * 32 + r) * 512 + cq];
  }
  __syncthreads();
  #pragma unroll
  for (int ii = 0; ii < 8; ++ii) {
    int slot = tid + 256 * ii;
    int n = slot >> 2, g = slot & 3;
    u16x8 pk;
    #pragma unroll
    for (int j = 0; j < 8; ++j) pk[j] = f2bf(L[g * 8 + j][n]);
    size_t off = (size_t)s * 16384 + n * 32 + ((g ^ ((n >> 2) & 3)) << 3);
    *(u16x8*)&op[off] = pk;
  }
}

// ---------------------------------------------------------------------------
// convgen: conv1d('SAME',K=3)+relu -> A_conv bf16 [NB][c*512+h], both paths.
// ---------------------------------------------------------------------------
template <int CIN>
__global__ __launch_bounds__(256)
void convgen_kernel(const float* __restrict__ X0e, const float* __restrict__ X1e,
                    const float* __restrict__ X2e,
                    const float* __restrict__ cwE, const float* __restrict__ cbE,
                    const float* __restrict__ X0r, const float* __restrict__ X1r,
                    const float* __restrict__ X2r,
                    const float* __restrict__ cwR, const float* __restrict__ cbR,
                    unsigned short* __restrict__ Ae, unsigned short* __restrict__ Ar) {
  __shared__ float wsm[64 * CIN * 3];
  __shared__ float bsm[64];
  const int path = blockIdx.y;
  const float* X[CIN]; const float* cw; const float* cb; unsigned short* A;
  if (path == 0) {
    X[0] = X0e; X[1] = X1e; if constexpr (CIN == 3) X[2] = X2e;
    cw = cwE; cb = cbE; A = Ae;
  } else {
    X[0] = X0r; X[1] = X1r; if constexpr (CIN == 3) X[2] = X2r;
    cw = cwR; cb = cbR; A = Ar;
  }
  const int tid = threadIdx.x;
  for (int i = tid; i < 64 * CIN * 3; i += 256) wsm[i] = cw[i];
  if (tid < 64) bsm[tid] = cb[tid];
  __syncthreads();

  const int o = tid & 63;
  const int b = blockIdx.x * 4 + (tid >> 6);
  const int h = o * 8;

  float xm[CIN][8], xl[CIN], xr[CIN];
  #pragma unroll
  for (int ci = 0; ci < CIN; ++ci) {
    const float* row = X[ci] + (size_t)b * HD + h;
    float4 a4 = *(const float4*)row;
    float4 b4 = *(const float4*)(row + 4);
    xm[ci][0] = a4.x; xm[ci][1] = a4.y; xm[ci][2] = a4.z; xm[ci][3] = a4.w;
    xm[ci][4] = b4.x; xm[ci][5] = b4.y; xm[ci][6] = b4.z; xm[ci][7] = b4.w;
    xl[ci] = (h > 0) ? row[-1] : 0.f;
    xr[ci] = (h + 8 < HD) ? row[8] : 0.f;
  }
  unsigned short* dst = A + (size_t)b * 32768 + h;
  for (int c = 0; c < 64; ++c) {
    float v[8];
    float cbv = bsm[c];
    #pragma unroll
    for (int e = 0; e < 8; ++e) v[e] = cbv;
    #pragma unroll
    for (int ci = 0; ci < CIN; ++ci) {
      float w0 = wsm[(c * CIN + ci) * 3 + 0];
      float w1 = wsm[(c * CIN + ci) * 3 + 1];
      float w2 = wsm[(c * CIN + ci) * 3 + 2];
      #pragma unroll
      for (int e = 0; e < 8; ++e) {
        float lft = e ? xm[ci][e - 1] : xl[ci];
        float rgt = (e < 7) ? xm[ci][e + 1] : xr[ci];
        v[e] = fmaf(lft, w0, fmaf(xm[ci][e], w1, fmaf(rgt, w2, v[e])));
      }
    }
    u16x8 pk;
    #pragma unroll
    for (int e = 0; e < 8; ++e) pk[e] = f2bf(fmaxf(v[e], 0.f));
    *(u16x8*)&dst[c * 512] = pk;
  }
}

// ---------------------------------------------------------------------------
// gemm_fc: part[path][ks] = A_conv(4096 x 32768 bf16) @ fw-image, KSPLIT=4.
// Depth-2 register prefetch (static set selection via unroll-by-2).
// ---------------------------------------------------------------------------
__global__ __launch_bounds__(256, 2)
void gemm_fc(const unsigned short* __restrict__ Abuf,
             const unsigned short* __restrict__ fwpE,
             const unsigned short* __restrict__ fwpR,
             float* __restrict__ partBase) {
  __shared__ unsigned short As[2][128 * 64];
  __shared__ unsigned short Bs[2][2 * 128 * 32];
  const int tid = threadIdx.x;
  const int lane = tid & 63;
  const int wv = tid >> 6;
  const int wm = wv >> 1, wn = wv & 1;
  const int lr = lane & 15, lg = lane >> 4;
  const int m0 = blockIdx.x * 128;
  const int n0 = blockIdx.y * 128;
  const int path = blockIdx.z >> 2;
  const int ks = blockIdx.z & 3;

  const unsigned short* A = Abuf + (size_t)path * ((size_t)NB * 32768);
  const unsigned short* fwp = (path == 0) ? fwpE : fwpR;
  float* part = partBase + (size_t)(path * 4 + ks) * ((size_t)NB * HD);

  const int arow = tid >> 1;
  const int achunk = (tid & 1) * 4;
  const unsigned short* aRow = A + (size_t)(m0 + arow) * 32768 + ks * 8192 + achunk * 8;
  const unsigned short* bBase = fwp + (size_t)(ks * 256) * 16384 + (size_t)n0 * 32;

  f32x4 acc[4][4];
  #pragma unroll
  for (int i = 0; i < 4; ++i)
    #pragma unroll
    for (int j = 0; j < 4; ++j) acc[i][j] = (f32x4){0.f, 0.f, 0.f, 0.f};

  auto gload = [&](int it, u16x8* ar, u16x8* br) {
    const unsigned short* ap = aRow + it * 64;
    #pragma unroll
    for (int q = 0; q < 4; ++q) ar[q] = *(const u16x8*)&ap[q * 8];
    const unsigned short* bp = bBase + (size_t)it * 2 * 16384;
    br[0] = *(const u16x8*)&bp[tid * 8];
    br[1] = *(const u16x8*)&bp[2048 + tid * 8];
    br[2] = *(const u16x8*)&bp[16384 + tid * 8];
    br[3] = *(const u16x8*)&bp[16384 + 2048 + tid * 8];
  };
  auto swrite = [&](int nb, const u16x8* ar, const u16x8* br) {
    #pragma unroll
    for (int q = 0; q < 4; ++q) {
      int chunk = achunk + q;
      *(u16x8*)&As[nb][arow * 64 + ((chunk ^ (arow & 7)) << 3)] = ar[q];
    }
    *(u16x8*)&Bs[nb][tid * 8] = br[0];
    *(u16x8*)&Bs[nb][2048 + tid * 8] = br[1];
    *(u16x8*)&Bs[nb][4096 + tid * 8] = br[2];
    *(u16x8*)&Bs[nb][4096 + 2048 + tid * 8] = br[3];
  };
  auto mfma_phase = [&](int nb) {
    bf16x8 af[2][4], bfr[2][4];
    #pragma unroll
    for (int u = 0; u < 2; ++u)
      #pragma unroll
      for (int i = 0; i < 4; ++i) {
        int r = wm * 64 + i * 16 + lr;
        af[u][i] = *(const bf16x8*)&As[nb][r * 64 + (((u * 4 + lg) ^ (r & 7)) << 3)];
        int nl = wn * 64 + i * 16 + lr;
        bfr[u][i] = *(const bf16x8*)&Bs[nb][u * 4096 + nl * 32 + ((lg ^ ((nl >> 2) & 3)) << 3)];
      }
    #pragma unroll
    for (int u = 0; u < 2; ++u)
      #pragma unroll
      for (int i = 0; i < 4; ++i)
        #pragma unroll
        for (int j = 0; j < 4; ++j)
          acc[i][j] = __builtin_amdgcn_mfma_f32_16x16x32_bf16(af[u][i], bfr[u][j], acc[i][j], 0, 0, 0);
  };

  u16x8 ar0[4], br0[4], ar1[4], br1[4];
  gload(0, ar0, br0);
  swrite(0, ar0, br0);
  gload(1, ar1, br1);
  __syncthreads();

  int cur = 0;
  for (int itp = 0; itp < 128; itp += 2) {
    if (itp + 2 < 128) gload(itp + 2, ar0, br0);
    mfma_phase(cur);
    swrite(cur ^ 1, ar1, br1);
    __syncthreads();
    cur ^= 1;
    if (itp + 3 < 128) gload(itp + 3, ar1, br1);
    mfma_phase(cur);
    if (itp + 2 < 128) swrite(cur ^ 1, ar0, br0);
    __syncthreads();
    cur ^= 1;
  }

  #pragma unroll
  for (int i = 0; i < 4; ++i) {
    int m = m0 + wm * 64 + i * 16 + lg * 4;
    #pragma unroll
    for (int j = 0; j < 4; ++j) {
      int n = n0 + wn * 64 + j * 16 + lr;
      #pragma unroll
      for (int q = 0; q < 4; ++q)
        part[(size_t)(m + q) * HD + n] = acc[i][j][q];
    }
  }
}

// ---------------------------------------------------------------------------
// reduce 4 split-K partials + bias + relu -> f32 out AND bf16 out
// ---------------------------------------------------------------------------
__global__ void reduce4_kernel(const float* __restrict__ pE, const float* __restrict__ pR,
                               const float* __restrict__ bE, const float* __restrict__ bR,
                               float* __restrict__ oE, float* __restrict__ oR,
                               unsigned short* __restrict__ obE, unsigned short* __restrict__ obR) {
  int p = blockIdx.y;
  const float* part = p ? pR : pE;
  const float* bias = p ? bR : bE;
  float* o = p ? oR : oE;
  unsigned short* ob = p ? obR : obE;
  int i = blockIdx.x * 256 + threadIdx.x;
  int col = (i << 2) & 511;
  float4 s = *(const float4*)&part[(size_t)i * 4];
  #pragma unroll
  for (int ks = 1; ks < 4; ++ks) {
    float4 t = *(const float4*)&part[(size_t)ks * (NB * HD) + i * 4];
    s.x += t.x; s.y += t.y; s.z += t.z; s.w += t.w;
  }
  float4 b4 = *(const float4*)&bias[col];
  s.x = fmaxf(s.x + b4.x, 0.f); s.y = fmaxf(s.y + b4.y, 0.f);
  s.z = fmaxf(s.z + b4.z, 0.f); s.w = fmaxf(s.w + b4.w, 0.f);
  *(float4*)&o[(size_t)i * 4] = s;
  u16x4 pk = {f2bf(s.x), f2bf(s.y), f2bf(s.z), f2bf(s.w)};
  *(u16x4*)&ob[(size_t)i * 4] = pk;
}

// ---------------------------------------------------------------------------
// bf16 NT GEMM: C(MxN, f32) = A(MxK) @ B(NxK)^T, bf16 row-major; depth-2
// register-prefetch single-barrier pipeline. K=512 -> NIT=8. N-tail guarded.
// ---------------------------------------------------------------------------
__global__ __launch_bounds__(256, 2)
void gemm_nt_bf16(const unsigned short* __restrict__ A, const unsigned short* __restrict__ B,
                  float* __restrict__ C, int M, int N, int K) {
  __shared__ unsigned short As[2][8192];
  __shared__ unsigned short Bs[2][8192];
  const int tid = threadIdx.x;
  const int lane = tid & 63;
  const int wv = tid >> 6;
  const int wm = wv >> 1, wn = wv & 1;
  const int m0 = blockIdx.x * 128, n0 = blockIdx.y * 128;
  const int lr = lane & 15, lg = lane >> 4;
  const int row = tid >> 1, half = tid & 1;
  const int nrow = n0 + row;
  const int NIT = K >> 6;

  f32x4 acc[4][4];
  #pragma unroll
  for (int i = 0; i < 4; ++i)
    #pragma unroll
    for (int j = 0; j < 4; ++j) acc[i][j] = (f32x4){0.f, 0.f, 0.f, 0.f};

  auto gload = [&](int it, u16x8* ar, u16x8* br) {
    const unsigned short* asrc = A + (size_t)(m0 + row) * K + it * 64 + half * 32;
    #pragma unroll
    for (int q = 0; q < 4; ++q) ar[q] = *(const u16x8*)&asrc[q * 8];
    const unsigned short* bsrc = B + (size_t)nrow * K + it * 64 + half * 32;
    u16x8 z = {0, 0, 0, 0, 0, 0, 0, 0};
    #pragma unroll
    for (int q = 0; q < 4; ++q) br[q] = (nrow < N) ? *(const u16x8*)&bsrc[q * 8] : z;
  };
  auto swrite = [&](int nb, const u16x8* ar, const u16x8* br) {
    #pragma unroll
    for (int q = 0; q < 4; ++q) {
      int chunk = half * 4 + q;
      *(u16x8*)&As[nb][row * 64 + ((chunk ^ (row & 7)) << 3)] = ar[q];
      *(u16x8*)&Bs[nb][row * 64 + ((chunk ^ (row & 7)) << 3)] = br[q];
    }
  };
  auto mfma_phase = [&](int nb) {
    #pragma unroll
    for (int u = 0; u < 2; ++u) {
      bf16x8 a[4], b[4];
      #pragma unroll
      for (int i = 0; i < 4; ++i) {
        int r = wm * 64 + i * 16 + lr;
        a[i] = *(const bf16x8*)&As[nb][r * 64 + (((u * 4 + lg) ^ (r & 7)) << 3)];
        int n = wn * 64 + i * 16 + lr;
        b[i] = *(const bf16x8*)&Bs[nb][n * 64 + (((u * 4 + lg) ^ (n & 7)) << 3)];
      }
      #pragma unroll
      for (int i = 0; i < 4; ++i)
        #pragma unroll
        for (int j = 0; j < 4; ++j)
          acc[i][j] = __builtin_amdgcn_mfma_f32_16x16x32_bf16(a[i], b[j], acc[i][j], 0, 0, 0);
    }
  };

  u16x8 ar0[4], br0[4], ar1[4], br1[4];
  gload(0, ar0, br0);
  swrite(0, ar0, br0);
  gload(1, ar1, br1);
  __syncthreads();

  int cur = 0;
  for (int itp = 0; itp < NIT; itp += 2) {
    if (itp + 2 < NIT) gload(itp + 2, ar0, br0);
    mfma_phase(cur);
    swrite(cur ^ 1, ar1, br1);
    __syncthreads();
    cur ^= 1;
    if (itp + 3 < NIT) gload(itp + 3, ar1, br1);
    mfma_phase(cur);
    if (itp + 2 < NIT) swrite(cur ^ 1, ar0, br0);
    __syncthreads();
    cur ^= 1;
  }

  #pragma unroll
  for (int i = 0; i < 4; ++i) {
    int m = m0 + wm * 64 + i * 16 + lg * 4;
    #pragma unroll
    for (int j = 0; j < 4; ++j) {
      int n = n0 + wn * 64 + j * 16 + lr;
      if (n < N) {
        #pragma unroll
        for (int q = 0; q < 4; ++q)
          C[(size_t)(m + q) * N + n] = acc[i][j][q];
      }
    }
  }
}

// ---------------------------------------------------------------------------
extern "C" void kernel_launch(void* const* d_in, const int* in_sizes, int n_in,
                              void* d_out, int out_size, void* d_ws, size_t ws_size,
                              hipStream_t stream) {
  const float* ent_embeds = (const float*)d_in[0];
  const float* rel_embeds = (const float*)d_in[1];
  const float* W_msg  = (const float*)d_in[2];
  const float* W_self = (const float*)d_in[3];
  const float* gru_Wih = (const float*)d_in[4];
  const float* gru_Whh = (const float*)d_in[5];
  const float* gru_bih = (const float*)d_in[6];
  const float* gru_bhh = (const float*)d_in[7];
  const float* gate_W = (const float*)d_in[8];
  const float* gate_b = (const float*)d_in[9];
  const float* e_conv1 = (const float*)d_in[10]; const float* e_cb1 = (const float*)d_in[11];
  const float* e_fc1   = (const float*)d_in[12]; const float* e_fb1 = (const float*)d_in[13];
  const float* e_conv2 = (const float*)d_in[14]; const float* e_cb2 = (const float*)d_in[15];
  const float* e_fc2   = (const float*)d_in[16]; const float* e_fb2 = (const float*)d_in[17];
  const float* r_conv1 = (const float*)d_in[18]; const float* r_cb1 = (const float*)d_in[19];
  const float* r_fc1   = (const float*)d_in[20]; const float* r_fb1 = (const float*)d_in[21];
  const float* r_conv2 = (const float*)d_in[22]; const float* r_cb2 = (const float*)d_in[23];
  const float* r_fc2   = (const float*)d_in[24]; const float* r_fb2 = (const float*)d_in[25];
  const int* src  = (const int*)d_in[26];
  const int* dst  = (const int*)d_in[27];
  const int* erel = (const int*)d_in[28];
  const int* subj = (const int*)d_in[29];
  const int* rel  = (const int*)d_in[30];
  const int* obj  = (const int*)d_in[31];
  float* out = (float*)d_out;

  // -------- workspace layout --------
  float* w = (float*)d_ws;
  float* ent   = w; w += (size_t)N_ENT * HD;
  float* relh  = w; w += (size_t)N_REL * HD;
  float* aggR  = w; w += (size_t)N_REL * HD;
  float* cntR  = w; w += N_REL;
  float* gi    = w; w += (size_t)N_REL * 1536;
  float* gh    = w; w += (size_t)N_REL * 1536;
  float* aggE  = w; w += (size_t)N_ENT * HD;     // } aggE..h1b reused post-loop as
  float* cntE  = w; w += N_ENT;                  // } packed-fw storage
  float* tmp   = w; w += (size_t)N_ENT * HD;
  float* h0b   = w; w += (size_t)N_ENT * HD;
  float* h1b   = w; w += (size_t)N_ENT * HD;
  float* se    = w; w += (size_t)NB * HD;
  float* re_   = w; w += (size_t)NB * HD;
  float* oe    = w; w += (size_t)NB * HD;
  float* o1    = w; w += (size_t)NB * HD;
  float* q1    = w; w += (size_t)NB * HD;
  float* o2    = w; w += (size_t)NB * HD;
  float* q2    = w; w += (size_t)NB * HD;
  unsigned short* ent_bf  = (unsigned short*)w; w += (size_t)N_ENT * HD / 2;
  unsigned short* relh_bf = (unsigned short*)w; w += (size_t)N_REL * HD / 2;
  unsigned short* rel_bf  = (unsigned short*)w; w += (size_t)N_REL * HD / 2;
  unsigned short* h0b_bf  = (unsigned short*)w; w += (size_t)N_ENT * HD / 2;
  unsigned short* h1b_bf  = (unsigned short*)w; w += (size_t)N_ENT * HD / 2;
  unsigned short* o1b = (unsigned short*)w; w += (size_t)NB * HD / 2;
  unsigned short* q1b = (unsigned short*)w; w += (size_t)NB * HD / 2;
  unsigned short* o2b = (unsigned short*)w; w += (size_t)NB * HD / 2;
  unsigned short* q2b = (unsigned short*)w; w += (size_t)NB * HD / 2;
  // recurrence weight packs (bf16)
  unsigned short* wp_ih = (unsigned short*)w;            // 1024x1536
  unsigned short* wp_hh = wp_ih + (size_t)1024 * 1536;   // 512x1536
  unsigned short* wp_l0 = wp_hh + (size_t)512 * 1536;    // 1024x512
  unsigned short* wp_l1 = wp_l0 + (size_t)1024 * 512;    // 1024x512
  unsigned short* wp_g  = wp_l1 + (size_t)1024 * 512;    // 512x512
  w += ((size_t)1024 * 1536 + 512 * 1536 + 2 * 1024 * 512 + 512 * 512) / 2;
  // batched CSR buffers (int), all 8 timesteps
  int* histD8  = (int*)w;                       // 8 x 20000
  int* histR8  = histD8 + (size_t)NT * N_ENT;   // 8 x 256 (contiguous for zeroing)
  int* partD8  = histR8 + (size_t)NT * N_REL;   // 8 x 257
  int* startD8 = partD8 + (size_t)NT * 257;     // 8 x 20001
  int* posD8   = startD8 + (size_t)NT * (N_ENT + 1);  // 8 x 20000
  int* startR8 = posD8 + (size_t)NT * N_ENT;    // 8 x 257
  int* posR8   = startR8 + (size_t)NT * 257;    // 8 x 256
  int* edgeD8  = posR8 + (size_t)NT * N_REL;    // 8 x 30000
  int* edgeR8  = edgeD8 + (size_t)NT * NE;      // 8 x 30000
  // fw packs alias the recurrence temporaries (used only post-loop)
  unsigned short* fwp0 = (unsigned short*)aggE;
  unsigned short* fwp1 = fwp0 + (size_t)16777216;
  unsigned short* fwp2 = fwp1 + (size_t)16777216;
  unsigned short* fwp3 = fwp2 + (size_t)16777216;
  (void)tmp;
  // decoder scratch in d_out (written+consumed before logits):
  unsigned short* Abuf = (unsigned short*)out;          // 2 x NB x 32768 u16
  float* pE = out + (size_t)2 * NB * 32768 / 2;         // f32 offset after Abuf
  float* pR = pE + (size_t)4 * NB * HD;

  const dim3 g_gru(2, 12, 2);  // 256 x 1536, z = {gi, gh}
  const dim3 g_ent(157, 4);    // 20000 x 512

  // -------- weight packing (once) --------
  {
    int t;
    t = (1024 * 1536) / 8; pack_nn_kernel<<<(t + 255) / 256, 256, 0, stream>>>(gru_Wih, wp_ih, 1024, 1536);
    t = (512 * 1536) / 8;  pack_nn_kernel<<<(t + 255) / 256, 256, 0, stream>>>(gru_Whh, wp_hh, 512, 1536);
    t = (512 * 512) / 8;
    pack_nn_kernel<<<(t + 255) / 256, 256, 0, stream>>>(W_msg, wp_l0, 512, 512);
    pack_nn_kernel<<<(t + 255) / 256, 256, 0, stream>>>(W_self, wp_l0 + (size_t)512 * 512, 512, 512);
    pack_nn_kernel<<<(t + 255) / 256, 256, 0, stream>>>(W_msg + (size_t)512 * 512, wp_l1, 512, 512);
    pack_nn_kernel<<<(t + 255) / 256, 256, 0, stream>>>(W_self + (size_t)512 * 512, wp_l1 + (size_t)512 * 512, 512, 512);
    pack_nn_kernel<<<(t + 255) / 256, 256, 0, stream>>>(gate_W, wp_g, 512, 512);
  }

  // -------- batched CSR build for all 8 timesteps (independent of state) ----
  zero_hist_all<<<(NT * (N_ENT + N_REL) + 255) / 256, 256, 0, stream>>>(histD8);
  hist_all<<<dim3((NE + 255) / 256, NT), 256, 0, stream>>>(dst, erel, histD8, histR8);
  scan_part_all<<<NT, 256, 0, stream>>>(histD8, partD8);
  scan_serial_all<<<NT, 1, 0, stream>>>(partD8, histR8, startR8, posR8);
  scan_local_all<<<NT, 256, 0, stream>>>(histD8, partD8, startD8, posD8);
  scatter_all<<<dim3((NE + 255) / 256, NT), 256, 0, stream>>>(dst, erel, posD8, posR8,
                                                              edgeD8, edgeR8);

  // -------- init --------
  rownorm_kernel<<<N_ENT / 4, 256, 0, stream>>>(ent_embeds, ent, ent_bf, N_ENT);
  hipMemcpyAsync(relh, rel_embeds, (size_t)N_REL * HD * 4, hipMemcpyDeviceToDevice, stream);
  f2b_kernel<<<(N_REL * HD / 8) / 256, 256, 0, stream>>>(rel_embeds, rel_bf, N_REL * HD);
  f2b_kernel<<<(N_REL * HD / 8) / 256, 256, 0, stream>>>(rel_embeds, relh_bf, N_REL * HD);

  // -------- timestep loop --------
  for (int t = 0; t < NT; ++t) {
    const int* st = src + t * NE;
    const int* rt = erel + t * NE;
    const int* edgeD = edgeD8 + (size_t)t * NE;
    const int* edgeR = edgeR8 + (size_t)t * NE;
    const int* startD = startD8 + (size_t)t * (N_ENT + 1);
    const int* startR = startR8 + (size_t)t * 257;

    // relation evolution
    agg_rel_csr<<<N_REL / 4, 256, 0, stream>>>(ent, st, edgeR, startR, aggR, cntR);
    gru_gemms<<<g_gru, 256, 0, stream>>>(aggR, cntR, rel_bf, relh_bf, wp_ih, wp_hh, gi, gh);
    gru_kernel<<<(N_REL * HD) / 256, 256, 0, stream>>>(gi, gh, gru_bih, gru_bhh, relh, relh_bf);

    // entity evolution: h = relu([mean-agg | h] @ [Wmsg;Wself]) per layer
    agg_ent_csr<<<N_ENT / 4, 256, 0, stream>>>(ent, relh, st, rt, edgeD, startD, aggE, cntE);
    gemm_nn2<1, 1><<<g_ent, 256, 0, stream>>>(aggE, 512, cntE, ent_bf, 512, wp_l0,
                                              nullptr, nullptr, h0b, h0b_bf, N_ENT, 512);
    agg_ent_csr<<<N_ENT / 4, 256, 0, stream>>>(h0b, relh, st, rt, edgeD, startD, aggE, cntE);
    gemm_nn2<1, 0><<<g_ent, 256, 0, stream>>>(aggE, 512, cntE, h0b_bf, 512, wp_l1,
                                              nullptr, nullptr, h1b, nullptr, N_ENT, 512);
    rownorm_kernel<<<N_ENT / 4, 256, 0, stream>>>(h1b, h1b, h1b_bf, N_ENT);
    gemm_nn2<3, 1><<<g_ent, 256, 0, stream>>>(nullptr, 0, nullptr, h1b_bf, 512, wp_g,
                                              gate_b, h1b, ent, ent_bf, N_ENT, 512);
  }

  // -------- decoder prep --------
  pack_fw_kernel<<<dim3(1024, 4), 256, 0, stream>>>(e_fc1, r_fc1, e_fc2, r_fc2,
                                                    fwp0, fwp1, fwp2, fwp3);
  gather_kernel<<<(NB * HD / 4) / 256, 256, 0, stream>>>(ent, subj, se, NB);
  gather_kernel<<<(NB * HD / 4) / 256, 256, 0, stream>>>(relh, rel, re_, NB);
  gather_kernel<<<(NB * HD / 4) / 256, 256, 0, stream>>>(ent, obj, oe, NB);

  unsigned short* A_E = Abuf;
  unsigned short* A_R = Abuf + (size_t)NB * 32768;

  // -------- decoder stage 1 --------
  convgen_kernel<2><<<dim3(NB / 4, 2), 256, 0, stream>>>(
      se, re_, nullptr, e_conv1, e_cb1,
      se, oe, nullptr, r_conv1, r_cb1, A_E, A_R);
  gemm_fc<<<dim3(32, 4, 8), 256, 0, stream>>>(Abuf, fwp0, fwp1, pE);
  reduce4_kernel<<<dim3(NB * HD / 4 / 256, 2), 256, 0, stream>>>(
      pE, pR, e_fb1, r_fb1, o1, q1, o1b, q1b);

  // -------- decoder stage 2 --------
  convgen_kernel<3><<<dim3(NB / 4, 2), 256, 0, stream>>>(
      o1, se, re_, e_conv2, e_cb2,
      q1, se, oe, r_conv2, r_cb2, A_E, A_R);
  gemm_fc<<<dim3(32, 4, 8), 256, 0, stream>>>(Abuf, fwp2, fwp3, pE);
  reduce4_kernel<<<dim3(NB * HD / 4 / 256, 2), 256, 0, stream>>>(
      pE, pR, e_fb2, r_fb2, o2, q2, o2b, q2b);

  // -------- logits (bf16 MFMA) --------
  size_t off0 = 0;
  size_t off1 = (size_t)NB * N_ENT;
  size_t off2 = off1 + (size_t)NB * N_REL;
  size_t off3 = off2 + (size_t)NB * N_ENT;
  gemm_nt_bf16<<<dim3(32, 157), 256, 0, stream>>>(o1b, ent_bf, out + off0, NB, N_ENT, HD);
  gemm_nt_bf16<<<dim3(32, 2), 256, 0, stream>>>(q1b, relh_bf, out + off1, NB, N_REL, HD);
  gemm_nt_bf16<<<dim3(32, 157), 256, 0, stream>>>(o2b, ent_bf, out + off2, NB, N_ENT, HD);
  gemm_nt_bf16<<<dim3(32, 2), 256, 0, stream>>>(q2b, relh_bf, out + off3, NB, N_REL, HD);
}

// Round 12
// 4134.203 us; speedup vs baseline: 1.2909x; 1.0960x over previous
//
#include <hip/hip_runtime.h>
#include <math.h>

// ---------------------------------------------------------------------------
// Refine (RE-GCN style): bf16-MFMA recurrence + decoder; f32 state with bf16
// mirrors. Batched per-timestep CSR segment-means. gemm_core now BK=32 with
// 32KB LDS -> 3 blocks/CU (was 64KB/2) + depth-2 register prefetch; identical
// accumulation order (bitwise same results). gemm_fc/gemm_nt unchanged.
// N_ENT=20000 N_REL=256 H=512 C=64 K=3 L=2 T=8 E=30000 B=4096
// ---------------------------------------------------------------------------

#define N_ENT 20000
#define N_REL 256
#define HD    512
#define NE    30000
#define NB    4096
#define NT    8

typedef __attribute__((ext_vector_type(8))) short          bf16x8;
typedef __attribute__((ext_vector_type(4))) float          f32x4;
typedef __attribute__((ext_vector_type(8))) unsigned short u16x8;
typedef __attribute__((ext_vector_type(4))) unsigned short u16x4;

static __device__ __forceinline__ float sigmoidf_(float x) {
  return 1.0f / (1.0f + expf(-x));
}
static __device__ __forceinline__ unsigned short f2bf(float f) {  // RNE
  unsigned u = __float_as_uint(f);
  return (unsigned short)((u + 0x7FFFu + ((u >> 16) & 1u)) >> 16);
}

// ---------------- row L2 normalize + bf16 mirror ---------------------------
__global__ void rownorm_kernel(const float* __restrict__ in, float* __restrict__ out,
                               unsigned short* __restrict__ outb, int rows) {
  int wid = (blockIdx.x * blockDim.x + threadIdx.x) >> 6;
  int lane = threadIdx.x & 63;
  if (wid >= rows) return;
  const float4* ip = (const float4*)(in + (size_t)wid * HD);
  float4 v0 = ip[lane];
  float4 v1 = ip[lane + 64];
  float s = v0.x * v0.x + v0.y * v0.y + v0.z * v0.z + v0.w * v0.w
          + v1.x * v1.x + v1.y * v1.y + v1.z * v1.z + v1.w * v1.w;
  #pragma unroll
  for (int m = 1; m < 64; m <<= 1) s += __shfl_xor(s, m);
  float inv = 1.0f / (sqrtf(s) + 1e-8f);
  float4* op = (float4*)(out + (size_t)wid * HD);
  v0.x *= inv; v0.y *= inv; v0.z *= inv; v0.w *= inv;
  v1.x *= inv; v1.y *= inv; v1.z *= inv; v1.w *= inv;
  op[lane] = v0; op[lane + 64] = v1;
  unsigned short* ob = outb + (size_t)wid * HD;
  u16x4 p0 = {f2bf(v0.x), f2bf(v0.y), f2bf(v0.z), f2bf(v0.w)};
  u16x4 p1 = {f2bf(v1.x), f2bf(v1.y), f2bf(v1.z), f2bf(v1.w)};
  *(u16x4*)&ob[lane * 4] = p0;
  *(u16x4*)&ob[(lane + 64) * 4] = p1;
}

// ---------------- batched CSR build (all 8 timesteps upfront) --------------
__global__ void zero_hist_all(int* __restrict__ h) {
  int i = blockIdx.x * 256 + threadIdx.x;
  if (i < NT * (N_ENT + N_REL)) h[i] = 0;
}

__global__ void hist_all(const int* __restrict__ dst, const int* __restrict__ rel,
                         int* __restrict__ histD8, int* __restrict__ histR8) {
  int e = blockIdx.x * 256 + threadIdx.x;
  int t = blockIdx.y;
  if (e >= NE) return;
  atomicAdd(&histD8[t * N_ENT + dst[t * NE + e]], 1);
  atomicAdd(&histR8[t * N_REL + rel[t * NE + e]], 1);
}

__global__ void scan_part_all(const int* __restrict__ histD8, int* __restrict__ partD8) {
  int t = blockIdx.x, tid = threadIdx.x;
  const int* hd = histD8 + t * N_ENT;
  int base = tid * 80;                       // 256*80 >= 20000
  int s = 0;
  for (int i = 0; i < 80; ++i) {
    int idx = base + i;
    if (idx < N_ENT) s += hd[idx];
  }
  partD8[t * 257 + tid] = s;
}

__global__ void scan_serial_all(int* __restrict__ partD8, const int* __restrict__ histR8,
                                int* __restrict__ startR8, int* __restrict__ posR8) {
  int t = blockIdx.x;
  int* pd = partD8 + t * 257;
  int run = 0;
  for (int i = 0; i < 256; ++i) { int v = pd[i]; pd[i] = run; run += v; }
  pd[256] = run;
  const int* hr = histR8 + t * N_REL;
  int* sr = startR8 + t * 257;
  int* pr = posR8 + t * N_REL;
  run = 0;
  for (int i = 0; i < 256; ++i) { int v = hr[i]; sr[i] = run; pr[i] = run; run += v; }
  sr[256] = run;
}

__global__ void scan_local_all(const int* __restrict__ histD8, const int* __restrict__ partD8,
                               int* __restrict__ startD8, int* __restrict__ posD8) {
  int t = blockIdx.x, tid = threadIdx.x;
  const int* hd = histD8 + t * N_ENT;
  int* sd = startD8 + t * (N_ENT + 1);
  int* pd = posD8 + t * N_ENT;
  int run = partD8[t * 257 + tid];
  int base = tid * 80;
  for (int i = 0; i < 80; ++i) {
    int idx = base + i;
    if (idx < N_ENT) {
      sd[idx] = run;
      pd[idx] = run;
      run += hd[idx];
    }
  }
  if (tid == 0) sd[N_ENT] = partD8[t * 257 + 256];
}

__global__ void scatter_all(const int* __restrict__ dst, const int* __restrict__ rel,
                            int* __restrict__ posD8, int* __restrict__ posR8,
                            int* __restrict__ edgeD8, int* __restrict__ edgeR8) {
  int e = blockIdx.x * 256 + threadIdx.x;
  int t = blockIdx.y;
  if (e >= NE) return;
  int p = atomicAdd(&posD8[t * N_ENT + dst[t * NE + e]], 1);
  edgeD8[t * NE + p] = e;
  int p2 = atomicAdd(&posR8[t * N_REL + rel[t * NE + e]], 1);
  edgeR8[t * NE + p2] = e;
}

// ---------------- seg-sum via CSR: one wave per output row (f32) -----------
__global__ __launch_bounds__(256)
void agg_rel_csr(const float* __restrict__ ent, const int* __restrict__ src,
                 const int* __restrict__ edgeR, const int* __restrict__ startR,
                 float* __restrict__ aggR, float* __restrict__ cntR) {
  int r = blockIdx.x * 4 + (threadIdx.x >> 6);
  if (r >= N_REL) return;
  int lane = threadIdx.x & 63;
  int s0 = startR[r], s1 = startR[r + 1];
  float4 a = make_float4(0.f, 0.f, 0.f, 0.f);
  float4 b = make_float4(0.f, 0.f, 0.f, 0.f);
  for (int i = s0; i < s1; ++i) {
    int e = edgeR[i];
    int s = src[e];
    const float4* p = (const float4*)(ent + (size_t)s * HD);
    float4 x = p[lane];
    float4 y = p[lane + 64];
    a.x += x.x; a.y += x.y; a.z += x.z; a.w += x.w;
    b.x += y.x; b.y += y.y; b.z += y.z; b.w += y.w;
  }
  float4* op = (float4*)(aggR + (size_t)r * HD);
  op[lane] = a;
  op[lane + 64] = b;
  if (lane == 0) cntR[r] = (float)(s1 - s0);
}

__global__ __launch_bounds__(256)
void agg_ent_csr(const float* __restrict__ h, const float* __restrict__ relh,
                 const int* __restrict__ src, const int* __restrict__ erel,
                 const int* __restrict__ edgeD, const int* __restrict__ startD,
                 float* __restrict__ aggE, float* __restrict__ cntE) {
  int d = blockIdx.x * 4 + (threadIdx.x >> 6);
  if (d >= N_ENT) return;
  int lane = threadIdx.x & 63;
  int s0 = startD[d], s1 = startD[d + 1];
  float4 a = make_float4(0.f, 0.f, 0.f, 0.f);
  float4 b = make_float4(0.f, 0.f, 0.f, 0.f);
  for (int i = s0; i < s1; ++i) {
    int e = edgeD[i];
    int s = src[e], r = erel[e];
    const float4* hp = (const float4*)(h + (size_t)s * HD);
    const float4* rp = (const float4*)(relh + (size_t)r * HD);
    float4 x = hp[lane];
    float4 y = hp[lane + 64];
    float4 u = rp[lane];
    float4 v = rp[lane + 64];
    a.x += x.x + u.x; a.y += x.y + u.y; a.z += x.z + u.z; a.w += x.w + u.w;
    b.x += y.x + v.x; b.y += y.y + v.y; b.z += y.z + v.z; b.w += y.w + v.w;
  }
  float4* op = (float4*)(aggE + (size_t)d * HD);
  op[lane] = a;
  op[lane + 64] = b;
  if (lane == 0) cntE[d] = (float)(s1 - s0);
}

// ---------------- GRU elementwise (+bias fold, +bf16 mirror) ---------------
__global__ void gru_kernel(const float* __restrict__ gi, const float* __restrict__ gh,
                           const float* __restrict__ bih, const float* __restrict__ bhh,
                           float* __restrict__ relh, unsigned short* __restrict__ relhb) {
  int i = blockIdx.x * blockDim.x + threadIdx.x;
  if (i >= N_REL * HD) return;
  int row = i >> 9, col = i & 511;
  const float* gir = gi + (size_t)row * 1536;
  const float* ghr = gh + (size_t)row * 1536;
  float ir = gir[col] + bih[col];
  float iz = gir[col + 512] + bih[col + 512];
  float inn = gir[col + 1024] + bih[col + 1024];
  float hr = ghr[col] + bhh[col];
  float hz = ghr[col + 512] + bhh[col + 512];
  float hn = ghr[col + 1024] + bhh[col + 1024];
  float r = sigmoidf_(ir + hr);
  float z = sigmoidf_(iz + hz);
  float n = tanhf(inn + r * hn);
  float v = (1.0f - z) * n + z * relh[i];
  relh[i] = v;
  relhb[i] = f2bf(v);
}

// ---------------- gather rows (f32) ----------------------------------------
__global__ void gather_kernel(const float* __restrict__ table, const int* __restrict__ idx,
                              float* __restrict__ out, int rows) {
  int i = blockIdx.x * blockDim.x + threadIdx.x;
  if (i >= rows * (HD / 4)) return;
  int row = i >> 7, q = i & 127;
  ((float4*)out)[i] = ((const float4*)(table + (size_t)idx[row] * HD))[q];
}

// ---------------- flat f32 -> bf16 convert (n multiple of 8) ---------------
__global__ void f2b_kernel(const float* __restrict__ in, unsigned short* __restrict__ out, int n) {
  int i = blockIdx.x * blockDim.x + threadIdx.x;
  if (i * 8 >= n) return;
  float4 a = *(const float4*)&in[i * 8];
  float4 b = *(const float4*)&in[i * 8 + 4];
  u16x8 pk = {f2bf(a.x), f2bf(a.y), f2bf(a.z), f2bf(a.w),
              f2bf(b.x), f2bf(b.y), f2bf(b.z), f2bf(b.w)};
  *(u16x8*)&out[i * 8] = pk;
}

// ---------------------------------------------------------------------------
// pack_nn: B (KxN f32 row-major) -> bf16 LDS-image layout:
// step s (32 k): idx = (s*N + n)*32 + ((g ^ ((n>>2)&3))<<3) + j  holds
// B[s*32 + g*8 + j][n].
// ---------------------------------------------------------------------------
__global__ void pack_nn_kernel(const float* __restrict__ B, unsigned short* __restrict__ out,
                               int K, int N) {
  int id = blockIdx.x * 256 + threadIdx.x;
  if (id >= (K >> 3) * N) return;
  int s = id / (N * 4);
  int rem = id - s * (N * 4);
  int n = rem >> 2, g = rem & 3;
  const float* src = B + (size_t)(s * 32 + g * 8) * N + n;
  u16x8 pk;
  #pragma unroll
  for (int j = 0; j < 8; ++j) pk[j] = f2bf(src[(size_t)j * N]);
  *(u16x8*)&out[((size_t)s * N + n) * 32 + ((g ^ ((n >> 2) & 3)) << 3)] = pk;
}

// ---------------------------------------------------------------------------
// GEMM core: BK=32, 32KB LDS, depth-2 register-prefetch single-barrier bf16
// MFMA GEMM. A = [A0 (M x K0, f32, row-scaled by 1/max(cnt,1)) | A1 (bf16)].
// ACT: 0 plain, 1 relu(+mirror), 3 gate. NIT = K/32 (always even here).
// Accumulation order identical to BK=64 version (same k-step sequence).
// ---------------------------------------------------------------------------
template <int ACT, int MIRROR>
static __device__ __forceinline__
void gemm_core(const float* __restrict__ A0, int K0, const float* __restrict__ cntA,
               const unsigned short* __restrict__ A1, int K1,
               const unsigned short* __restrict__ Bp,
               const float* __restrict__ bias, const float* __restrict__ D,
               float* __restrict__ C, unsigned short* __restrict__ Cb,
               int M, int N, int m0, int n0,
               unsigned short (*As)[4096], unsigned short (*Bs)[4096]) {
  const int tid = threadIdx.x;
  const int lane = tid & 63;
  const int wv = tid >> 6;
  const int wm = wv >> 1, wn = wv & 1;
  const int lr = lane & 15, lg = lane >> 4;
  const int arow = tid >> 1;
  const int ahalf = tid & 1;                 // which 16-k half of the 32-k step
  const int NIT = (K0 + K1) >> 5;

  float s0 = 1.0f;
  if (K0 > 0 && (m0 + arow) < M) s0 = 1.0f / fmaxf(cntA[m0 + arow], 1.0f);

  f32x4 acc[4][4];
  #pragma unroll
  for (int i = 0; i < 4; ++i)
    #pragma unroll
    for (int j = 0; j < 4; ++j) acc[i][j] = (f32x4){0.f, 0.f, 0.f, 0.f};

  auto gload = [&](int it, u16x8* ar, u16x8* br) {
    int mrow = m0 + arow;
    int kk = it * 32 + ahalf * 16;
    if (mrow < M) {
      if (kk < K0) {
        const float* p = A0 + (size_t)mrow * K0 + kk;
        #pragma unroll
        for (int q = 0; q < 2; ++q) {
          float4 x = *(const float4*)(p + q * 8);
          float4 y = *(const float4*)(p + q * 8 + 4);
          ar[q] = (u16x8){f2bf(x.x * s0), f2bf(x.y * s0), f2bf(x.z * s0), f2bf(x.w * s0),
                          f2bf(y.x * s0), f2bf(y.y * s0), f2bf(y.z * s0), f2bf(y.w * s0)};
        }
      } else {
        const unsigned short* p = A1 + (size_t)mrow * K1 + (kk - K0);
        #pragma unroll
        for (int q = 0; q < 2; ++q) ar[q] = *(const u16x8*)&p[q * 8];
      }
    } else {
      #pragma unroll
      for (int q = 0; q < 2; ++q) ar[q] = (u16x8){0, 0, 0, 0, 0, 0, 0, 0};
    }
    const unsigned short* b0 = Bp + ((size_t)it * N + n0) * 32;
    br[0] = *(const u16x8*)&b0[tid * 8];
    br[1] = *(const u16x8*)&b0[2048 + tid * 8];
  };
  auto swrite = [&](int nb, const u16x8* ar, const u16x8* br) {
    #pragma unroll
    for (int q = 0; q < 2; ++q) {
      int chunk = ahalf * 2 + q;            // 4 chunks of 8 per 32-k row
      *(u16x8*)&As[nb][arow * 32 + ((chunk ^ ((arow >> 1) & 3)) << 3)] = ar[q];
    }
    *(u16x8*)&Bs[nb][tid * 8] = br[0];
    *(u16x8*)&Bs[nb][2048 + tid * 8] = br[1];
  };
  auto mfma_phase = [&](int nb) {
    bf16x8 a[4], b[4];
    #pragma unroll
    for (int i = 0; i < 4; ++i) {
      int r = wm * 64 + i * 16 + lr;
      a[i] = *(const bf16x8*)&As[nb][r * 32 + ((lg ^ ((r >> 1) & 3)) << 3)];
      int nl = wn * 64 + i * 16 + lr;
      b[i] = *(const bf16x8*)&Bs[nb][nl * 32 + ((lg ^ ((nl >> 2) & 3)) << 3)];
    }
    #pragma unroll
    for (int i = 0; i < 4; ++i)
      #pragma unroll
      for (int j = 0; j < 4; ++j)
        acc[i][j] = __builtin_amdgcn_mfma_f32_16x16x32_bf16(a[i], b[j], acc[i][j], 0, 0, 0);
  };

  // depth-2 prologue: it0 -> LDS[0]; it1 -> reg set S1
  u16x8 ar0[2], br0[2], ar1[2], br1[2];
  gload(0, ar0, br0);
  swrite(0, ar0, br0);
  gload(1, ar1, br1);
  __syncthreads();

  int cur = 0;
  for (int itp = 0; itp < NIT; itp += 2) {
    if (itp + 2 < NIT) gload(itp + 2, ar0, br0);
    mfma_phase(cur);
    swrite(cur ^ 1, ar1, br1);              // itp+1 (< NIT since NIT even)
    __syncthreads();
    cur ^= 1;
    if (itp + 3 < NIT) gload(itp + 3, ar1, br1);
    mfma_phase(cur);
    if (itp + 2 < NIT) swrite(cur ^ 1, ar0, br0);
    __syncthreads();
    cur ^= 1;
  }

  #pragma unroll
  for (int i = 0; i < 4; ++i) {
    int m = m0 + wm * 64 + i * 16 + lg * 4;
    #pragma unroll
    for (int j = 0; j < 4; ++j) {
      int n = n0 + wn * 64 + j * 16 + lr;
      #pragma unroll
      for (int q = 0; q < 4; ++q) {
        int mr = m + q;
        if (mr >= M) continue;
        size_t o = (size_t)mr * N + n;
        float v = acc[i][j][q];
        if (ACT == 0) {
          C[o] = v;
        } else if (ACT == 1) {
          float rr = fmaxf(v, 0.0f);
          C[o] = rr;
          if (MIRROR) Cb[o] = f2bf(rr);
        } else {
          float u_ = sigmoidf_(v + bias[n]);
          float rr = u_ * D[o] + (1.0f - u_) * C[o];
          C[o] = rr;
          if (MIRROR) Cb[o] = f2bf(rr);
        }
      }
    }
  }
}

template <int ACT, int MIRROR>
__global__ __launch_bounds__(256, 3)
void gemm_nn2(const float* __restrict__ A0, int K0, const float* __restrict__ cntA,
              const unsigned short* __restrict__ A1, int K1,
              const unsigned short* __restrict__ Bp,
              const float* __restrict__ bias, const float* __restrict__ D,
              float* __restrict__ C, unsigned short* __restrict__ Cb, int M, int N) {
  __shared__ unsigned short As[2][4096];
  __shared__ unsigned short Bs[2][4096];
  gemm_core<ACT, MIRROR>(A0, K0, cntA, A1, K1, Bp, bias, D, C, Cb, M, N,
                         blockIdx.x * 128, blockIdx.y * 128, As, Bs);
}

// Fused GRU GEMMs: z=0 -> gi = [aggR/cnt | rel_bf] @ wp_ih; z=1 -> gh = relh_bf @ wp_hh
__global__ __launch_bounds__(256, 3)
void gru_gemms(const float* __restrict__ aggR, const float* __restrict__ cntR,
               const unsigned short* __restrict__ rel_bf,
               const unsigned short* __restrict__ relh_bf,
               const unsigned short* __restrict__ wp_ih,
               const unsigned short* __restrict__ wp_hh,
               float* __restrict__ gi, float* __restrict__ gh) {
  __shared__ unsigned short As[2][4096];
  __shared__ unsigned short Bs[2][4096];
  if (blockIdx.z == 0)
    gemm_core<0, 0>(aggR, 512, cntR, rel_bf, 512, wp_ih, nullptr, nullptr,
                    gi, nullptr, N_REL, 1536, blockIdx.x * 128, blockIdx.y * 128, As, Bs);
  else
    gemm_core<0, 0>(nullptr, 0, nullptr, relh_bf, 512, wp_hh, nullptr, nullptr,
                    gh, nullptr, N_REL, 1536, blockIdx.x * 128, blockIdx.y * 128, As, Bs);
}

// ---------------------------------------------------------------------------
// pack_fw: fw (32768x512 f32) -> bf16 image (same layout as pack_nn, N=512)
// ---------------------------------------------------------------------------
__global__ __launch_bounds__(256)
void pack_fw_kernel(const float* __restrict__ f0, const float* __restrict__ f1,
                    const float* __restrict__ f2, const float* __restrict__ f3,
                    unsigned short* __restrict__ o0, unsigned short* __restrict__ o1,
                    unsigned short* __restrict__ o2, unsigned short* __restrict__ o3) {
  __shared__ float L[32][512];
  const float* fw; unsigned short* op;
  switch (blockIdx.y) {
    case 0: fw = f0; op = o0; break;
    case 1: fw = f1; op = o1; break;
    case 2: fw = f2; op = o2; break;
    default: fw = f3; op = o3; break;
  }
  int s = blockIdx.x, tid = threadIdx.x;
  #pragma unroll
  for (int i = 0; i < 16; ++i) {
    int idx = tid + 256 * i;
    int r = idx >> 7, cq = (idx & 127) << 2;
    *(float4*)&L[r][cq] = *(const float4*)&fw[(size_t)(s * 32 + r) * 512 + cq];
  }
  __syncthreads();
  #pragma unroll
  for (int ii = 0; ii < 8; ++ii) {
    int slot = tid + 256 * ii;
    int n = slot >> 2, g = slot & 3;
    u16x8 pk;
    #pragma unroll
    for (int j = 0; j < 8; ++j) pk[j] = f2bf(L[g * 8 + j][n]);
    size_t off = (size_t)s * 16384 + n * 32 + ((g ^ ((n >> 2) & 3)) << 3);
    *(u16x8*)&op[off] = pk;
  }
}

// ---------------------------------------------------------------------------
// convgen: conv1d('SAME',K=3)+relu -> A_conv bf16 [NB][c*512+h], both paths.
// ---------------------------------------------------------------------------
template <int CIN>
__global__ __launch_bounds__(256)
void convgen_kernel(const float* __restrict__ X0e, const float* __restrict__ X1e,
                    const float* __restrict__ X2e,
                    const float* __restrict__ cwE, const float* __restrict__ cbE,
                    const float* __restrict__ X0r, const float* __restrict__ X1r,
                    const float* __restrict__ X2r,
                    const float* __restrict__ cwR, const float* __restrict__ cbR,
                    unsigned short* __restrict__ Ae, unsigned short* __restrict__ Ar) {
  __shared__ float wsm[64 * CIN * 3];
  __shared__ float bsm[64];
  const int path = blockIdx.y;
  const float* X[CIN]; const float* cw; const float* cb; unsigned short* A;
  if (path == 0) {
    X[0] = X0e; X[1] = X1e; if constexpr (CIN == 3) X[2] = X2e;
    cw = cwE; cb = cbE; A = Ae;
  } else {
    X[0] = X0r; X[1] = X1r; if constexpr (CIN == 3) X[2] = X2r;
    cw = cwR; cb = cbR; A = Ar;
  }
  const int tid = threadIdx.x;
  for (int i = tid; i < 64 * CIN * 3; i += 256) wsm[i] = cw[i];
  if (tid < 64) bsm[tid] = cb[tid];
  __syncthreads();

  const int o = tid & 63;
  const int b = blockIdx.x * 4 + (tid >> 6);
  const int h = o * 8;

  float xm[CIN][8], xl[CIN], xr[CIN];
  #pragma unroll
  for (int ci = 0; ci < CIN; ++ci) {
    const float* row = X[ci] + (size_t)b * HD + h;
    float4 a4 = *(const float4*)row;
    float4 b4 = *(const float4*)(row + 4);
    xm[ci][0] = a4.x; xm[ci][1] = a4.y; xm[ci][2] = a4.z; xm[ci][3] = a4.w;
    xm[ci][4] = b4.x; xm[ci][5] = b4.y; xm[ci][6] = b4.z; xm[ci][7] = b4.w;
    xl[ci] = (h > 0) ? row[-1] : 0.f;
    xr[ci] = (h + 8 < HD) ? row[8] : 0.f;
  }
  unsigned short* dst = A + (size_t)b * 32768 + h;
  for (int c = 0; c < 64; ++c) {
    float v[8];
    float cbv = bsm[c];
    #pragma unroll
    for (int e = 0; e < 8; ++e) v[e] = cbv;
    #pragma unroll
    for (int ci = 0; ci < CIN; ++ci) {
      float w0 = wsm[(c * CIN + ci) * 3 + 0];
      float w1 = wsm[(c * CIN + ci) * 3 + 1];
      float w2 = wsm[(c * CIN + ci) * 3 + 2];
      #pragma unroll
      for (int e = 0; e < 8; ++e) {
        float lft = e ? xm[ci][e - 1] : xl[ci];
        float rgt = (e < 7) ? xm[ci][e + 1] : xr[ci];
        v[e] = fmaf(lft, w0, fmaf(xm[ci][e], w1, fmaf(rgt, w2, v[e])));
      }
    }
    u16x8 pk;
    #pragma unroll
    for (int e = 0; e < 8; ++e) pk[e] = f2bf(fmaxf(v[e], 0.f));
    *(u16x8*)&dst[c * 512] = pk;
  }
}

// ---------------------------------------------------------------------------
// gemm_fc: part[path][ks] = A_conv(4096 x 32768 bf16) @ fw-image, KSPLIT=4.
// Depth-2 register prefetch (static set selection via unroll-by-2). BK=64.
// ---------------------------------------------------------------------------
__global__ __launch_bounds__(256, 2)
void gemm_fc(const unsigned short* __restrict__ Abuf,
             const unsigned short* __restrict__ fwpE,
             const unsigned short* __restrict__ fwpR,
             float* __restrict__ partBase) {
  __shared__ unsigned short As[2][128 * 64];
  __shared__ unsigned short Bs[2][2 * 128 * 32];
  const int tid = threadIdx.x;
  const int lane = tid & 63;
  const int wv = tid >> 6;
  const int wm = wv >> 1, wn = wv & 1;
  const int lr = lane & 15, lg = lane >> 4;
  const int m0 = blockIdx.x * 128;
  const int n0 = blockIdx.y * 128;
  const int path = blockIdx.z >> 2;
  const int ks = blockIdx.z & 3;

  const unsigned short* A = Abuf + (size_t)path * ((size_t)NB * 32768);
  const unsigned short* fwp = (path == 0) ? fwpE : fwpR;
  float* part = partBase + (size_t)(path * 4 + ks) * ((size_t)NB * HD);

  const int arow = tid >> 1;
  const int achunk = (tid & 1) * 4;
  const unsigned short* aRow = A + (size_t)(m0 + arow) * 32768 + ks * 8192 + achunk * 8;
  const unsigned short* bBase = fwp + (size_t)(ks * 256) * 16384 + (size_t)n0 * 32;

  f32x4 acc[4][4];
  #pragma unroll
  for (int i = 0; i < 4; ++i)
    #pragma unroll
    for (int j = 0; j < 4; ++j) acc[i][j] = (f32x4){0.f, 0.f, 0.f, 0.f};

  auto gload = [&](int it, u16x8* ar, u16x8* br) {
    const unsigned short* ap = aRow + it * 64;
    #pragma unroll
    for (int q = 0; q < 4; ++q) ar[q] = *(const u16x8*)&ap[q * 8];
    const unsigned short* bp = bBase + (size_t)it * 2 * 16384;
    br[0] = *(const u16x8*)&bp[tid * 8];
    br[1] = *(const u16x8*)&bp[2048 + tid * 8];
    br[2] = *(const u16x8*)&bp[16384 + tid * 8];
    br[3] = *(const u16x8*)&bp[16384 + 2048 + tid * 8];
  };
  auto swrite = [&](int nb, const u16x8* ar, const u16x8* br) {
    #pragma unroll
    for (int q = 0; q < 4; ++q) {
      int chunk = achunk + q;
      *(u16x8*)&As[nb][arow * 64 + ((chunk ^ (arow & 7)) << 3)] = ar[q];
    }
    *(u16x8*)&Bs[nb][tid * 8] = br[0];
    *(u16x8*)&Bs[nb][2048 + tid * 8] = br[1];
    *(u16x8*)&Bs[nb][4096 + tid * 8] = br[2];
    *(u16x8*)&Bs[nb][4096 + 2048 + tid * 8] = br[3];
  };
  auto mfma_phase = [&](int nb) {
    bf16x8 af[2][4], bfr[2][4];
    #pragma unroll
    for (int u = 0; u < 2; ++u)
      #pragma unroll
      for (int i = 0; i < 4; ++i) {
        int r = wm * 64 + i * 16 + lr;
        af[u][i] = *(const bf16x8*)&As[nb][r * 64 + (((u * 4 + lg) ^ (r & 7)) << 3)];
        int nl = wn * 64 + i * 16 + lr;
        bfr[u][i] = *(const bf16x8*)&Bs[nb][u * 4096 + nl * 32 + ((lg ^ ((nl >> 2) & 3)) << 3)];
      }
    #pragma unroll
    for (int u = 0; u < 2; ++u)
      #pragma unroll
      for (int i = 0; i < 4; ++i)
        #pragma unroll
        for (int j = 0; j < 4; ++j)
          acc[i][j] = __builtin_amdgcn_mfma_f32_16x16x32_bf16(af[u][i], bfr[u][j], acc[i][j], 0, 0, 0);
  };

  u16x8 ar0[4], br0[4], ar1[4], br1[4];
  gload(0, ar0, br0);
  swrite(0, ar0, br0);
  gload(1, ar1, br1);
  __syncthreads();

  int cur = 0;
  for (int itp = 0; itp < 128; itp += 2) {
    if (itp + 2 < 128) gload(itp + 2, ar0, br0);
    mfma_phase(cur);
    swrite(cur ^ 1, ar1, br1);
    __syncthreads();
    cur ^= 1;
    if (itp + 3 < 128) gload(itp + 3, ar1, br1);
    mfma_phase(cur);
    if (itp + 2 < 128) swrite(cur ^ 1, ar0, br0);
    __syncthreads();
    cur ^= 1;
  }

  #pragma unroll
  for (int i = 0; i < 4; ++i) {
    int m = m0 + wm * 64 + i * 16 + lg * 4;
    #pragma unroll
    for (int j = 0; j < 4; ++j) {
      int n = n0 + wn * 64 + j * 16 + lr;
      #pragma unroll
      for (int q = 0; q < 4; ++q)
        part[(size_t)(m + q) * HD + n] = acc[i][j][q];
    }
  }
}

// ---------------------------------------------------------------------------
// reduce 4 split-K partials + bias + relu -> f32 out AND bf16 out
// ---------------------------------------------------------------------------
__global__ void reduce4_kernel(const float* __restrict__ pE, const float* __restrict__ pR,
                               const float* __restrict__ bE, const float* __restrict__ bR,
                               float* __restrict__ oE, float* __restrict__ oR,
                               unsigned short* __restrict__ obE, unsigned short* __restrict__ obR) {
  int p = blockIdx.y;
  const float* part = p ? pR : pE;
  const float* bias = p ? bR : bE;
  float* o = p ? oR : oE;
  unsigned short* ob = p ? obR : obE;
  int i = blockIdx.x * 256 + threadIdx.x;
  int col = (i << 2) & 511;
  float4 s = *(const float4*)&part[(size_t)i * 4];
  #pragma unroll
  for (int ks = 1; ks < 4; ++ks) {
    float4 t = *(const float4*)&part[(size_t)ks * (NB * HD) + i * 4];
    s.x += t.x; s.y += t.y; s.z += t.z; s.w += t.w;
  }
  float4 b4 = *(const float4*)&bias[col];
  s.x = fmaxf(s.x + b4.x, 0.f); s.y = fmaxf(s.y + b4.y, 0.f);
  s.z = fmaxf(s.z + b4.z, 0.f); s.w = fmaxf(s.w + b4.w, 0.f);
  *(float4*)&o[(size_t)i * 4] = s;
  u16x4 pk = {f2bf(s.x), f2bf(s.y), f2bf(s.z), f2bf(s.w)};
  *(u16x4*)&ob[(size_t)i * 4] = pk;
}

// ---------------------------------------------------------------------------
// bf16 NT GEMM: C(MxN, f32) = A(MxK) @ B(NxK)^T, bf16 row-major; depth-2
// register-prefetch single-barrier pipeline. K=512 -> NIT=8. N-tail guarded.
// ---------------------------------------------------------------------------
__global__ __launch_bounds__(256, 2)
void gemm_nt_bf16(const unsigned short* __restrict__ A, const unsigned short* __restrict__ B,
                  float* __restrict__ C, int M, int N, int K) {
  __shared__ unsigned short As[2][8192];
  __shared__ unsigned short Bs[2][8192];
  const int tid = threadIdx.x;
  const int lane = tid & 63;
  const int wv = tid >> 6;
  const int wm = wv >> 1, wn = wv & 1;
  const int m0 = blockIdx.x * 128, n0 = blockIdx.y * 128;
  const int lr = lane & 15, lg = lane >> 4;
  const int row = tid >> 1, half = tid & 1;
  const int nrow = n0 + row;
  const int NIT = K >> 6;

  f32x4 acc[4][4];
  #pragma unroll
  for (int i = 0; i < 4; ++i)
    #pragma unroll
    for (int j = 0; j < 4; ++j) acc[i][j] = (f32x4){0.f, 0.f, 0.f, 0.f};

  auto gload = [&](int it, u16x8* ar, u16x8* br) {
    const unsigned short* asrc = A + (size_t)(m0 + row) * K + it * 64 + half * 32;
    #pragma unroll
    for (int q = 0; q < 4; ++q) ar[q] = *(const u16x8*)&asrc[q * 8];
    const unsigned short* bsrc = B + (size_t)nrow * K + it * 64 + half * 32;
    u16x8 z = {0, 0, 0, 0, 0, 0, 0, 0};
    #pragma unroll
    for (int q = 0; q < 4; ++q) br[q] = (nrow < N) ? *(const u16x8*)&bsrc[q * 8] : z;
  };
  auto swrite = [&](int nb, const u16x8* ar, const u16x8* br) {
    #pragma unroll
    for (int q = 0; q < 4; ++q) {
      int chunk = half * 4 + q;
      *(u16x8*)&As[nb][row * 64 + ((chunk ^ (row & 7)) << 3)] = ar[q];
      *(u16x8*)&Bs[nb][row * 64 + ((chunk ^ (row & 7)) << 3)] = br[q];
    }
  };
  auto mfma_phase = [&](int nb) {
    #pragma unroll
    for (int u = 0; u < 2; ++u) {
      bf16x8 a[4], b[4];
      #pragma unroll
      for (int i = 0; i < 4; ++i) {
        int r = wm * 64 + i * 16 + lr;
        a[i] = *(const bf16x8*)&As[nb][r * 64 + (((u * 4 + lg) ^ (r & 7)) << 3)];
        int n = wn * 64 + i * 16 + lr;
        b[i] = *(const bf16x8*)&Bs[nb][n * 64 + (((u * 4 + lg) ^ (n & 7)) << 3)];
      }
      #pragma unroll
      for (int i = 0; i < 4; ++i)
        #pragma unroll
        for (int j = 0; j < 4; ++j)
          acc[i][j] = __builtin_amdgcn_mfma_f32_16x16x32_bf16(a[i], b[j], acc[i][j], 0, 0, 0);
    }
  };

  u16x8 ar0[4], br0[4], ar1[4], br1[4];
  gload(0, ar0, br0);
  swrite(0, ar0, br0);
  gload(1, ar1, br1);
  __syncthreads();

  int cur = 0;
  for (int itp = 0; itp < NIT; itp += 2) {
    if (itp + 2 < NIT) gload(itp + 2, ar0, br0);
    mfma_phase(cur);
    swrite(cur ^ 1, ar1, br1);
    __syncthreads();
    cur ^= 1;
    if (itp + 3 < NIT) gload(itp + 3, ar1, br1);
    mfma_phase(cur);
    if (itp + 2 < NIT) swrite(cur ^ 1, ar0, br0);
    __syncthreads();
    cur ^= 1;
  }

  #pragma unroll
  for (int i = 0; i < 4; ++i) {
    int m = m0 + wm * 64 + i * 16 + lg * 4;
    #pragma unroll
    for (int j = 0; j < 4; ++j) {
      int n = n0 + wn * 64 + j * 16 + lr;
      if (n < N) {
        #pragma unroll
        for (int q = 0; q < 4; ++q)
          C[(size_t)(m + q) * N + n] = acc[i][j][q];
      }
    }
  }
}

// ---------------------------------------------------------------------------
extern "C" void kernel_launch(void* const* d_in, const int* in_sizes, int n_in,
                              void* d_out, int out_size, void* d_ws, size_t ws_size,
                              hipStream_t stream) {
  const float* ent_embeds = (const float*)d_in[0];
  const float* rel_embeds = (const float*)d_in[1];
  const float* W_msg  = (const float*)d_in[2];
  const float* W_self = (const float*)d_in[3];
  const float* gru_Wih = (const float*)d_in[4];
  const float* gru_Whh = (const float*)d_in[5];
  const float* gru_bih = (const float*)d_in[6];
  const float* gru_bhh = (const float*)d_in[7];
  const float* gate_W = (const float*)d_in[8];
  const float* gate_b = (const float*)d_in[9];
  const float* e_conv1 = (const float*)d_in[10]; const float* e_cb1 = (const float*)d_in[11];
  const float* e_fc1   = (const float*)d_in[12]; const float* e_fb1 = (const float*)d_in[13];
  const float* e_conv2 = (const float*)d_in[14]; const float* e_cb2 = (const float*)d_in[15];
  const float* e_fc2   = (const float*)d_in[16]; const float* e_fb2 = (const float*)d_in[17];
  const float* r_conv1 = (const float*)d_in[18]; const float* r_cb1 = (const float*)d_in[19];
  const float* r_fc1   = (const float*)d_in[20]; const float* r_fb1 = (const float*)d_in[21];
  const float* r_conv2 = (const float*)d_in[22]; const float* r_cb2 = (const float*)d_in[23];
  const float* r_fc2   = (const float*)d_in[24]; const float* r_fb2 = (const float*)d_in[25];
  const int* src  = (const int*)d_in[26];
  const int* dst  = (const int*)d_in[27];
  const int* erel = (const int*)d_in[28];
  const int* subj = (const int*)d_in[29];
  const int* rel  = (const int*)d_in[30];
  const int* obj  = (const int*)d_in[31];
  float* out = (float*)d_out;

  // -------- workspace layout --------
  float* w = (float*)d_ws;
  float* ent   = w; w += (size_t)N_ENT * HD;
  float* relh  = w; w += (size_t)N_REL * HD;
  float* aggR  = w; w += (size_t)N_REL * HD;
  float* cntR  = w; w += N_REL;
  float* gi    = w; w += (size_t)N_REL * 1536;
  float* gh    = w; w += (size_t)N_REL * 1536;
  float* aggE  = w; w += (size_t)N_ENT * HD;     // } aggE..h1b reused post-loop as
  float* cntE  = w; w += N_ENT;                  // } packed-fw storage
  float* tmp   = w; w += (size_t)N_ENT * HD;
  float* h0b   = w; w += (size_t)N_ENT * HD;
  float* h1b   = w; w += (size_t)N_ENT * HD;
  float* se    = w; w += (size_t)NB * HD;
  float* re_   = w; w += (size_t)NB * HD;
  float* oe    = w; w += (size_t)NB * HD;
  float* o1    = w; w += (size_t)NB * HD;
  float* q1    = w; w += (size_t)NB * HD;
  float* o2    = w; w += (size_t)NB * HD;
  float* q2    = w; w += (size_t)NB * HD;
  unsigned short* ent_bf  = (unsigned short*)w; w += (size_t)N_ENT * HD / 2;
  unsigned short* relh_bf = (unsigned short*)w; w += (size_t)N_REL * HD / 2;
  unsigned short* rel_bf  = (unsigned short*)w; w += (size_t)N_REL * HD / 2;
  unsigned short* h0b_bf  = (unsigned short*)w; w += (size_t)N_ENT * HD / 2;
  unsigned short* h1b_bf  = (unsigned short*)w; w += (size_t)N_ENT * HD / 2;
  unsigned short* o1b = (unsigned short*)w; w += (size_t)NB * HD / 2;
  unsigned short* q1b = (unsigned short*)w; w += (size_t)NB * HD / 2;
  unsigned short* o2b = (unsigned short*)w; w += (size_t)NB * HD / 2;
  unsigned short* q2b = (unsigned short*)w; w += (size_t)NB * HD / 2;
  // recurrence weight packs (bf16)
  unsigned short* wp_ih = (unsigned short*)w;            // 1024x1536
  unsigned short* wp_hh = wp_ih + (size_t)1024 * 1536;   // 512x1536
  unsigned short* wp_l0 = wp_hh + (size_t)512 * 1536;    // 1024x512
  unsigned short* wp_l1 = wp_l0 + (size_t)1024 * 512;    // 1024x512
  unsigned short* wp_g  = wp_l1 + (size_t)1024 * 512;    // 512x512
  w += ((size_t)1024 * 1536 + 512 * 1536 + 2 * 1024 * 512 + 512 * 512) / 2;
  // batched CSR buffers (int), all 8 timesteps
  int* histD8  = (int*)w;                       // 8 x 20000
  int* histR8  = histD8 + (size_t)NT * N_ENT;   // 8 x 256 (contiguous for zeroing)
  int* partD8  = histR8 + (size_t)NT * N_REL;   // 8 x 257
  int* startD8 = partD8 + (size_t)NT * 257;     // 8 x 20001
  int* posD8   = startD8 + (size_t)NT * (N_ENT + 1);  // 8 x 20000
  int* startR8 = posD8 + (size_t)NT * N_ENT;    // 8 x 257
  int* posR8   = startR8 + (size_t)NT * 257;    // 8 x 256
  int* edgeD8  = posR8 + (size_t)NT * N_REL;    // 8 x 30000
  int* edgeR8  = edgeD8 + (size_t)NT * NE;      // 8 x 30000
  // fw packs alias the recurrence temporaries (used only post-loop)
  unsigned short* fwp0 = (unsigned short*)aggE;
  unsigned short* fwp1 = fwp0 + (size_t)16777216;
  unsigned short* fwp2 = fwp1 + (size_t)16777216;
  unsigned short* fwp3 = fwp2 + (size_t)16777216;
  (void)tmp;
  // decoder scratch in d_out (written+consumed before logits):
  unsigned short* Abuf = (unsigned short*)out;          // 2 x NB x 32768 u16
  float* pE = out + (size_t)2 * NB * 32768 / 2;         // f32 offset after Abuf
  float* pR = pE + (size_t)4 * NB * HD;

  const dim3 g_gru(2, 12, 2);  // 256 x 1536, z = {gi, gh}
  const dim3 g_ent(157, 4);    // 20000 x 512

  // -------- weight packing (once) --------
  {
    int t;
    t = (1024 * 1536) / 8; pack_nn_kernel<<<(t + 255) / 256, 256, 0, stream>>>(gru_Wih, wp_ih, 1024, 1536);
    t = (512 * 1536) / 8;  pack_nn_kernel<<<(t + 255) / 256, 256, 0, stream>>>(gru_Whh, wp_hh, 512, 1536);
    t = (512 * 512) / 8;
    pack_nn_kernel<<<(t + 255) / 256, 256, 0, stream>>>(W_msg, wp_l0, 512, 512);
    pack_nn_kernel<<<(t + 255) / 256, 256, 0, stream>>>(W_self, wp_l0 + (size_t)512 * 512, 512, 512);
    pack_nn_kernel<<<(t + 255) / 256, 256, 0, stream>>>(W_msg + (size_t)512 * 512, wp_l1, 512, 512);
    pack_nn_kernel<<<(t + 255) / 256, 256, 0, stream>>>(W_self + (size_t)512 * 512, wp_l1 + (size_t)512 * 512, 512, 512);
    pack_nn_kernel<<<(t + 255) / 256, 256, 0, stream>>>(gate_W, wp_g, 512, 512);
  }

  // -------- batched CSR build for all 8 timesteps (independent of state) ----
  zero_hist_all<<<(NT * (N_ENT + N_REL) + 255) / 256, 256, 0, stream>>>(histD8);
  hist_all<<<dim3((NE + 255) / 256, NT), 256, 0, stream>>>(dst, erel, histD8, histR8);
  scan_part_all<<<NT, 256, 0, stream>>>(histD8, partD8);
  scan_serial_all<<<NT, 1, 0, stream>>>(partD8, histR8, startR8, posR8);
  scan_local_all<<<NT, 256, 0, stream>>>(histD8, partD8, startD8, posD8);
  scatter_all<<<dim3((NE + 255) / 256, NT), 256, 0, stream>>>(dst, erel, posD8, posR8,
                                                              edgeD8, edgeR8);

  // -------- init --------
  rownorm_kernel<<<N_ENT / 4, 256, 0, stream>>>(ent_embeds, ent, ent_bf, N_ENT);
  hipMemcpyAsync(relh, rel_embeds, (size_t)N_REL * HD * 4, hipMemcpyDeviceToDevice, stream);
  f2b_kernel<<<(N_REL * HD / 8) / 256, 256, 0, stream>>>(rel_embeds, rel_bf, N_REL * HD);
  f2b_kernel<<<(N_REL * HD / 8) / 256, 256, 0, stream>>>(rel_embeds, relh_bf, N_REL * HD);

  // -------- timestep loop --------
  for (int t = 0; t < NT; ++t) {
    const int* st = src + t * NE;
    const int* rt = erel + t * NE;
    const int* edgeD = edgeD8 + (size_t)t * NE;
    const int* edgeR = edgeR8 + (size_t)t * NE;
    const int* startD = startD8 + (size_t)t * (N_ENT + 1);
    const int* startR = startR8 + (size_t)t * 257;

    // relation evolution
    agg_rel_csr<<<N_REL / 4, 256, 0, stream>>>(ent, st, edgeR, startR, aggR, cntR);
    gru_gemms<<<g_gru, 256, 0, stream>>>(aggR, cntR, rel_bf, relh_bf, wp_ih, wp_hh, gi, gh);
    gru_kernel<<<(N_REL * HD) / 256, 256, 0, stream>>>(gi, gh, gru_bih, gru_bhh, relh, relh_bf);

    // entity evolution: h = relu([mean-agg | h] @ [Wmsg;Wself]) per layer
    agg_ent_csr<<<N_ENT / 4, 256, 0, stream>>>(ent, relh, st, rt, edgeD, startD, aggE, cntE);
    gemm_nn2<1, 1><<<g_ent, 256, 0, stream>>>(aggE, 512, cntE, ent_bf, 512, wp_l0,
                                              nullptr, nullptr, h0b, h0b_bf, N_ENT, 512);
    agg_ent_csr<<<N_ENT / 4, 256, 0, stream>>>(h0b, relh, st, rt, edgeD, startD, aggE, cntE);
    gemm_nn2<1, 0><<<g_ent, 256, 0, stream>>>(aggE, 512, cntE, h0b_bf, 512, wp_l1,
                                              nullptr, nullptr, h1b, nullptr, N_ENT, 512);
    rownorm_kernel<<<N_ENT / 4, 256, 0, stream>>>(h1b, h1b, h1b_bf, N_ENT);
    gemm_nn2<3, 1><<<g_ent, 256, 0, stream>>>(nullptr, 0, nullptr, h1b_bf, 512, wp_g,
                                              gate_b, h1b, ent, ent_bf, N_ENT, 512);
  }

  // -------- decoder prep --------
  pack_fw_kernel<<<dim3(1024, 4), 256, 0, stream>>>(e_fc1, r_fc1, e_fc2, r_fc2,
                                                    fwp0, fwp1, fwp2, fwp3);
  gather_kernel<<<(NB * HD / 4) / 256, 256, 0, stream>>>(ent, subj, se, NB);
  gather_kernel<<<(NB * HD / 4) / 256, 256, 0, stream>>>(relh, rel, re_, NB);
  gather_kernel<<<(NB * HD / 4) / 256, 256, 0, stream>>>(ent, obj, oe, NB);

  unsigned short* A_E = Abuf;
  unsigned short* A_R = Abuf + (size_t)NB * 32768;

  // -------- decoder stage 1 --------
  convgen_kernel<2><<<dim3(NB / 4, 2), 256, 0, stream>>>(
      se, re_, nullptr, e_conv1, e_cb1,
      se, oe, nullptr, r_conv1, r_cb1, A_E, A_R);
  gemm_fc<<<dim3(32, 4, 8), 256, 0, stream>>>(Abuf, fwp0, fwp1, pE);
  reduce4_kernel<<<dim3(NB * HD / 4 / 256, 2), 256, 0, stream>>>(
      pE, pR, e_fb1, r_fb1, o1, q1, o1b, q1b);

  // -------- decoder stage 2 --------
  convgen_kernel<3><<<dim3(NB / 4, 2), 256, 0, stream>>>(
      o1, se, re_, e_conv2, e_cb2,
      q1, se, oe, r_conv2, r_cb2, A_E, A_R);
  gemm_fc<<<dim3(32, 4, 8), 256, 0, stream>>>(Abuf, fwp2, fwp3, pE);
  reduce4_kernel<<<dim3(NB * HD / 4 / 256, 2), 256, 0, stream>>>(
      pE, pR, e_fb2, r_fb2, o2, q2, o2b, q2b);

  // -------- logits (bf16 MFMA) --------
  size_t off0 = 0;
  size_t off1 = (size_t)NB * N_ENT;
  size_t off2 = off1 + (size_t)NB * N_REL;
  size_t off3 = off2 + (size_t)NB * N_ENT;
  gemm_nt_bf16<<<dim3(32, 157), 256, 0, stream>>>(o1b, ent_bf, out + off0, NB, N_ENT, HD);
  gemm_nt_bf16<<<dim3(32, 2), 256, 0, stream>>>(q1b, relh_bf, out + off1, NB, N_REL, HD);
  gemm_nt_bf16<<<dim3(32, 157), 256, 0, stream>>>(o2b, ent_bf, out + off2, NB, N_ENT, HD);
  gemm_nt_bf16<<<dim3(32, 2), 256, 0, stream>>>(q2b, relh_bf, out + off3, NB, N_REL, HD);
}

// Round 13
// 4100.430 us; speedup vs baseline: 1.3015x; 1.0082x over previous
//
#include <hip/hip_runtime.h>
#include <math.h>

// ---------------------------------------------------------------------------
// Refine (RE-GCN style): bf16-MFMA recurrence + decoder; f32 state with bf16
// mirrors. Batched CSR segment-means. gemm_core BK=32 / 3 blocks/CU, depth-2
// reg prefetch. Row-norm fused into layer-1 (partial sumsq out) and gate
// (scale-on-stage) GEMMs -> no in-loop rownorm kernel. Logit GEMMs merged
// into 2 launches via z-dim.
// N_ENT=20000 N_REL=256 H=512 C=64 K=3 L=2 T=8 E=30000 B=4096
// ---------------------------------------------------------------------------

#define N_ENT 20000
#define N_REL 256
#define HD    512
#define NE    30000
#define NB    4096
#define NT    8

typedef __attribute__((ext_vector_type(8))) short          bf16x8;
typedef __attribute__((ext_vector_type(4))) float          f32x4;
typedef __attribute__((ext_vector_type(8))) unsigned short u16x8;
typedef __attribute__((ext_vector_type(4))) unsigned short u16x4;

static __device__ __forceinline__ float sigmoidf_(float x) {
  return 1.0f / (1.0f + expf(-x));
}
static __device__ __forceinline__ unsigned short f2bf(float f) {  // RNE
  unsigned u = __float_as_uint(f);
  return (unsigned short)((u + 0x7FFFu + ((u >> 16) & 1u)) >> 16);
}

// ---------------- row L2 normalize + bf16 mirror (init only) ---------------
__global__ void rownorm_kernel(const float* __restrict__ in, float* __restrict__ out,
                               unsigned short* __restrict__ outb, int rows) {
  int wid = (blockIdx.x * blockDim.x + threadIdx.x) >> 6;
  int lane = threadIdx.x & 63;
  if (wid >= rows) return;
  const float4* ip = (const float4*)(in + (size_t)wid * HD);
  float4 v0 = ip[lane];
  float4 v1 = ip[lane + 64];
  float s = v0.x * v0.x + v0.y * v0.y + v0.z * v0.z + v0.w * v0.w
          + v1.x * v1.x + v1.y * v1.y + v1.z * v1.z + v1.w * v1.w;
  #pragma unroll
  for (int m = 1; m < 64; m <<= 1) s += __shfl_xor(s, m);
  float inv = 1.0f / (sqrtf(s) + 1e-8f);
  float4* op = (float4*)(out + (size_t)wid * HD);
  v0.x *= inv; v0.y *= inv; v0.z *= inv; v0.w *= inv;
  v1.x *= inv; v1.y *= inv; v1.z *= inv; v1.w *= inv;
  op[lane] = v0; op[lane + 64] = v1;
  unsigned short* ob = outb + (size_t)wid * HD;
  u16x4 p0 = {f2bf(v0.x), f2bf(v0.y), f2bf(v0.z), f2bf(v0.w)};
  u16x4 p1 = {f2bf(v1.x), f2bf(v1.y), f2bf(v1.z), f2bf(v1.w)};
  *(u16x4*)&ob[lane * 4] = p0;
  *(u16x4*)&ob[(lane + 64) * 4] = p1;
}

// ---------------- batched CSR build (all 8 timesteps upfront) --------------
__global__ void zero_hist_all(int* __restrict__ h) {
  int i = blockIdx.x * 256 + threadIdx.x;
  if (i < NT * (N_ENT + N_REL)) h[i] = 0;
}

__global__ void hist_all(const int* __restrict__ dst, const int* __restrict__ rel,
                         int* __restrict__ histD8, int* __restrict__ histR8) {
  int e = blockIdx.x * 256 + threadIdx.x;
  int t = blockIdx.y;
  if (e >= NE) return;
  atomicAdd(&histD8[t * N_ENT + dst[t * NE + e]], 1);
  atomicAdd(&histR8[t * N_REL + rel[t * NE + e]], 1);
}

__global__ void scan_part_all(const int* __restrict__ histD8, int* __restrict__ partD8) {
  int t = blockIdx.x, tid = threadIdx.x;
  const int* hd = histD8 + t * N_ENT;
  int base = tid * 80;                       // 256*80 >= 20000
  int s = 0;
  for (int i = 0; i < 80; ++i) {
    int idx = base + i;
    if (idx < N_ENT) s += hd[idx];
  }
  partD8[t * 257 + tid] = s;
}

__global__ void scan_serial_all(int* __restrict__ partD8, const int* __restrict__ histR8,
                                int* __restrict__ startR8, int* __restrict__ posR8) {
  int t = blockIdx.x;
  int* pd = partD8 + t * 257;
  int run = 0;
  for (int i = 0; i < 256; ++i) { int v = pd[i]; pd[i] = run; run += v; }
  pd[256] = run;
  const int* hr = histR8 + t * N_REL;
  int* sr = startR8 + t * 257;
  int* pr = posR8 + t * N_REL;
  run = 0;
  for (int i = 0; i < 256; ++i) { int v = hr[i]; sr[i] = run; pr[i] = run; run += v; }
  sr[256] = run;
}

__global__ void scan_local_all(const int* __restrict__ histD8, const int* __restrict__ partD8,
                               int* __restrict__ startD8, int* __restrict__ posD8) {
  int t = blockIdx.x, tid = threadIdx.x;
  const int* hd = histD8 + t * N_ENT;
  int* sd = startD8 + t * (N_ENT + 1);
  int* pd = posD8 + t * N_ENT;
  int run = partD8[t * 257 + tid];
  int base = tid * 80;
  for (int i = 0; i < 80; ++i) {
    int idx = base + i;
    if (idx < N_ENT) {
      sd[idx] = run;
      pd[idx] = run;
      run += hd[idx];
    }
  }
  if (tid == 0) sd[N_ENT] = partD8[t * 257 + 256];
}

__global__ void scatter_all(const int* __restrict__ dst, const int* __restrict__ rel,
                            int* __restrict__ posD8, int* __restrict__ posR8,
                            int* __restrict__ edgeD8, int* __restrict__ edgeR8) {
  int e = blockIdx.x * 256 + threadIdx.x;
  int t = blockIdx.y;
  if (e >= NE) return;
  int p = atomicAdd(&posD8[t * N_ENT + dst[t * NE + e]], 1);
  edgeD8[t * NE + p] = e;
  int p2 = atomicAdd(&posR8[t * N_REL + rel[t * NE + e]], 1);
  edgeR8[t * NE + p2] = e;
}

// ---------------- seg-sum via CSR: one wave per output row (f32) -----------
__global__ __launch_bounds__(256)
void agg_rel_csr(const float* __restrict__ ent, const int* __restrict__ src,
                 const int* __restrict__ edgeR, const int* __restrict__ startR,
                 float* __restrict__ aggR, float* __restrict__ cntR) {
  int r = blockIdx.x * 4 + (threadIdx.x >> 6);
  if (r >= N_REL) return;
  int lane = threadIdx.x & 63;
  int s0 = startR[r], s1 = startR[r + 1];
  float4 a = make_float4(0.f, 0.f, 0.f, 0.f);
  float4 b = make_float4(0.f, 0.f, 0.f, 0.f);
  for (int i = s0; i < s1; ++i) {
    int e = edgeR[i];
    int s = src[e];
    const float4* p = (const float4*)(ent + (size_t)s * HD);
    float4 x = p[lane];
    float4 y = p[lane + 64];
    a.x += x.x; a.y += x.y; a.z += x.z; a.w += x.w;
    b.x += y.x; b.y += y.y; b.z += y.z; b.w += y.w;
  }
  float4* op = (float4*)(aggR + (size_t)r * HD);
  op[lane] = a;
  op[lane + 64] = b;
  if (lane == 0) cntR[r] = (float)(s1 - s0);
}

__global__ __launch_bounds__(256)
void agg_ent_csr(const float* __restrict__ h, const float* __restrict__ relh,
                 const int* __restrict__ src, const int* __restrict__ erel,
                 const int* __restrict__ edgeD, const int* __restrict__ startD,
                 float* __restrict__ aggE, float* __restrict__ cntE) {
  int d = blockIdx.x * 4 + (threadIdx.x >> 6);
  if (d >= N_ENT) return;
  int lane = threadIdx.x & 63;
  int s0 = startD[d], s1 = startD[d + 1];
  float4 a = make_float4(0.f, 0.f, 0.f, 0.f);
  float4 b = make_float4(0.f, 0.f, 0.f, 0.f);
  for (int i = s0; i < s1; ++i) {
    int e = edgeD[i];
    int s = src[e], r = erel[e];
    const float4* hp = (const float4*)(h + (size_t)s * HD);
    const float4* rp = (const float4*)(relh + (size_t)r * HD);
    float4 x = hp[lane];
    float4 y = hp[lane + 64];
    float4 u = rp[lane];
    float4 v = rp[lane + 64];
    a.x += x.x + u.x; a.y += x.y + u.y; a.z += x.z + u.z; a.w += x.w + u.w;
    b.x += y.x + v.x; b.y += y.y + v.y; b.z += y.z + v.z; b.w += y.w + v.w;
  }
  float4* op = (float4*)(aggE + (size_t)d * HD);
  op[lane] = a;
  op[lane + 64] = b;
  if (lane == 0) cntE[d] = (float)(s1 - s0);
}

// ---------------- GRU elementwise (+bias fold, +bf16 mirror) ---------------
__global__ void gru_kernel(const float* __restrict__ gi, const float* __restrict__ gh,
                           const float* __restrict__ bih, const float* __restrict__ bhh,
                           float* __restrict__ relh, unsigned short* __restrict__ relhb) {
  int i = blockIdx.x * blockDim.x + threadIdx.x;
  if (i >= N_REL * HD) return;
  int row = i >> 9, col = i & 511;
  const float* gir = gi + (size_t)row * 1536;
  const float* ghr = gh + (size_t)row * 1536;
  float ir = gir[col] + bih[col];
  float iz = gir[col + 512] + bih[col + 512];
  float inn = gir[col + 1024] + bih[col + 1024];
  float hr = ghr[col] + bhh[col];
  float hz = ghr[col + 512] + bhh[col + 512];
  float hn = ghr[col + 1024] + bhh[col + 1024];
  float r = sigmoidf_(ir + hr);
  float z = sigmoidf_(iz + hz);
  float n = tanhf(inn + r * hn);
  float v = (1.0f - z) * n + z * relh[i];
  relh[i] = v;
  relhb[i] = f2bf(v);
}

// ---------------- gather rows (f32) ----------------------------------------
__global__ void gather_kernel(const float* __restrict__ table, const int* __restrict__ idx,
                              float* __restrict__ out, int rows) {
  int i = blockIdx.x * blockDim.x + threadIdx.x;
  if (i >= rows * (HD / 4)) return;
  int row = i >> 7, q = i & 127;
  ((float4*)out)[i] = ((const float4*)(table + (size_t)idx[row] * HD))[q];
}

// ---------------- flat f32 -> bf16 convert (n multiple of 8) ---------------
__global__ void f2b_kernel(const float* __restrict__ in, unsigned short* __restrict__ out, int n) {
  int i = blockIdx.x * blockDim.x + threadIdx.x;
  if (i * 8 >= n) return;
  float4 a = *(const float4*)&in[i * 8];
  float4 b = *(const float4*)&in[i * 8 + 4];
  u16x8 pk = {f2bf(a.x), f2bf(a.y), f2bf(a.z), f2bf(a.w),
              f2bf(b.x), f2bf(b.y), f2bf(b.z), f2bf(b.w)};
  *(u16x8*)&out[i * 8] = pk;
}

// ---------------------------------------------------------------------------
// pack_nn: B (KxN f32 row-major) -> bf16 LDS-image layout.
// ---------------------------------------------------------------------------
__global__ void pack_nn_kernel(const float* __restrict__ B, unsigned short* __restrict__ out,
                               int K, int N) {
  int id = blockIdx.x * 256 + threadIdx.x;
  if (id >= (K >> 3) * N) return;
  int s = id / (N * 4);
  int rem = id - s * (N * 4);
  int n = rem >> 2, g = rem & 3;
  const float* src = B + (size_t)(s * 32 + g * 8) * N + n;
  u16x8 pk;
  #pragma unroll
  for (int j = 0; j < 8; ++j) pk[j] = f2bf(src[(size_t)j * N]);
  *(u16x8*)&out[((size_t)s * N + n) * 32 + ((g ^ ((n >> 2) & 3)) << 3)] = pk;
}

// ---------------------------------------------------------------------------
// GEMM core: BK=32, 32KB LDS, depth-2 register prefetch.
// A = [A0 (M x K0, f32, row-scaled per SCALEMODE) | A1 (M x K1, bf16)].
// SCALEMODE: 0 none; 1 s=1/max(scl[row],1); 2 s=1/(sqrt(sum8 scl[row*8..]))+eps
// ACT: 0 plain f32; 1 relu (C + optional mirror Cb + optional pnrm partials
//      when WNRM, slot nslot); 3 gate with D scaled by norm (SCALEMODE==2).
// ---------------------------------------------------------------------------
template <int ACT, int MIRROR, int SCALEMODE, int WNRM>
static __device__ __forceinline__
void gemm_core(const float* __restrict__ A0, int K0, const float* __restrict__ scl,
               const unsigned short* __restrict__ A1, int K1,
               const unsigned short* __restrict__ Bp,
               const float* __restrict__ bias, const float* __restrict__ D,
               float* __restrict__ C, unsigned short* __restrict__ Cb,
               float* __restrict__ pnrm, int nslot,
               int M, int N, int m0, int n0,
               unsigned short (*As)[4096], unsigned short (*Bs)[4096]) {
  const int tid = threadIdx.x;
  const int lane = tid & 63;
  const int wv = tid >> 6;
  const int wm = wv >> 1, wn = wv & 1;
  const int lr = lane & 15, lg = lane >> 4;
  const int arow = tid >> 1;
  const int ahalf = tid & 1;
  const int NIT = (K0 + K1) >> 5;

  float s0 = 1.0f;
  if (SCALEMODE == 1 && K0 > 0 && (m0 + arow) < M) {
    s0 = 1.0f / fmaxf(scl[m0 + arow], 1.0f);
  } else if (SCALEMODE == 2 && K0 > 0 && (m0 + arow) < M) {
    float tsum = 0.f;
    #pragma unroll
    for (int k2 = 0; k2 < 8; ++k2) tsum += scl[(size_t)(m0 + arow) * 8 + k2];
    s0 = 1.0f / (sqrtf(tsum) + 1e-8f);
  }

  f32x4 acc[4][4];
  #pragma unroll
  for (int i = 0; i < 4; ++i)
    #pragma unroll
    for (int j = 0; j < 4; ++j) acc[i][j] = (f32x4){0.f, 0.f, 0.f, 0.f};

  auto gload = [&](int it, u16x8* ar, u16x8* br) {
    int mrow = m0 + arow;
    int kk = it * 32 + ahalf * 16;
    if (mrow < M) {
      if (kk < K0) {
        const float* p = A0 + (size_t)mrow * K0 + kk;
        #pragma unroll
        for (int q = 0; q < 2; ++q) {
          float4 x = *(const float4*)(p + q * 8);
          float4 y = *(const float4*)(p + q * 8 + 4);
          ar[q] = (u16x8){f2bf(x.x * s0), f2bf(x.y * s0), f2bf(x.z * s0), f2bf(x.w * s0),
                          f2bf(y.x * s0), f2bf(y.y * s0), f2bf(y.z * s0), f2bf(y.w * s0)};
        }
      } else {
        const unsigned short* p = A1 + (size_t)mrow * K1 + (kk - K0);
        #pragma unroll
        for (int q = 0; q < 2; ++q) ar[q] = *(const u16x8*)&p[q * 8];
      }
    } else {
      #pragma unroll
      for (int q = 0; q < 2; ++q) ar[q] = (u16x8){0, 0, 0, 0, 0, 0, 0, 0};
    }
    const unsigned short* b0 = Bp + ((size_t)it * N + n0) * 32;
    br[0] = *(const u16x8*)&b0[tid * 8];
    br[1] = *(const u16x8*)&b0[2048 + tid * 8];
  };
  auto swrite = [&](int nb, const u16x8* ar, const u16x8* br) {
    #pragma unroll
    for (int q = 0; q < 2; ++q) {
      int chunk = ahalf * 2 + q;
      *(u16x8*)&As[nb][arow * 32 + ((chunk ^ ((arow >> 1) & 3)) << 3)] = ar[q];
    }
    *(u16x8*)&Bs[nb][tid * 8] = br[0];
    *(u16x8*)&Bs[nb][2048 + tid * 8] = br[1];
  };
  auto mfma_phase = [&](int nb) {
    bf16x8 a[4], b[4];
    #pragma unroll
    for (int i = 0; i < 4; ++i) {
      int r = wm * 64 + i * 16 + lr;
      a[i] = *(const bf16x8*)&As[nb][r * 32 + ((lg ^ ((r >> 1) & 3)) << 3)];
      int nl = wn * 64 + i * 16 + lr;
      b[i] = *(const bf16x8*)&Bs[nb][nl * 32 + ((lg ^ ((nl >> 2) & 3)) << 3)];
    }
    #pragma unroll
    for (int i = 0; i < 4; ++i)
      #pragma unroll
      for (int j = 0; j < 4; ++j)
        acc[i][j] = __builtin_amdgcn_mfma_f32_16x16x32_bf16(a[i], b[j], acc[i][j], 0, 0, 0);
  };

  u16x8 ar0[2], br0[2], ar1[2], br1[2];
  gload(0, ar0, br0);
  swrite(0, ar0, br0);
  gload(1, ar1, br1);
  __syncthreads();

  int cur = 0;
  for (int itp = 0; itp < NIT; itp += 2) {
    if (itp + 2 < NIT) gload(itp + 2, ar0, br0);
    mfma_phase(cur);
    swrite(cur ^ 1, ar1, br1);
    __syncthreads();
    cur ^= 1;
    if (itp + 3 < NIT) gload(itp + 3, ar1, br1);
    mfma_phase(cur);
    if (itp + 2 < NIT) swrite(cur ^ 1, ar0, br0);
    __syncthreads();
    cur ^= 1;
  }

  float psq[4][4];
  if (WNRM) {
    #pragma unroll
    for (int i = 0; i < 4; ++i)
      #pragma unroll
      for (int q = 0; q < 4; ++q) psq[i][q] = 0.f;
  }

  #pragma unroll
  for (int i = 0; i < 4; ++i) {
    int m = m0 + wm * 64 + i * 16 + lg * 4;
    float sn[4];
    if (ACT == 3 && SCALEMODE == 2) {
      #pragma unroll
      for (int q = 0; q < 4; ++q) {
        int mr = m + q;
        if (mr < M) {
          float tsum = 0.f;
          #pragma unroll
          for (int k2 = 0; k2 < 8; ++k2) tsum += scl[(size_t)mr * 8 + k2];
          sn[q] = 1.0f / (sqrtf(tsum) + 1e-8f);
        } else sn[q] = 1.0f;
      }
    }
    #pragma unroll
    for (int j = 0; j < 4; ++j) {
      int n = n0 + wn * 64 + j * 16 + lr;
      #pragma unroll
      for (int q = 0; q < 4; ++q) {
        int mr = m + q;
        if (mr >= M) continue;
        size_t o = (size_t)mr * N + n;
        float v = acc[i][j][q];
        if (ACT == 0) {
          C[o] = v;
        } else if (ACT == 1) {
          float rr = fmaxf(v, 0.0f);
          C[o] = rr;
          if (MIRROR) Cb[o] = f2bf(rr);
          if (WNRM) psq[i][q] += rr * rr;
        } else {
          float u_ = sigmoidf_(v + bias[n]);
          float dv = (SCALEMODE == 2) ? D[o] * sn[q] : D[o];
          float rr = u_ * dv + (1.0f - u_) * C[o];
          C[o] = rr;
          if (MIRROR) Cb[o] = f2bf(rr);
        }
      }
    }
  }

  if (WNRM) {
    #pragma unroll
    for (int mm = 1; mm < 16; mm <<= 1) {
      #pragma unroll
      for (int i = 0; i < 4; ++i)
        #pragma unroll
        for (int q = 0; q < 4; ++q)
          psq[i][q] += __shfl_xor(psq[i][q], mm);
    }
    if (lr == 0) {
      #pragma unroll
      for (int i = 0; i < 4; ++i)
        #pragma unroll
        for (int q = 0; q < 4; ++q) {
          int mr = m0 + wm * 64 + i * 16 + lg * 4 + q;
          if (mr < M) pnrm[(size_t)mr * 8 + nslot * 2 + wn] = psq[i][q];
        }
    }
  }
}

template <int ACT, int MIRROR, int SCALEMODE, int WNRM>
__global__ __launch_bounds__(256, 3)
void gemm_nn2(const float* __restrict__ A0, int K0, const float* __restrict__ scl,
              const unsigned short* __restrict__ A1, int K1,
              const unsigned short* __restrict__ Bp,
              const float* __restrict__ bias, const float* __restrict__ D,
              float* __restrict__ C, unsigned short* __restrict__ Cb,
              float* __restrict__ pnrm, int M, int N) {
  __shared__ unsigned short As[2][4096];
  __shared__ unsigned short Bs[2][4096];
  gemm_core<ACT, MIRROR, SCALEMODE, WNRM>(A0, K0, scl, A1, K1, Bp, bias, D, C, Cb,
                                          pnrm, blockIdx.y, M, N,
                                          blockIdx.x * 128, blockIdx.y * 128, As, Bs);
}

// Fused GRU GEMMs: z=0 -> gi = [aggR/cnt | rel_bf] @ wp_ih; z=1 -> gh = relh_bf @ wp_hh
__global__ __launch_bounds__(256, 3)
void gru_gemms(const float* __restrict__ aggR, const float* __restrict__ cntR,
               const unsigned short* __restrict__ rel_bf,
               const unsigned short* __restrict__ relh_bf,
               const unsigned short* __restrict__ wp_ih,
               const unsigned short* __restrict__ wp_hh,
               float* __restrict__ gi, float* __restrict__ gh) {
  __shared__ unsigned short As[2][4096];
  __shared__ unsigned short Bs[2][4096];
  if (blockIdx.z == 0)
    gemm_core<0, 0, 1, 0>(aggR, 512, cntR, rel_bf, 512, wp_ih, nullptr, nullptr,
                          gi, nullptr, nullptr, 0, N_REL, 1536,
                          blockIdx.x * 128, blockIdx.y * 128, As, Bs);
  else
    gemm_core<0, 0, 0, 0>(nullptr, 0, nullptr, relh_bf, 512, wp_hh, nullptr, nullptr,
                          gh, nullptr, nullptr, 0, N_REL, 1536,
                          blockIdx.x * 128, blockIdx.y * 128, As, Bs);
}

// ---------------------------------------------------------------------------
// pack_fw: fw (32768x512 f32) -> bf16 image (same layout as pack_nn, N=512)
// ---------------------------------------------------------------------------
__global__ __launch_bounds__(256)
void pack_fw_kernel(const float* __restrict__ f0, const float* __restrict__ f1,
                    const float* __restrict__ f2, const float* __restrict__ f3,
                    unsigned short* __restrict__ o0, unsigned short* __restrict__ o1,
                    unsigned short* __restrict__ o2, unsigned short* __restrict__ o3) {
  __shared__ float L[32][512];
  const float* fw; unsigned short* op;
  switch (blockIdx.y) {
    case 0: fw = f0; op = o0; break;
    case 1: fw = f1; op = o1; break;
    case 2: fw = f2; op = o2; break;
    default: fw = f3; op = o3; break;
  }
  int s = blockIdx.x, tid = threadIdx.x;
  #pragma unroll
  for (int i = 0; i < 16; ++i) {
    int idx = tid + 256 * i;
    int r = idx >> 7, cq = (idx & 127) << 2;
    *(float4*)&L[r][cq] = *(const float4*)&fw[(size_t)(s * 32 + r) * 512 + cq];
  }
  __syncthreads();
  #pragma unroll
  for (int ii = 0; ii < 8; ++ii) {
    int slot = tid + 256 * ii;
    int n = slot >> 2, g = slot & 3;
    u16x8 pk;
    #pragma unroll
    for (int j = 0; j < 8; ++j) pk[j] = f2bf(L[g * 8 + j][n]);
    size_t off = (size_t)s * 16384 + n * 32 + ((g ^ ((n >> 2) & 3)) << 3);
    *(u16x8*)&op[off] = pk;
  }
}

// ---------------------------------------------------------------------------
// convgen: conv1d('SAME',K=3)+relu -> A_conv bf16 [NB][c*512+h], both paths.
// ---------------------------------------------------------------------------
template <int CIN>
__global__ __launch_bounds__(256)
void convgen_kernel(const float* __restrict__ X0e, const float* __restrict__ X1e,
                    const float* __restrict__ X2e,
                    const float* __restrict__ cwE, const float* __restrict__ cbE,
                    const float* __restrict__ X0r, const float* __restrict__ X1r,
                    const float* __restrict__ X2r,
                    const float* __restrict__ cwR, const float* __restrict__ cbR,
                    unsigned short* __restrict__ Ae, unsigned short* __restrict__ Ar) {
  __shared__ float wsm[64 * CIN * 3];
  __shared__ float bsm[64];
  const int path = blockIdx.y;
  const float* X[CIN]; const float* cw; const float* cb; unsigned short* A;
  if (path == 0) {
    X[0] = X0e; X[1] = X1e; if constexpr (CIN == 3) X[2] = X2e;
    cw = cwE; cb = cbE; A = Ae;
  } else {
    X[0] = X0r; X[1] = X1r; if constexpr (CIN == 3) X[2] = X2r;
    cw = cwR; cb = cbR; A = Ar;
  }
  const int tid = threadIdx.x;
  for (int i = tid; i < 64 * CIN * 3; i += 256) wsm[i] = cw[i];
  if (tid < 64) bsm[tid] = cb[tid];
  __syncthreads();

  const int o = tid & 63;
  const int b = blockIdx.x * 4 + (tid >> 6);
  const int h = o * 8;

  float xm[CIN][8], xl[CIN], xr[CIN];
  #pragma unroll
  for (int ci = 0; ci < CIN; ++ci) {
    const float* row = X[ci] + (size_t)b * HD + h;
    float4 a4 = *(const float4*)row;
    float4 b4 = *(const float4*)(row + 4);
    xm[ci][0] = a4.x; xm[ci][1] = a4.y; xm[ci][2] = a4.z; xm[ci][3] = a4.w;
    xm[ci][4] = b4.x; xm[ci][5] = b4.y; xm[ci][6] = b4.z; xm[ci][7] = b4.w;
    xl[ci] = (h > 0) ? row[-1] : 0.f;
    xr[ci] = (h + 8 < HD) ? row[8] : 0.f;
  }
  unsigned short* dst = A + (size_t)b * 32768 + h;
  for (int c = 0; c < 64; ++c) {
    float v[8];
    float cbv = bsm[c];
    #pragma unroll
    for (int e = 0; e < 8; ++e) v[e] = cbv;
    #pragma unroll
    for (int ci = 0; ci < CIN; ++ci) {
      float w0 = wsm[(c * CIN + ci) * 3 + 0];
      float w1 = wsm[(c * CIN + ci) * 3 + 1];
      float w2 = wsm[(c * CIN + ci) * 3 + 2];
      #pragma unroll
      for (int e = 0; e < 8; ++e) {
        float lft = e ? xm[ci][e - 1] : xl[ci];
        float rgt = (e < 7) ? xm[ci][e + 1] : xr[ci];
        v[e] = fmaf(lft, w0, fmaf(xm[ci][e], w1, fmaf(rgt, w2, v[e])));
      }
    }
    u16x8 pk;
    #pragma unroll
    for (int e = 0; e < 8; ++e) pk[e] = f2bf(fmaxf(v[e], 0.f));
    *(u16x8*)&dst[c * 512] = pk;
  }
}

// ---------------------------------------------------------------------------
// gemm_fc: part[path][ks] = A_conv(4096 x 32768 bf16) @ fw-image, KSPLIT=4.
// Depth-2 register prefetch. BK=64.
// ---------------------------------------------------------------------------
__global__ __launch_bounds__(256, 2)
void gemm_fc(const unsigned short* __restrict__ Abuf,
             const unsigned short* __restrict__ fwpE,
             const unsigned short* __restrict__ fwpR,
             float* __restrict__ partBase) {
  __shared__ unsigned short As[2][128 * 64];
  __shared__ unsigned short Bs[2][2 * 128 * 32];
  const int tid = threadIdx.x;
  const int lane = tid & 63;
  const int wv = tid >> 6;
  const int wm = wv >> 1, wn = wv & 1;
  const int lr = lane & 15, lg = lane >> 4;
  const int m0 = blockIdx.x * 128;
  const int n0 = blockIdx.y * 128;
  const int path = blockIdx.z >> 2;
  const int ks = blockIdx.z & 3;

  const unsigned short* A = Abuf + (size_t)path * ((size_t)NB * 32768);
  const unsigned short* fwp = (path == 0) ? fwpE : fwpR;
  float* part = partBase + (size_t)(path * 4 + ks) * ((size_t)NB * HD);

  const int arow = tid >> 1;
  const int achunk = (tid & 1) * 4;
  const unsigned short* aRow = A + (size_t)(m0 + arow) * 32768 + ks * 8192 + achunk * 8;
  const unsigned short* bBase = fwp + (size_t)(ks * 256) * 16384 + (size_t)n0 * 32;

  f32x4 acc[4][4];
  #pragma unroll
  for (int i = 0; i < 4; ++i)
    #pragma unroll
    for (int j = 0; j < 4; ++j) acc[i][j] = (f32x4){0.f, 0.f, 0.f, 0.f};

  auto gload = [&](int it, u16x8* ar, u16x8* br) {
    const unsigned short* ap = aRow + it * 64;
    #pragma unroll
    for (int q = 0; q < 4; ++q) ar[q] = *(const u16x8*)&ap[q * 8];
    const unsigned short* bp = bBase + (size_t)it * 2 * 16384;
    br[0] = *(const u16x8*)&bp[tid * 8];
    br[1] = *(const u16x8*)&bp[2048 + tid * 8];
    br[2] = *(const u16x8*)&bp[16384 + tid * 8];
    br[3] = *(const u16x8*)&bp[16384 + 2048 + tid * 8];
  };
  auto swrite = [&](int nb, const u16x8* ar, const u16x8* br) {
    #pragma unroll
    for (int q = 0; q < 4; ++q) {
      int chunk = achunk + q;
      *(u16x8*)&As[nb][arow * 64 + ((chunk ^ (arow & 7)) << 3)] = ar[q];
    }
    *(u16x8*)&Bs[nb][tid * 8] = br[0];
    *(u16x8*)&Bs[nb][2048 + tid * 8] = br[1];
    *(u16x8*)&Bs[nb][4096 + tid * 8] = br[2];
    *(u16x8*)&Bs[nb][4096 + 2048 + tid * 8] = br[3];
  };
  auto mfma_phase = [&](int nb) {
    bf16x8 af[2][4], bfr[2][4];
    #pragma unroll
    for (int u = 0; u < 2; ++u)
      #pragma unroll
      for (int i = 0; i < 4; ++i) {
        int r = wm * 64 + i * 16 + lr;
        af[u][i] = *(const bf16x8*)&As[nb][r * 64 + (((u * 4 + lg) ^ (r & 7)) << 3)];
        int nl = wn * 64 + i * 16 + lr;
        bfr[u][i] = *(const bf16x8*)&Bs[nb][u * 4096 + nl * 32 + ((lg ^ ((nl >> 2) & 3)) << 3)];
      }
    #pragma unroll
    for (int u = 0; u < 2; ++u)
      #pragma unroll
      for (int i = 0; i < 4; ++i)
        #pragma unroll
        for (int j = 0; j < 4; ++j)
          acc[i][j] = __builtin_amdgcn_mfma_f32_16x16x32_bf16(af[u][i], bfr[u][j], acc[i][j], 0, 0, 0);
  };

  u16x8 ar0[4], br0[4], ar1[4], br1[4];
  gload(0, ar0, br0);
  swrite(0, ar0, br0);
  gload(1, ar1, br1);
  __syncthreads();

  int cur = 0;
  for (int itp = 0; itp < 128; itp += 2) {
    if (itp + 2 < 128) gload(itp + 2, ar0, br0);
    mfma_phase(cur);
    swrite(cur ^ 1, ar1, br1);
    __syncthreads();
    cur ^= 1;
    if (itp + 3 < 128) gload(itp + 3, ar1, br1);
    mfma_phase(cur);
    if (itp + 2 < 128) swrite(cur ^ 1, ar0, br0);
    __syncthreads();
    cur ^= 1;
  }

  #pragma unroll
  for (int i = 0; i < 4; ++i) {
    int m = m0 + wm * 64 + i * 16 + lg * 4;
    #pragma unroll
    for (int j = 0; j < 4; ++j) {
      int n = n0 + wn * 64 + j * 16 + lr;
      #pragma unroll
      for (int q = 0; q < 4; ++q)
        part[(size_t)(m + q) * HD + n] = acc[i][j][q];
    }
  }
}

// ---------------------------------------------------------------------------
// reduce 4 split-K partials + bias + relu -> f32 out AND bf16 out
// ---------------------------------------------------------------------------
__global__ void reduce4_kernel(const float* __restrict__ pE, const float* __restrict__ pR,
                               const float* __restrict__ bE, const float* __restrict__ bR,
                               float* __restrict__ oE, float* __restrict__ oR,
                               unsigned short* __restrict__ obE, unsigned short* __restrict__ obR) {
  int p = blockIdx.y;
  const float* part = p ? pR : pE;
  const float* bias = p ? bR : bE;
  float* o = p ? oR : oE;
  unsigned short* ob = p ? obR : obE;
  int i = blockIdx.x * 256 + threadIdx.x;
  int col = (i << 2) & 511;
  float4 s = *(const float4*)&part[(size_t)i * 4];
  #pragma unroll
  for (int ks = 1; ks < 4; ++ks) {
    float4 t = *(const float4*)&part[(size_t)ks * (NB * HD) + i * 4];
    s.x += t.x; s.y += t.y; s.z += t.z; s.w += t.w;
  }
  float4 b4 = *(const float4*)&bias[col];
  s.x = fmaxf(s.x + b4.x, 0.f); s.y = fmaxf(s.y + b4.y, 0.f);
  s.z = fmaxf(s.z + b4.z, 0.f); s.w = fmaxf(s.w + b4.w, 0.f);
  *(float4*)&o[(size_t)i * 4] = s;
  u16x4 pk = {f2bf(s.x), f2bf(s.y), f2bf(s.z), f2bf(s.w)};
  *(u16x4*)&ob[(size_t)i * 4] = pk;
}

// ---------------------------------------------------------------------------
// bf16 NT GEMM pair: z selects (A0->C0) or (A1->C1). Shared B (NxK bf16).
// Depth-2 register-prefetch single-barrier pipeline. N-tail guarded.
// ---------------------------------------------------------------------------
__global__ __launch_bounds__(256, 2)
void gemm_nt_bf16(const unsigned short* __restrict__ Aa, const unsigned short* __restrict__ Ab,
                  const unsigned short* __restrict__ B,
                  float* __restrict__ Ca, float* __restrict__ Cb2,
                  int M, int N, int K) {
  __shared__ unsigned short As[2][8192];
  __shared__ unsigned short Bs[2][8192];
  const unsigned short* A = (blockIdx.z == 0) ? Aa : Ab;
  float* C = (blockIdx.z == 0) ? Ca : Cb2;
  const int tid = threadIdx.x;
  const int lane = tid & 63;
  const int wv = tid >> 6;
  const int wm = wv >> 1, wn = wv & 1;
  const int m0 = blockIdx.x * 128, n0 = blockIdx.y * 128;
  const int lr = lane & 15, lg = lane >> 4;
  const int row = tid >> 1, half = tid & 1;
  const int nrow = n0 + row;
  const int NIT = K >> 6;

  f32x4 acc[4][4];
  #pragma unroll
  for (int i = 0; i < 4; ++i)
    #pragma unroll
    for (int j = 0; j < 4; ++j) acc[i][j] = (f32x4){0.f, 0.f, 0.f, 0.f};

  auto gload = [&](int it, u16x8* ar, u16x8* br) {
    const unsigned short* asrc = A + (size_t)(m0 + row) * K + it * 64 + half * 32;
    #pragma unroll
    for (int q = 0; q < 4; ++q) ar[q] = *(const u16x8*)&asrc[q * 8];
    const unsigned short* bsrc = B + (size_t)nrow * K + it * 64 + half * 32;
    u16x8 z = {0, 0, 0, 0, 0, 0, 0, 0};
    #pragma unroll
    for (int q = 0; q < 4; ++q) br[q] = (nrow < N) ? *(const u16x8*)&bsrc[q * 8] : z;
  };
  auto swrite = [&](int nb, const u16x8* ar, const u16x8* br) {
    #pragma unroll
    for (int q = 0; q < 4; ++q) {
      int chunk = half * 4 + q;
      *(u16x8*)&As[nb][row * 64 + ((chunk ^ (row & 7)) << 3)] = ar[q];
      *(u16x8*)&Bs[nb][row * 64 + ((chunk ^ (row & 7)) << 3)] = br[q];
    }
  };
  auto mfma_phase = [&](int nb) {
    #pragma unroll
    for (int u = 0; u < 2; ++u) {
      bf16x8 a[4], b[4];
      #pragma unroll
      for (int i = 0; i < 4; ++i) {
        int r = wm * 64 + i * 16 + lr;
        a[i] = *(const bf16x8*)&As[nb][r * 64 + (((u * 4 + lg) ^ (r & 7)) << 3)];
        int n = wn * 64 + i * 16 + lr;
        b[i] = *(const bf16x8*)&Bs[nb][n * 64 + (((u * 4 + lg) ^ (n & 7)) << 3)];
      }
      #pragma unroll
      for (int i = 0; i < 4; ++i)
        #pragma unroll
        for (int j = 0; j < 4; ++j)
          acc[i][j] = __builtin_amdgcn_mfma_f32_16x16x32_bf16(a[i], b[j], acc[i][j], 0, 0, 0);
    }
  };

  u16x8 ar0[4], br0[4], ar1[4], br1[4];
  gload(0, ar0, br0);
  swrite(0, ar0, br0);
  gload(1, ar1, br1);
  __syncthreads();

  int cur = 0;
  for (int itp = 0; itp < NIT; itp += 2) {
    if (itp + 2 < NIT) gload(itp + 2, ar0, br0);
    mfma_phase(cur);
    swrite(cur ^ 1, ar1, br1);
    __syncthreads();
    cur ^= 1;
    if (itp + 3 < NIT) gload(itp + 3, ar1, br1);
    mfma_phase(cur);
    if (itp + 2 < NIT) swrite(cur ^ 1, ar0, br0);
    __syncthreads();
    cur ^= 1;
  }

  #pragma unroll
  for (int i = 0; i < 4; ++i) {
    int m = m0 + wm * 64 + i * 16 + lg * 4;
    #pragma unroll
    for (int j = 0; j < 4; ++j) {
      int n = n0 + wn * 64 + j * 16 + lr;
      if (n < N) {
        #pragma unroll
        for (int q = 0; q < 4; ++q)
          C[(size_t)(m + q) * N + n] = acc[i][j][q];
      }
    }
  }
}

// ---------------------------------------------------------------------------
extern "C" void kernel_launch(void* const* d_in, const int* in_sizes, int n_in,
                              void* d_out, int out_size, void* d_ws, size_t ws_size,
                              hipStream_t stream) {
  const float* ent_embeds = (const float*)d_in[0];
  const float* rel_embeds = (const float*)d_in[1];
  const float* W_msg  = (const float*)d_in[2];
  const float* W_self = (const float*)d_in[3];
  const float* gru_Wih = (const float*)d_in[4];
  const float* gru_Whh = (const float*)d_in[5];
  const float* gru_bih = (const float*)d_in[6];
  const float* gru_bhh = (const float*)d_in[7];
  const float* gate_W = (const float*)d_in[8];
  const float* gate_b = (const float*)d_in[9];
  const float* e_conv1 = (const float*)d_in[10]; const float* e_cb1 = (const float*)d_in[11];
  const float* e_fc1   = (const float*)d_in[12]; const float* e_fb1 = (const float*)d_in[13];
  const float* e_conv2 = (const float*)d_in[14]; const float* e_cb2 = (const float*)d_in[15];
  const float* e_fc2   = (const float*)d_in[16]; const float* e_fb2 = (const float*)d_in[17];
  const float* r_conv1 = (const float*)d_in[18]; const float* r_cb1 = (const float*)d_in[19];
  const float* r_fc1   = (const float*)d_in[20]; const float* r_fb1 = (const float*)d_in[21];
  const float* r_conv2 = (const float*)d_in[22]; const float* r_cb2 = (const float*)d_in[23];
  const float* r_fc2   = (const float*)d_in[24]; const float* r_fb2 = (const float*)d_in[25];
  const int* src  = (const int*)d_in[26];
  const int* dst  = (const int*)d_in[27];
  const int* erel = (const int*)d_in[28];
  const int* subj = (const int*)d_in[29];
  const int* rel  = (const int*)d_in[30];
  const int* obj  = (const int*)d_in[31];
  float* out = (float*)d_out;

  // -------- workspace layout --------
  float* w = (float*)d_ws;
  float* ent   = w; w += (size_t)N_ENT * HD;
  float* relh  = w; w += (size_t)N_REL * HD;
  float* aggR  = w; w += (size_t)N_REL * HD;
  float* cntR  = w; w += N_REL;
  float* gi    = w; w += (size_t)N_REL * 1536;
  float* gh    = w; w += (size_t)N_REL * 1536;
  float* aggE  = w; w += (size_t)N_ENT * HD;     // } aggE..h1b reused post-loop as
  float* cntE  = w; w += N_ENT;                  // } packed-fw storage
  float* tmp   = w; w += (size_t)N_ENT * HD;
  float* h0b   = w; w += (size_t)N_ENT * HD;
  float* h1b   = w; w += (size_t)N_ENT * HD;
  float* se    = w; w += (size_t)NB * HD;
  float* re_   = w; w += (size_t)NB * HD;
  float* oe    = w; w += (size_t)NB * HD;
  float* o1    = w; w += (size_t)NB * HD;
  float* q1    = w; w += (size_t)NB * HD;
  float* o2    = w; w += (size_t)NB * HD;
  float* q2    = w; w += (size_t)NB * HD;
  unsigned short* ent_bf  = (unsigned short*)w; w += (size_t)N_ENT * HD / 2;
  unsigned short* relh_bf = (unsigned short*)w; w += (size_t)N_REL * HD / 2;
  unsigned short* rel_bf  = (unsigned short*)w; w += (size_t)N_REL * HD / 2;
  unsigned short* h0b_bf  = (unsigned short*)w; w += (size_t)N_ENT * HD / 2;
  unsigned short* o1b = (unsigned short*)w; w += (size_t)NB * HD / 2;
  unsigned short* q1b = (unsigned short*)w; w += (size_t)NB * HD / 2;
  unsigned short* o2b = (unsigned short*)w; w += (size_t)NB * HD / 2;
  unsigned short* q2b = (unsigned short*)w; w += (size_t)NB * HD / 2;
  // norm partials: 8 per entity row
  float* pnrm = w; w += (size_t)N_ENT * 8;
  // recurrence weight packs (bf16)
  unsigned short* wp_ih = (unsigned short*)w;            // 1024x1536
  unsigned short* wp_hh = wp_ih + (size_t)1024 * 1536;   // 512x1536
  unsigned short* wp_l0 = wp_hh + (size_t)512 * 1536;    // 1024x512
  unsigned short* wp_l1 = wp_l0 + (size_t)1024 * 512;    // 1024x512
  unsigned short* wp_g  = wp_l1 + (size_t)1024 * 512;    // 512x512
  w += ((size_t)1024 * 1536 + 512 * 1536 + 2 * 1024 * 512 + 512 * 512) / 2;
  // batched CSR buffers (int), all 8 timesteps
  int* histD8  = (int*)w;                       // 8 x 20000
  int* histR8  = histD8 + (size_t)NT * N_ENT;   // 8 x 256 (contiguous for zeroing)
  int* partD8  = histR8 + (size_t)NT * N_REL;   // 8 x 257
  int* startD8 = partD8 + (size_t)NT * 257;     // 8 x 20001
  int* posD8   = startD8 + (size_t)NT * (N_ENT + 1);  // 8 x 20000
  int* startR8 = posD8 + (size_t)NT * N_ENT;    // 8 x 257
  int* posR8   = startR8 + (size_t)NT * 257;    // 8 x 256
  int* edgeD8  = posR8 + (size_t)NT * N_REL;    // 8 x 30000
  int* edgeR8  = edgeD8 + (size_t)NT * NE;      // 8 x 30000
  // fw packs alias the recurrence temporaries (used only post-loop)
  unsigned short* fwp0 = (unsigned short*)aggE;
  unsigned short* fwp1 = fwp0 + (size_t)16777216;
  unsigned short* fwp2 = fwp1 + (size_t)16777216;
  unsigned short* fwp3 = fwp2 + (size_t)16777216;
  (void)tmp;
  // decoder scratch in d_out (written+consumed before logits):
  unsigned short* Abuf = (unsigned short*)out;          // 2 x NB x 32768 u16
  float* pE = out + (size_t)2 * NB * 32768 / 2;         // f32 offset after Abuf
  float* pR = pE + (size_t)4 * NB * HD;

  const dim3 g_gru(2, 12, 2);  // 256 x 1536, z = {gi, gh}
  const dim3 g_ent(157, 4);    // 20000 x 512

  // -------- weight packing (once) --------
  {
    int t;
    t = (1024 * 1536) / 8; pack_nn_kernel<<<(t + 255) / 256, 256, 0, stream>>>(gru_Wih, wp_ih, 1024, 1536);
    t = (512 * 1536) / 8;  pack_nn_kernel<<<(t + 255) / 256, 256, 0, stream>>>(gru_Whh, wp_hh, 512, 1536);
    t = (512 * 512) / 8;
    pack_nn_kernel<<<(t + 255) / 256, 256, 0, stream>>>(W_msg, wp_l0, 512, 512);
    pack_nn_kernel<<<(t + 255) / 256, 256, 0, stream>>>(W_self, wp_l0 + (size_t)512 * 512, 512, 512);
    pack_nn_kernel<<<(t + 255) / 256, 256, 0, stream>>>(W_msg + (size_t)512 * 512, wp_l1, 512, 512);
    pack_nn_kernel<<<(t + 255) / 256, 256, 0, stream>>>(W_self + (size_t)512 * 512, wp_l1 + (size_t)512 * 512, 512, 512);
    pack_nn_kernel<<<(t + 255) / 256, 256, 0, stream>>>(gate_W, wp_g, 512, 512);
  }

  // -------- batched CSR build for all 8 timesteps --------
  zero_hist_all<<<(NT * (N_ENT + N_REL) + 255) / 256, 256, 0, stream>>>(histD8);
  hist_all<<<dim3((NE + 255) / 256, NT), 256, 0, stream>>>(dst, erel, histD8, histR8);
  scan_part_all<<<NT, 256, 0, stream>>>(histD8, partD8);
  scan_serial_all<<<NT, 1, 0, stream>>>(partD8, histR8, startR8, posR8);
  scan_local_all<<<NT, 256, 0, stream>>>(histD8, partD8, startD8, posD8);
  scatter_all<<<dim3((NE + 255) / 256, NT), 256, 0, stream>>>(dst, erel, posD8, posR8,
                                                              edgeD8, edgeR8);

  // -------- init --------
  rownorm_kernel<<<N_ENT / 4, 256, 0, stream>>>(ent_embeds, ent, ent_bf, N_ENT);
  hipMemcpyAsync(relh, rel_embeds, (size_t)N_REL * HD * 4, hipMemcpyDeviceToDevice, stream);
  f2b_kernel<<<(N_REL * HD / 8) / 256, 256, 0, stream>>>(rel_embeds, rel_bf, N_REL * HD);
  f2b_kernel<<<(N_REL * HD / 8) / 256, 256, 0, stream>>>(rel_embeds, relh_bf, N_REL * HD);

  // -------- timestep loop --------
  for (int t = 0; t < NT; ++t) {
    const int* st = src + t * NE;
    const int* rt = erel + t * NE;
    const int* edgeD = edgeD8 + (size_t)t * NE;
    const int* edgeR = edgeR8 + (size_t)t * NE;
    const int* startD = startD8 + (size_t)t * (N_ENT + 1);
    const int* startR = startR8 + (size_t)t * 257;

    // relation evolution
    agg_rel_csr<<<N_REL / 4, 256, 0, stream>>>(ent, st, edgeR, startR, aggR, cntR);
    gru_gemms<<<g_gru, 256, 0, stream>>>(aggR, cntR, rel_bf, relh_bf, wp_ih, wp_hh, gi, gh);
    gru_kernel<<<(N_REL * HD) / 256, 256, 0, stream>>>(gi, gh, gru_bih, gru_bhh, relh, relh_bf);

    // entity evolution: h = relu([mean-agg | h] @ [Wmsg;Wself]) per layer
    agg_ent_csr<<<N_ENT / 4, 256, 0, stream>>>(ent, relh, st, rt, edgeD, startD, aggE, cntE);
    gemm_nn2<1, 1, 1, 0><<<g_ent, 256, 0, stream>>>(aggE, 512, cntE, ent_bf, 512, wp_l0,
                                                    nullptr, nullptr, h0b, h0b_bf,
                                                    nullptr, N_ENT, 512);
    agg_ent_csr<<<N_ENT / 4, 256, 0, stream>>>(h0b, relh, st, rt, edgeD, startD, aggE, cntE);
    // layer 1: relu + per-row sumsq partials (pnrm fully overwritten each step)
    gemm_nn2<1, 0, 1, 1><<<g_ent, 256, 0, stream>>>(aggE, 512, cntE, h0b_bf, 512, wp_l1,
                                                    nullptr, nullptr, h1b, nullptr,
                                                    pnrm, N_ENT, 512);
    // gate: A = h1b row-scaled by 1/(sqrt(sum pnrm)+1e-8); D = h1b scaled same
    gemm_nn2<3, 1, 2, 0><<<g_ent, 256, 0, stream>>>(h1b, 512, pnrm, nullptr, 0, wp_g,
                                                    gate_b, h1b, ent, ent_bf,
                                                    nullptr, N_ENT, 512);
  }

  // -------- decoder prep --------
  pack_fw_kernel<<<dim3(1024, 4), 256, 0, stream>>>(e_fc1, r_fc1, e_fc2, r_fc2,
                                                    fwp0, fwp1, fwp2, fwp3);
  gather_kernel<<<(NB * HD / 4) / 256, 256, 0, stream>>>(ent, subj, se, NB);
  gather_kernel<<<(NB * HD / 4) / 256, 256, 0, stream>>>(relh, rel, re_, NB);
  gather_kernel<<<(NB * HD / 4) / 256, 256, 0, stream>>>(ent, obj, oe, NB);

  unsigned short* A_E = Abuf;
  unsigned short* A_R = Abuf + (size_t)NB * 32768;

  // -------- decoder stage 1 --------
  convgen_kernel<2><<<dim3(NB / 4, 2), 256, 0, stream>>>(
      se, re_, nullptr, e_conv1, e_cb1,
      se, oe, nullptr, r_conv1, r_cb1, A_E, A_R);
  gemm_fc<<<dim3(32, 4, 8), 256, 0, stream>>>(Abuf, fwp0, fwp1, pE);
  reduce4_kernel<<<dim3(NB * HD / 4 / 256, 2), 256, 0, stream>>>(
      pE, pR, e_fb1, r_fb1, o1, q1, o1b, q1b);

  // -------- decoder stage 2 --------
  convgen_kernel<3><<<dim3(NB / 4, 2), 256, 0, stream>>>(
      o1, se, re_, e_conv2, e_cb2,
      q1, se, oe, r_conv2, r_cb2, A_E, A_R);
  gemm_fc<<<dim3(32, 4, 8), 256, 0, stream>>>(Abuf, fwp2, fwp3, pE);
  reduce4_kernel<<<dim3(NB * HD / 4 / 256, 2), 256, 0, stream>>>(
      pE, pR, e_fb2, r_fb2, o2, q2, o2b, q2b);

  // -------- logits (bf16 MFMA), merged into 2 launches --------
  size_t off0 = 0;
  size_t off1 = (size_t)NB * N_ENT;
  size_t off2 = off1 + (size_t)NB * N_REL;
  size_t off3 = off2 + (size_t)NB * N_ENT;
  gemm_nt_bf16<<<dim3(32, 157, 2), 256, 0, stream>>>(o1b, o2b, ent_bf,
                                                     out + off0, out + off2, NB, N_ENT, HD);
  gemm_nt_bf16<<<dim3(32, 2, 2), 256, 0, stream>>>(q1b, q2b, relh_bf,
                                                   out + off1, out + off3, NB, N_REL, HD);
}